// Round 4
// baseline (182.187 us; speedup 1.0000x reference)
//
#include <hip/hip_runtime.h>

#define EPB 32          // envs per block (16 per wave, 2 per 8-lane group)
#define BLOCK 128       // 2 independent waves; env = 8 lanes, wave-internal
#define HS 292          // H LDS stride (288 + 4)
#define GS 148          // G/Ginv LDS stride (144 + 4)
#define SS 28           // b / aux stride (24 + 4)

#define WFENCE() __builtin_amdgcn_wave_barrier()   // compiler fence, 0 instr

#define DPP_XOR1 0xB1   // quad_perm [1,0,3,2]  : lane ^= 1
#define DPP_XOR2 0x4E   // quad_perm [2,3,0,1]  : lane ^= 2
#define DPP_QP3  0x1B   // quad_perm [3,2,1,0]  : lane ^= 3 (single hop)
#define DPP_HMIR 0x141  // row_half_mirror      : lane ^= 7 (within 8)

// gather slot-group g (0..7) holds the s-triple of lane (t ^ GMAP[g]):
// slots built as [own, ^1, ^2, ^3, ^7, ^6, ^5, ^4]
constexpr int GMAP[8] = {0, 1, 2, 3, 7, 6, 5, 4};

typedef float f2 __attribute__((ext_vector_type(2)));

__device__ __forceinline__ f2 pkfma(f2 a, f2 b, f2 c) {
  return __builtin_elementwise_fma(a, b, c);   // -> v_pk_fma_f32 on gfx950
}

// acc += dot(f4, s4)
#define FMA4(acc, f, s)                                         \
  acc = fmaf((f).x, (s).x,                                      \
        fmaf((f).y, (s).y,                                      \
        fmaf((f).z, (s).z,                                      \
        fmaf((f).w, (s).w, (acc)))))

// acc4 += s * v4
#define VFMA(acc, s, v)                                         \
  { (acc).x = fmaf((s), (v).x, (acc).x);                        \
    (acc).y = fmaf((s), (v).y, (acc).y);                        \
    (acc).z = fmaf((s), (v).z, (acc).z);                        \
    (acc).w = fmaf((s), (v).w, (acc).w); }

#define ADD4(A, B) { (A).x += (B).x; (A).y += (B).y; (A).z += (B).z; (A).w += (B).w; }

template<int CTRL>
__device__ __forceinline__ float dppv(float v) {
  return __int_as_float(__builtin_amdgcn_update_dpp(
      0, __float_as_int(v), CTRL, 0xF, 0xF, true));
}

template<int K>
__device__ __forceinline__ float getel(const float4& a, const float4& b, const float4& c) {
  if constexpr (K == 0) return a.x; else if constexpr (K == 1) return a.y;
  else if constexpr (K == 2) return a.z; else if constexpr (K == 3) return a.w;
  else if constexpr (K == 4) return b.x; else if constexpr (K == 5) return b.y;
  else if constexpr (K == 6) return b.z; else if constexpr (K == 7) return b.w;
  else if constexpr (K == 8) return c.x; else if constexpr (K == 9) return c.y;
  else if constexpr (K == 10) return c.z; else return c.w;
}
template<int K>
__device__ __forceinline__ void setel(float4& a, float4& b, float4& c, float v) {
  if constexpr (K == 0) a.x = v; else if constexpr (K == 1) a.y = v;
  else if constexpr (K == 2) a.z = v; else if constexpr (K == 3) a.w = v;
  else if constexpr (K == 4) b.x = v; else if constexpr (K == 5) b.y = v;
  else if constexpr (K == 6) b.z = v; else if constexpr (K == 7) b.w = v;
  else if constexpr (K == 8) c.x = v; else if constexpr (K == 9) c.y = v;
  else if constexpr (K == 10) c.z = v; else c.w = v;
}

// write scalar into slot S (0..23) of an f2[12] row (all-constant indices)
template<int S>
__device__ __forceinline__ void putS2(f2* m, float v) {
  if constexpr ((S & 1) == 0) m[S / 2].x = v; else m[S / 2].y = v;
}

// float4 view of quad Q (slots 4Q..4Q+3) of an f2[12] row — for bit-exact
// reuse of the FMA4 ordering in the mu computation.
#define PMQ(pm, Q) make_float4(pm[2*(Q)].x, pm[2*(Q)].y, pm[2*(Q)+1].x, pm[2*(Q)+1].y)

__device__ __forceinline__ float dot12(float4 a0, float4 a1, float4 a2,
                                       const float* p) {
  const float4* p4 = (const float4*)p;
  float4 b0 = p4[0], b1 = p4[1], b2 = p4[2];
  float acc = 0.f;
  FMA4(acc, a0, b0); FMA4(acc, a1, b1); FMA4(acc, a2, b2);
  return acc;
}

// ---- register-resident Gauss-Jordan (SPD, no pivoting) --------------------
template<int K>
__device__ __forceinline__ void pivot_pub(float4& a, float4& b, float4& c, float* piv) {
  float ip = 1.0f / getel<K>(a, b, c);
  setel<K>(a, b, c, 1.0f);
  a.x *= ip; a.y *= ip; a.z *= ip; a.w *= ip;
  b.x *= ip; b.y *= ip; b.z *= ip; b.w *= ip;
  c.x *= ip; c.y *= ip; c.z *= ip; c.w *= ip;
  float4* pv = (float4*)piv;
  pv[0] = a; pv[1] = b; pv[2] = c;
}

#define ELIM(f, A, B, C)                                              \
  { (A).x = fmaf(-(f), p0.x, (A).x); (A).y = fmaf(-(f), p0.y, (A).y); \
    (A).z = fmaf(-(f), p0.z, (A).z); (A).w = fmaf(-(f), p0.w, (A).w); \
    (B).x = fmaf(-(f), p1.x, (B).x); (B).y = fmaf(-(f), p1.y, (B).y); \
    (B).z = fmaf(-(f), p1.z, (B).z); (B).w = fmaf(-(f), p1.w, (B).w); \
    (C).x = fmaf(-(f), p2.x, (C).x); (C).y = fmaf(-(f), p2.y, (C).y); \
    (C).z = fmaf(-(f), p2.z, (C).z); (C).w = fmaf(-(f), p2.w, (C).w); }

template<int K>
__device__ __forceinline__ void rgj_step(float4& a0, float4& b0, float4& c0,
                                         float4& a1, float4& b1, float4& c1,
                                         float* piv, int t) {
  if constexpr (K < 8) {
    if (t == K) pivot_pub<K>(a0, b0, c0, piv);
  } else {
    if (t == K - 8) pivot_pub<K>(a1, b1, c1, piv);
  }
  WFENCE();
  const float4* pv = (const float4*)piv;
  float4 p0 = pv[0], p1 = pv[1], p2 = pv[2];
  {
    const bool own = (K < 8) && (t == K);
    float cur = getel<K>(a0, b0, c0);
    float f = own ? 0.0f : cur;
    setel<K>(a0, b0, c0, own ? cur : 0.0f);
    ELIM(f, a0, b0, c0);
  }
  {
    const bool own = (K >= 8) && (t == K - 8);
    float cur = getel<K>(a1, b1, c1);
    float f = own ? 0.0f : cur;
    setel<K>(a1, b1, c1, own ? cur : 0.0f);
    ELIM(f, a1, b1, c1);
  }
  WFENCE();
}

template<int K>
__device__ __forceinline__ void rgj_all(float4& a0, float4& b0, float4& c0,
                                        float4& a1, float4& b1, float4& c1,
                                        float* piv, int t) {
  rgj_step<K>(a0, b0, c0, a1, b1, c1, piv, t);
  if constexpr (K < 11) rgj_all<K + 1>(a0, b0, c0, a1, b1, c1, piv, t);
}

// ---- merged Gram rows (HtH) for rows t and i1, into registers -------------
__device__ __forceinline__ void gram_rows(const float* myH, int t, int i1,
    float4& a0, float4& b0, float4& c0, float4& a1, float4& b1, float4& c1) {
  a0 = make_float4(0.f, 0.f, 0.f, 0.f);
  b0 = a0; c0 = a0; a1 = a0; b1 = a0; c1 = a0;
#pragma unroll
  for (int k = 0; k < 24; ++k) {
    const float4* hk = (const float4*)(myH + k * 12);
    float4 h0 = hk[0], h1 = hk[1], h2 = hk[2];
    float f0 = myH[k * 12 + t];
    float f1 = myH[k * 12 + i1];
    VFMA(a0, f0, h0); VFMA(b0, f0, h1); VFMA(c0, f0, h2);
    VFMA(a1, f1, h0); VFMA(b1, f1, h1); VFMA(c1, f1, h2);
  }
}

// ---- one permuted Fm slot (all 3 rows at once, shared H[c] load) ----------
template<int g, int k>
__device__ __forceinline__ void slot3(const float* myH, int t,
    const float4* W0, const float4* W1, const float4* W2,
    f2* P0, f2* P1, f2* P2) {
  const int c = 3 * (t ^ GMAP[g]) + k;
  const float4* hc = (const float4*)(myH + c * 12);
  float4 h0 = hc[0], h1 = hc[1], h2 = hc[2];
  float d0 = 0.f, d1 = 0.f, d2 = 0.f;
  FMA4(d0, h0, W0[0]); FMA4(d0, h1, W0[1]); FMA4(d0, h2, W0[2]);
  FMA4(d1, h0, W1[0]); FMA4(d1, h1, W1[1]); FMA4(d1, h2, W1[2]);
  FMA4(d2, h0, W2[0]); FMA4(d2, h1, W2[1]); FMA4(d2, h2, W2[2]);
  constexpr int S = 3 * g + k;
  putS2<S>(P0, ((g == 0 && k == 0) ? 1.0f : 0.0f) - d0);
  putS2<S>(P1, ((g == 0 && k == 1) ? 1.0f : 0.0f) - d1);
  putS2<S>(P2, ((g == 0 && k == 2) ? 1.0f : 0.0f) - d2);
}

// b element in gather-permuted slot S
template<int S>
__device__ __forceinline__ float bgat(const float* bB, int t) {
  constexpr int g = S / 3, k = S % 3;
  return bB[3 * (t ^ GMAP[g]) + k];
}

// ---- per-env register state ----------------------------------------------
struct ES {
  f2 pm0[12], pm1[12], pm2[12];   // permuted Fm rows (72 VGPR)
  float mu0, mu1, mu2;
  float cf0, cf1, cf2;
  float l0, l1, l2, z0, z1, z2;
};

// full prologue for one env: G=P+HtH, invert, y, W, Fm slots, mu, cf
__device__ __forceinline__ void build_env(ES& S, const float* myH, float* gi,
                                          float* aux, const float* bB,
                                          const float* cfp, int t, int i1, int r0w) {
  float4 g0a, g0b, g0c, g1a, g1b, g1c;
  gram_rows(myH, t, i1, g0a, g0b, g0c, g1a, g1b, g1c);
  {
    const float4* p0 = (const float4*)(gi + t * 12);
    const float4* p1 = (const float4*)(gi + i1 * 12);
    float4 q0 = p0[0], q1 = p0[1], q2 = p0[2];
    float4 r0 = p1[0], r1 = p1[1], r2 = p1[2];
    ADD4(g0a, q0); ADD4(g0b, q1); ADD4(g0c, q2);
    ADD4(g1a, r0); ADD4(g1b, r1); ADD4(g1c, r2);
  }
  rgj_all<0>(g0a, g0b, g0c, g1a, g1b, g1c, aux + 12, t);
  {
    float4* w0 = (float4*)(gi + t * 12);
    w0[0] = g0a; w0[1] = g0b; w0[2] = g0c;
    if (t < 4) {
      float4* w1 = (float4*)(gi + (t + 8) * 12);
      w1[0] = g1a; w1[1] = g1b; w1[2] = g1c;
    }
  }
  float y0 = dot12(g0a, g0b, g0c, aux);
  float y1 = dot12(g1a, g1b, g1c, aux);
  WFENCE();
  aux[12 + t] = y0;
  if (t < 4) aux[20 + t] = y1;
  WFENCE();

  float4 hr0[3], hr1[3], hr2[3];
  { const float4* p = (const float4*)(myH + (r0w + 0) * 12); hr0[0]=p[0]; hr0[1]=p[1]; hr0[2]=p[2]; }
  { const float4* p = (const float4*)(myH + (r0w + 1) * 12); hr1[0]=p[0]; hr1[1]=p[1]; hr1[2]=p[2]; }
  { const float4* p = (const float4*)(myH + (r0w + 2) * 12); hr2[0]=p[0]; hr2[1]=p[1]; hr2[2]=p[2]; }
  float u0, u1, u2;
  {
    const float4* y4 = (const float4*)(aux + 12);
    float4 ya = y4[0], yb = y4[1], yc = y4[2];
    u0 = 0.f; FMA4(u0, hr0[0], ya); FMA4(u0, hr0[1], yb); FMA4(u0, hr0[2], yc);
    u1 = 0.f; FMA4(u1, hr1[0], ya); FMA4(u1, hr1[1], yb); FMA4(u1, hr1[2], yc);
    u2 = 0.f; FMA4(u2, hr2[0], ya); FMA4(u2, hr2[1], yb); FMA4(u2, hr2[2], yc);
  }

  float4 W0[3], W1[3], W2[3];
  W0[0] = make_float4(0.f,0.f,0.f,0.f); W0[1] = W0[0]; W0[2] = W0[0];
  W1[0] = W0[0]; W1[1] = W0[0]; W1[2] = W0[0];
  W2[0] = W0[0]; W2[1] = W0[0]; W2[2] = W0[0];
#define ACC_W(c, EX)                                                   \
  { const float4* g4 = (const float4*)(gi + (c) * 12);                 \
    float4 r0 = g4[0], r1 = g4[1], r2 = g4[2];                         \
    float k0 = hr0[(c) >> 2].EX, k1 = hr1[(c) >> 2].EX, k2 = hr2[(c) >> 2].EX; \
    VFMA(W0[0], k0, r0); VFMA(W0[1], k0, r1); VFMA(W0[2], k0, r2);     \
    VFMA(W1[0], k1, r0); VFMA(W1[1], k1, r1); VFMA(W1[2], k1, r2);     \
    VFMA(W2[0], k2, r0); VFMA(W2[1], k2, r1); VFMA(W2[2], k2, r2); }
  ACC_W(0, x) ACC_W(1, y) ACC_W(2,  z) ACC_W(3,  w)
  ACC_W(4, x) ACC_W(5, y) ACC_W(6,  z) ACC_W(7,  w)
  ACC_W(8, x) ACC_W(9, y) ACC_W(10, z) ACC_W(11, w)
#undef ACC_W

#define SL(g, k) slot3<g, k>(myH, t, W0, W1, W2, S.pm0, S.pm1, S.pm2);
  SL(0,0) SL(0,1) SL(0,2)  SL(1,0) SL(1,1) SL(1,2)
  SL(2,0) SL(2,1) SL(2,2)  SL(3,0) SL(3,1) SL(3,2)
  SL(4,0) SL(4,1) SL(4,2)  SL(5,0) SL(5,1) SL(5,2)
  SL(6,0) SL(6,1) SL(6,2)  SL(7,0) SL(7,1) SL(7,2)
#undef SL

  {
    float4 bg0 = make_float4(bgat<0>(bB,t),  bgat<1>(bB,t),  bgat<2>(bB,t),  bgat<3>(bB,t));
    float4 bg1 = make_float4(bgat<4>(bB,t),  bgat<5>(bB,t),  bgat<6>(bB,t),  bgat<7>(bB,t));
    float4 bg2 = make_float4(bgat<8>(bB,t),  bgat<9>(bB,t),  bgat<10>(bB,t), bgat<11>(bB,t));
    float4 bg3 = make_float4(bgat<12>(bB,t), bgat<13>(bB,t), bgat<14>(bB,t), bgat<15>(bB,t));
    float4 bg4 = make_float4(bgat<16>(bB,t), bgat<17>(bB,t), bgat<18>(bB,t), bgat<19>(bB,t));
    float4 bg5 = make_float4(bgat<20>(bB,t), bgat<21>(bB,t), bgat<22>(bB,t), bgat<23>(bB,t));
    float d0 = 0.f, d1 = 0.f, d2 = 0.f;
    FMA4(d0, PMQ(S.pm0,0), bg0); FMA4(d1, PMQ(S.pm1,0), bg0); FMA4(d2, PMQ(S.pm2,0), bg0);
    FMA4(d0, PMQ(S.pm0,1), bg1); FMA4(d1, PMQ(S.pm1,1), bg1); FMA4(d2, PMQ(S.pm2,1), bg1);
    FMA4(d0, PMQ(S.pm0,2), bg2); FMA4(d1, PMQ(S.pm1,2), bg2); FMA4(d2, PMQ(S.pm2,2), bg2);
    FMA4(d0, PMQ(S.pm0,3), bg3); FMA4(d1, PMQ(S.pm1,3), bg3); FMA4(d2, PMQ(S.pm2,3), bg3);
    FMA4(d0, PMQ(S.pm0,4), bg4); FMA4(d1, PMQ(S.pm1,4), bg4); FMA4(d2, PMQ(S.pm2,4), bg4);
    FMA4(d0, PMQ(S.pm0,5), bg5); FMA4(d1, PMQ(S.pm1,5), bg5); FMA4(d2, PMQ(S.pm2,5), bg5);
    S.mu0 = u0 - d0;
    S.mu1 = u1 - d1;
    S.mu2 = u2 - d2;
  }
  S.cf0 = cfp[0]; S.cf1 = cfp[1]; S.cf2 = cfp[2];
  S.l0 = S.l1 = S.l2 = S.z0 = S.z1 = S.z2 = 0.f;
}

// epilogue for one env: lz writes, then x = (HtH)^-1 Ht (z - b)
__device__ __forceinline__ void epi_env(ES& S, const float* myH, float* gi,
                                        float* aux, float* bBm,
                                        float* xout, float* lzout,
                                        int env_, int t, int i1, int r0w) {
  lzout[(size_t)env_ * 48 + r0w]          = S.l0;
  lzout[(size_t)env_ * 48 + r0w + 1]      = S.l1;
  lzout[(size_t)env_ * 48 + r0w + 2]      = S.l2;
  lzout[(size_t)env_ * 48 + 24 + r0w]     = S.z0;
  lzout[(size_t)env_ * 48 + 24 + r0w + 1] = S.z1;
  lzout[(size_t)env_ * 48 + 24 + r0w + 2] = S.z2;

  float bo0 = bBm[r0w];
  float bo1 = bBm[r0w + 1];
  float bo2 = bBm[r0w + 2];
  WFENCE();
  aux[r0w]     = S.z0 - bo0;
  aux[r0w + 1] = S.z1 - bo1;
  aux[r0w + 2] = S.z2 - bo2;
  WFENCE();

  float rv0 = 0.f, rv8 = 0.f;
  {
    const float4* a4 = (const float4*)aux;
    float4 au0 = a4[0], au1 = a4[1], au2 = a4[2], au3 = a4[3], au4 = a4[4], au5 = a4[5];
#define RVS(k, AV) { rv0 = fmaf(myH[(k) * 12 + t],  (AV), rv0);   \
                     rv8 = fmaf(myH[(k) * 12 + i1], (AV), rv8); }
    RVS(0,  au0.x) RVS(1,  au0.y) RVS(2,  au0.z) RVS(3,  au0.w)
    RVS(4,  au1.x) RVS(5,  au1.y) RVS(6,  au1.z) RVS(7,  au1.w)
    RVS(8,  au2.x) RVS(9,  au2.y) RVS(10, au2.z) RVS(11, au2.w)
    RVS(12, au3.x) RVS(13, au3.y) RVS(14, au3.z) RVS(15, au3.w)
    RVS(16, au4.x) RVS(17, au4.y) RVS(18, au4.z) RVS(19, au4.w)
    RVS(20, au5.x) RVS(21, au5.y) RVS(22, au5.z) RVS(23, au5.w)
#undef RVS
  }

  float4 g0a, g0b, g0c, g1a, g1b, g1c;
  gram_rows(myH, t, i1, g0a, g0b, g0c, g1a, g1b, g1c);
  WFENCE();
  aux[t] = rv0;
  if (t < 4) aux[t + 8] = rv8;
  WFENCE();
  rgj_all<0>(g0a, g0b, g0c, g1a, g1b, g1c, bBm, t);

  xout[(size_t)env_ * 12 + t] = dot12(g0a, g0b, g0c, aux);
  if (t < 4)
    xout[(size_t)env_ * 12 + t + 8] = dot12(g1a, g1b, g1c, aux);
}

// ---- iteration body macros (E = env state variable name) ------------------
#define IT_S(E) \
  float E##s0 = E.l0 + E.z0, E##s1 = E.l1 + E.z1, E##s2 = E.l2 + E.z2;

#define IT_L1(E) \
  float E##g3  = dppv<DPP_XOR1>(E##s0), E##g4  = dppv<DPP_XOR1>(E##s1), E##g5  = dppv<DPP_XOR1>(E##s2); \
  float E##g6  = dppv<DPP_XOR2>(E##s0), E##g7  = dppv<DPP_XOR2>(E##s1), E##g8  = dppv<DPP_XOR2>(E##s2); \
  float E##g9  = dppv<DPP_QP3>(E##s0),  E##g10 = dppv<DPP_QP3>(E##s1),  E##g11 = dppv<DPP_QP3>(E##s2);  \
  float E##g12 = dppv<DPP_HMIR>(E##s0), E##g13 = dppv<DPP_HMIR>(E##s1), E##g14 = dppv<DPP_HMIR>(E##s2);

#define IT_L2(E) \
  float E##g15 = dppv<DPP_HMIR>(E##g3), E##g16 = dppv<DPP_HMIR>(E##g4), E##g17 = dppv<DPP_HMIR>(E##g5); \
  float E##g18 = dppv<DPP_HMIR>(E##g6), E##g19 = dppv<DPP_HMIR>(E##g7), E##g20 = dppv<DPP_HMIR>(E##g8); \
  float E##g21 = dppv<DPP_HMIR>(E##g9), E##g22 = dppv<DPP_HMIR>(E##g10), E##g23 = dppv<DPP_HMIR>(E##g11);

#define IT_FMA(E) \
  f2 E##vp0 = {E##s0, E##s1},   E##vp1 = {E##s2, E##g3},   E##vp2 = {E##g4, E##g5};   \
  f2 E##vp3 = {E##g6, E##g7},   E##vp4 = {E##g8, E##g9},   E##vp5 = {E##g10, E##g11}; \
  f2 E##vp6 = {E##g12, E##g13}, E##vp7 = {E##g14, E##g15}, E##vp8 = {E##g16, E##g17}; \
  f2 E##vp9 = {E##g18, E##g19}, E##vp10 = {E##g20, E##g21}, E##vp11 = {E##g22, E##g23}; \
  f2 E##A0 = {E.mu0, 0.f}, E##A1 = {E.mu1, 0.f}, E##A2 = {E.mu2, 0.f}; \
  f2 E##B0 = {0.f, 0.f}, E##B1 = {0.f, 0.f}, E##B2 = {0.f, 0.f}; \
  E##A0 = pkfma(E.pm0[0], E##vp0, E##A0); E##A1 = pkfma(E.pm1[0], E##vp0, E##A1); E##A2 = pkfma(E.pm2[0], E##vp0, E##A2); \
  E##A0 = pkfma(E.pm0[1], E##vp1, E##A0); E##A1 = pkfma(E.pm1[1], E##vp1, E##A1); E##A2 = pkfma(E.pm2[1], E##vp1, E##A2); \
  E##A0 = pkfma(E.pm0[2], E##vp2, E##A0); E##A1 = pkfma(E.pm1[2], E##vp2, E##A1); E##A2 = pkfma(E.pm2[2], E##vp2, E##A2); \
  E##A0 = pkfma(E.pm0[3], E##vp3, E##A0); E##A1 = pkfma(E.pm1[3], E##vp3, E##A1); E##A2 = pkfma(E.pm2[3], E##vp3, E##A2); \
  E##A0 = pkfma(E.pm0[4], E##vp4, E##A0); E##A1 = pkfma(E.pm1[4], E##vp4, E##A1); E##A2 = pkfma(E.pm2[4], E##vp4, E##A2); \
  E##A0 = pkfma(E.pm0[5], E##vp5, E##A0); E##A1 = pkfma(E.pm1[5], E##vp5, E##A1); E##A2 = pkfma(E.pm2[5], E##vp5, E##A2); \
  E##B0 = pkfma(E.pm0[6], E##vp6, E##B0); E##B1 = pkfma(E.pm1[6], E##vp6, E##B1); E##B2 = pkfma(E.pm2[6], E##vp6, E##B2); \
  E##B0 = pkfma(E.pm0[7], E##vp7, E##B0); E##B1 = pkfma(E.pm1[7], E##vp7, E##B1); E##B2 = pkfma(E.pm2[7], E##vp7, E##B2); \
  E##B0 = pkfma(E.pm0[8], E##vp8, E##B0); E##B1 = pkfma(E.pm1[8], E##vp8, E##B1); E##B2 = pkfma(E.pm2[8], E##vp8, E##B2); \
  E##B0 = pkfma(E.pm0[9], E##vp9, E##B0); E##B1 = pkfma(E.pm1[9], E##vp9, E##B1); E##B2 = pkfma(E.pm2[9], E##vp9, E##B2); \
  E##B0 = pkfma(E.pm0[10], E##vp10, E##B0); E##B1 = pkfma(E.pm1[10], E##vp10, E##B1); E##B2 = pkfma(E.pm2[10], E##vp10, E##B2); \
  E##B0 = pkfma(E.pm0[11], E##vp11, E##B0); E##B1 = pkfma(E.pm1[11], E##vp11, E##B1); E##B2 = pkfma(E.pm2[11], E##vp11, E##B2);

#define IT_TAIL(E) \
  f2 E##C0 = E##A0 + E##B0, E##C1 = E##A1 + E##B1, E##C2 = E##A2 + E##B2; \
  float E##w0 = E##C0.x + E##C0.y, E##w1 = E##C1.x + E##C1.y, E##w2 = E##C2.x + E##C2.y; \
  float E##zp0 = fmaf(-2.0f, E##w0, E##s0); \
  float E##zp1 = fmaf(-2.0f, E##w1, E##s1); \
  float E##zp2 = fmaf(-2.0f, E##w2, E##s2); \
  E.l0 = E##w0; E.l1 = E##w1; E.l2 = E##w2; \
  bool E##gt = E##zp2 > pthr; \
  float E##e0 = E##gt ? E.cf0 : 0.0f; \
  float E##e1 = E##gt ? E.cf1 : 0.0f; \
  float E##e2 = E##gt ? E.cf2 : 0.0f; \
  E.z0 = __builtin_amdgcn_fmed3f(E##zp0, plo, phi) * E##e0; \
  E.z1 = __builtin_amdgcn_fmed3f(E##zp1, plo, phi) * E##e1; \
  E.z2 = __builtin_amdgcn_fmed3f(E##zp2, plo, phi) * E##e2;

__global__ __attribute__((amdgpu_flat_work_group_size(BLOCK, BLOCK),
                          amdgpu_waves_per_eu(1, 4)))
void pdhg_kernel(const float* __restrict__ P, const float* __restrict__ q,
                 const float* __restrict__ H, const float* __restrict__ b,
                 const float* __restrict__ cf, const int* __restrict__ itp,
                 float* __restrict__ out, int Btot) {
  __shared__ __align__(16) float sH[EPB * HS];
  __shared__ __align__(16) float sGi[EPB * GS];
  __shared__ __align__(16) float sB[EPB * SS];
  __shared__ __align__(16) float sAux[EPB * SS];

  const int tid  = threadIdx.x;
  const int wq   = tid >> 6;          // wave 0..1 — fully independent
  const int lane = tid & 63;
  const int g8   = lane >> 3;         // 8-lane group 0..7
  const int t    = lane & 7;
  const int eA   = wq * 16 + g8;      // this group's two envs (block-local)
  const int eB   = eA + 8;
  const int envA = blockIdx.x * EPB + eA;
  const int envB = envA + 8;
  const int envW0 = blockIdx.x * EPB + wq * 16;
  const int niter = itp[0];
  const int r0w = 3 * t;
  const int i1 = (t < 4) ? t + 8 : t;   // second owned row (safe alias for t>=4)

  // ---- PER-WAVE float4 staging of this wave's 16 envs: H, P, q, b ----
  {
    const float4* gH = (const float4*)(H + (size_t)envW0 * 288);
#pragma unroll
    for (int rep = 0; rep < 18; ++rep) {          // 16 envs * 72 f4 = 1152
      int i = lane + rep * 64;
      int ee = i / 72, off = i - ee * 72;
      *(float4*)&sH[(wq * 16 + ee) * HS + off * 4] = gH[i];
    }
    const float4* gP = (const float4*)(P + (size_t)envW0 * 144);
#pragma unroll
    for (int rep = 0; rep < 9; ++rep) {           // 16 envs * 36 f4 = 576
      int i = lane + rep * 64;
      int ee = i / 36, off = i - ee * 36;
      *(float4*)&sGi[(wq * 16 + ee) * GS + off * 4] = gP[i];
    }
    const float4* gq = (const float4*)(q + (size_t)envW0 * 12);
    if (lane < 48) {                              // 16 envs * 3 f4
      int ee = lane / 3, off = lane - ee * 3;
      *(float4*)&sAux[(wq * 16 + ee) * SS + off * 4] = gq[lane];
    }
    const float4* gb = (const float4*)(b + (size_t)envW0 * 24);
    {                                             // 16 envs * 6 f4 = 96
      int i = lane;
      int ee = i / 6, off = i - ee * 6;
      *(float4*)&sB[(wq * 16 + ee) * SS + off * 4] = gb[i];
      if (lane < 32) {
        i = lane + 64;
        ee = i / 6; off = i - ee * 6;
        *(float4*)&sB[(wq * 16 + ee) * SS + off * 4] = gb[i];
      }
    }
  }
  WFENCE();

  const float* myHA = &sH[eA * HS];
  const float* myHB = &sH[eB * HS];
  float* giA  = &sGi[eA * GS];
  float* giBp = &sGi[eB * GS];
  float* auxA = &sAux[eA * SS];
  float* auxBp = &sAux[eB * SS];
  float* bA   = &sB[eA * SS];
  float* bBp  = &sB[eB * SS];

  ES A, B;
  build_env(A, myHA, giA, auxA, bA, cf + (size_t)envA * 24 + r0w, t, i1, r0w);
  build_env(B, myHB, giBp, auxBp, bBp, cf + (size_t)envB * 24 + r0w, t, i1, r0w);

  // ---- iterations: two independent envs interleaved in one wave ----------
  const float plo  = (t < 4) ? -3.0e38f : -10.0f;
  const float phi  = (t < 4) ?  3.0e38f :  10.0f;
  const float pthr = (t < 4) ? 0.0f     : -3.0e38f;
#pragma unroll 1
  for (int it = 0; it < niter; ++it) {
    IT_S(A)  IT_S(B)
    IT_L1(A) IT_L1(B)
    IT_L2(A) IT_L2(B)
    IT_FMA(A) IT_FMA(B)
    IT_TAIL(A) IT_TAIL(B)
  }

  // ---- outputs ------------------------------------------------------------
  float* xout  = out;
  float* lzout = out + (size_t)Btot * 12;
  epi_env(A, myHA, giA, auxA, bA, xout, lzout, envA, t, i1, r0w);
  epi_env(B, myHB, giBp, auxBp, bBp, xout, lzout, envB, t, i1, r0w);
}

extern "C" void kernel_launch(void* const* d_in, const int* in_sizes, int n_in,
                              void* d_out, int out_size, void* d_ws, size_t ws_size,
                              hipStream_t stream) {
  const float* P  = (const float*)d_in[0];
  const float* q  = (const float*)d_in[1];
  const float* H  = (const float*)d_in[2];
  const float* b  = (const float*)d_in[3];
  const float* cf = (const float*)d_in[4];
  const int*   it = (const int*)d_in[5];
  float* out = (float*)d_out;
  const int B = in_sizes[1] / 12;       // q is [B,12]
  const int grid = B / EPB;             // 16384/32 = 512 blocks
  pdhg_kernel<<<grid, BLOCK, 0, stream>>>(P, q, H, b, cf, it, out, B);
}

// Round 5
// 181.651 us; speedup vs baseline: 1.0030x; 1.0030x over previous
//
#include <hip/hip_runtime.h>

#define EPB 32          // envs per block (16 per wave, 2 per 8-lane group)
#define BLOCK 128       // 2 independent waves; env = 8 lanes, wave-internal
#define HS 292          // H LDS stride (288 + 4)
#define GS 148          // G/Ginv LDS stride (144 + 4)
#define SS 28           // b / aux stride (24 + 4)

#define WFENCE() __builtin_amdgcn_wave_barrier()   // compiler fence, 0 instr

#define DPP_XOR1 0xB1   // quad_perm [1,0,3,2]  : lane ^= 1
#define DPP_XOR2 0x4E   // quad_perm [2,3,0,1]  : lane ^= 2
#define DPP_QP3  0x1B   // quad_perm [3,2,1,0]  : lane ^= 3 (single hop)
#define DPP_HMIR 0x141  // row_half_mirror      : lane ^= 7 (within 8)

// gather slot-group g (0..7) holds the s-triple of lane (t ^ GMAP[g]):
// slots built as [own, ^1, ^2, ^3, ^7, ^6, ^5, ^4]
constexpr int GMAP[8] = {0, 1, 2, 3, 7, 6, 5, 4};

typedef float f2 __attribute__((ext_vector_type(2)));

__device__ __forceinline__ f2 pkfma(f2 a, f2 b, f2 c) {
  return __builtin_elementwise_fma(a, b, c);   // -> v_pk_fma_f32 on gfx950
}

// acc += dot(f4, s4)
#define FMA4(acc, f, s)                                         \
  acc = fmaf((f).x, (s).x,                                      \
        fmaf((f).y, (s).y,                                      \
        fmaf((f).z, (s).z,                                      \
        fmaf((f).w, (s).w, (acc)))))

// acc4 += s * v4
#define VFMA(acc, s, v)                                         \
  { (acc).x = fmaf((s), (v).x, (acc).x);                        \
    (acc).y = fmaf((s), (v).y, (acc).y);                        \
    (acc).z = fmaf((s), (v).z, (acc).z);                        \
    (acc).w = fmaf((s), (v).w, (acc).w); }

#define ADD4(A, B) { (A).x += (B).x; (A).y += (B).y; (A).z += (B).z; (A).w += (B).w; }

template<int CTRL>
__device__ __forceinline__ float dppv(float v) {
  return __int_as_float(__builtin_amdgcn_update_dpp(
      0, __float_as_int(v), CTRL, 0xF, 0xF, true));
}

template<int K>
__device__ __forceinline__ float getel(const float4& a, const float4& b, const float4& c) {
  if constexpr (K == 0) return a.x; else if constexpr (K == 1) return a.y;
  else if constexpr (K == 2) return a.z; else if constexpr (K == 3) return a.w;
  else if constexpr (K == 4) return b.x; else if constexpr (K == 5) return b.y;
  else if constexpr (K == 6) return b.z; else if constexpr (K == 7) return b.w;
  else if constexpr (K == 8) return c.x; else if constexpr (K == 9) return c.y;
  else if constexpr (K == 10) return c.z; else return c.w;
}
template<int K>
__device__ __forceinline__ void setel(float4& a, float4& b, float4& c, float v) {
  if constexpr (K == 0) a.x = v; else if constexpr (K == 1) a.y = v;
  else if constexpr (K == 2) a.z = v; else if constexpr (K == 3) a.w = v;
  else if constexpr (K == 4) b.x = v; else if constexpr (K == 5) b.y = v;
  else if constexpr (K == 6) b.z = v; else if constexpr (K == 7) b.w = v;
  else if constexpr (K == 8) c.x = v; else if constexpr (K == 9) c.y = v;
  else if constexpr (K == 10) c.z = v; else c.w = v;
}

// write scalar into slot S (0..23) of an f2[12] row (all-constant indices)
template<int S>
__device__ __forceinline__ void putS2(f2* m, float v) {
  if constexpr ((S & 1) == 0) m[S / 2].x = v; else m[S / 2].y = v;
}

// float4 view of quad Q (slots 4Q..4Q+3) of an f2[12] row — for bit-exact
// reuse of the FMA4 ordering in the mu computation.
#define PMQ(pm, Q) make_float4(pm[2*(Q)].x, pm[2*(Q)].y, pm[2*(Q)+1].x, pm[2*(Q)+1].y)

__device__ __forceinline__ float dot12(float4 a0, float4 a1, float4 a2,
                                       const float* p) {
  const float4* p4 = (const float4*)p;
  float4 b0 = p4[0], b1 = p4[1], b2 = p4[2];
  float acc = 0.f;
  FMA4(acc, a0, b0); FMA4(acc, a1, b1); FMA4(acc, a2, b2);
  return acc;
}

// ---- register-resident Gauss-Jordan (SPD, no pivoting) --------------------
template<int K>
__device__ __forceinline__ void pivot_pub(float4& a, float4& b, float4& c, float* piv) {
  float ip = 1.0f / getel<K>(a, b, c);
  setel<K>(a, b, c, 1.0f);
  a.x *= ip; a.y *= ip; a.z *= ip; a.w *= ip;
  b.x *= ip; b.y *= ip; b.z *= ip; b.w *= ip;
  c.x *= ip; c.y *= ip; c.z *= ip; c.w *= ip;
  float4* pv = (float4*)piv;
  pv[0] = a; pv[1] = b; pv[2] = c;
}

#define ELIM(f, A, B, C)                                              \
  { (A).x = fmaf(-(f), p0.x, (A).x); (A).y = fmaf(-(f), p0.y, (A).y); \
    (A).z = fmaf(-(f), p0.z, (A).z); (A).w = fmaf(-(f), p0.w, (A).w); \
    (B).x = fmaf(-(f), p1.x, (B).x); (B).y = fmaf(-(f), p1.y, (B).y); \
    (B).z = fmaf(-(f), p1.z, (B).z); (B).w = fmaf(-(f), p1.w, (B).w); \
    (C).x = fmaf(-(f), p2.x, (C).x); (C).y = fmaf(-(f), p2.y, (C).y); \
    (C).z = fmaf(-(f), p2.z, (C).z); (C).w = fmaf(-(f), p2.w, (C).w); }

template<int K>
__device__ __forceinline__ void rgj_step(float4& a0, float4& b0, float4& c0,
                                         float4& a1, float4& b1, float4& c1,
                                         float* piv, int t) {
  if constexpr (K < 8) {
    if (t == K) pivot_pub<K>(a0, b0, c0, piv);
  } else {
    if (t == K - 8) pivot_pub<K>(a1, b1, c1, piv);
  }
  WFENCE();
  const float4* pv = (const float4*)piv;
  float4 p0 = pv[0], p1 = pv[1], p2 = pv[2];
  {
    const bool own = (K < 8) && (t == K);
    float cur = getel<K>(a0, b0, c0);
    float f = own ? 0.0f : cur;
    setel<K>(a0, b0, c0, own ? cur : 0.0f);
    ELIM(f, a0, b0, c0);
  }
  {
    const bool own = (K >= 8) && (t == K - 8);
    float cur = getel<K>(a1, b1, c1);
    float f = own ? 0.0f : cur;
    setel<K>(a1, b1, c1, own ? cur : 0.0f);
    ELIM(f, a1, b1, c1);
  }
  WFENCE();
}

template<int K>
__device__ __forceinline__ void rgj_all(float4& a0, float4& b0, float4& c0,
                                        float4& a1, float4& b1, float4& c1,
                                        float* piv, int t) {
  rgj_step<K>(a0, b0, c0, a1, b1, c1, piv, t);
  if constexpr (K < 11) rgj_all<K + 1>(a0, b0, c0, a1, b1, c1, piv, t);
}

// ---- merged Gram rows (HtH) for rows t and i1, into registers -------------
__device__ __forceinline__ void gram_rows(const float* myH, int t, int i1,
    float4& a0, float4& b0, float4& c0, float4& a1, float4& b1, float4& c1) {
  a0 = make_float4(0.f, 0.f, 0.f, 0.f);
  b0 = a0; c0 = a0; a1 = a0; b1 = a0; c1 = a0;
#pragma unroll
  for (int k = 0; k < 24; ++k) {
    const float4* hk = (const float4*)(myH + k * 12);
    float4 h0 = hk[0], h1 = hk[1], h2 = hk[2];
    float f0 = myH[k * 12 + t];
    float f1 = myH[k * 12 + i1];
    VFMA(a0, f0, h0); VFMA(b0, f0, h1); VFMA(c0, f0, h2);
    VFMA(a1, f1, h0); VFMA(b1, f1, h1); VFMA(c1, f1, h2);
  }
}

// ---- one permuted Fm slot (all 3 rows at once, shared H[c] load) ----------
template<int g, int k>
__device__ __forceinline__ void slot3(const float* myH, int t,
    const float4* W0, const float4* W1, const float4* W2,
    f2* P0, f2* P1, f2* P2) {
  const int c = 3 * (t ^ GMAP[g]) + k;
  const float4* hc = (const float4*)(myH + c * 12);
  float4 h0 = hc[0], h1 = hc[1], h2 = hc[2];
  float d0 = 0.f, d1 = 0.f, d2 = 0.f;
  FMA4(d0, h0, W0[0]); FMA4(d0, h1, W0[1]); FMA4(d0, h2, W0[2]);
  FMA4(d1, h0, W1[0]); FMA4(d1, h1, W1[1]); FMA4(d1, h2, W1[2]);
  FMA4(d2, h0, W2[0]); FMA4(d2, h1, W2[1]); FMA4(d2, h2, W2[2]);
  constexpr int S = 3 * g + k;
  putS2<S>(P0, ((g == 0 && k == 0) ? 1.0f : 0.0f) - d0);
  putS2<S>(P1, ((g == 0 && k == 1) ? 1.0f : 0.0f) - d1);
  putS2<S>(P2, ((g == 0 && k == 2) ? 1.0f : 0.0f) - d2);
}

// b element in gather-permuted slot S
template<int S>
__device__ __forceinline__ float bgat(const float* bB, int t) {
  constexpr int g = S / 3, k = S % 3;
  return bB[3 * (t ^ GMAP[g]) + k];
}

// ---- per-env register state ----------------------------------------------
struct ES {
  f2 pm0[12], pm1[12], pm2[12];   // permuted Fm rows (72 VGPR)
  float mu0, mu1, mu2;
  float cf0, cf1, cf2;
  float l0, l1, l2, z0, z1, z2;
};

// full prologue for one env: G=P+HtH, invert, y, W, Fm slots, mu, cf
__device__ __forceinline__ void build_env(ES& S, const float* myH, float* gi,
                                          float* aux, const float* bB,
                                          const float* cfp, int t, int i1, int r0w) {
  float4 g0a, g0b, g0c, g1a, g1b, g1c;
  gram_rows(myH, t, i1, g0a, g0b, g0c, g1a, g1b, g1c);
  {
    const float4* p0 = (const float4*)(gi + t * 12);
    const float4* p1 = (const float4*)(gi + i1 * 12);
    float4 q0 = p0[0], q1 = p0[1], q2 = p0[2];
    float4 r0 = p1[0], r1 = p1[1], r2 = p1[2];
    ADD4(g0a, q0); ADD4(g0b, q1); ADD4(g0c, q2);
    ADD4(g1a, r0); ADD4(g1b, r1); ADD4(g1c, r2);
  }
  rgj_all<0>(g0a, g0b, g0c, g1a, g1b, g1c, aux + 12, t);
  {
    float4* w0 = (float4*)(gi + t * 12);
    w0[0] = g0a; w0[1] = g0b; w0[2] = g0c;
    if (t < 4) {
      float4* w1 = (float4*)(gi + (t + 8) * 12);
      w1[0] = g1a; w1[1] = g1b; w1[2] = g1c;
    }
  }
  float y0 = dot12(g0a, g0b, g0c, aux);
  float y1 = dot12(g1a, g1b, g1c, aux);
  WFENCE();
  aux[12 + t] = y0;
  if (t < 4) aux[20 + t] = y1;
  WFENCE();

  float4 hr0[3], hr1[3], hr2[3];
  { const float4* p = (const float4*)(myH + (r0w + 0) * 12); hr0[0]=p[0]; hr0[1]=p[1]; hr0[2]=p[2]; }
  { const float4* p = (const float4*)(myH + (r0w + 1) * 12); hr1[0]=p[0]; hr1[1]=p[1]; hr1[2]=p[2]; }
  { const float4* p = (const float4*)(myH + (r0w + 2) * 12); hr2[0]=p[0]; hr2[1]=p[1]; hr2[2]=p[2]; }
  float u0, u1, u2;
  {
    const float4* y4 = (const float4*)(aux + 12);
    float4 ya = y4[0], yb = y4[1], yc = y4[2];
    u0 = 0.f; FMA4(u0, hr0[0], ya); FMA4(u0, hr0[1], yb); FMA4(u0, hr0[2], yc);
    u1 = 0.f; FMA4(u1, hr1[0], ya); FMA4(u1, hr1[1], yb); FMA4(u1, hr1[2], yc);
    u2 = 0.f; FMA4(u2, hr2[0], ya); FMA4(u2, hr2[1], yb); FMA4(u2, hr2[2], yc);
  }

  float4 W0[3], W1[3], W2[3];
  W0[0] = make_float4(0.f,0.f,0.f,0.f); W0[1] = W0[0]; W0[2] = W0[0];
  W1[0] = W0[0]; W1[1] = W0[0]; W1[2] = W0[0];
  W2[0] = W0[0]; W2[1] = W0[0]; W2[2] = W0[0];
#define ACC_W(c, EX)                                                   \
  { const float4* g4 = (const float4*)(gi + (c) * 12);                 \
    float4 r0 = g4[0], r1 = g4[1], r2 = g4[2];                         \
    float k0 = hr0[(c) >> 2].EX, k1 = hr1[(c) >> 2].EX, k2 = hr2[(c) >> 2].EX; \
    VFMA(W0[0], k0, r0); VFMA(W0[1], k0, r1); VFMA(W0[2], k0, r2);     \
    VFMA(W1[0], k1, r0); VFMA(W1[1], k1, r1); VFMA(W1[2], k1, r2);     \
    VFMA(W2[0], k2, r0); VFMA(W2[1], k2, r1); VFMA(W2[2], k2, r2); }
  ACC_W(0, x) ACC_W(1, y) ACC_W(2,  z) ACC_W(3,  w)
  ACC_W(4, x) ACC_W(5, y) ACC_W(6,  z) ACC_W(7,  w)
  ACC_W(8, x) ACC_W(9, y) ACC_W(10, z) ACC_W(11, w)
#undef ACC_W

#define SL(g, k) slot3<g, k>(myH, t, W0, W1, W2, S.pm0, S.pm1, S.pm2);
  SL(0,0) SL(0,1) SL(0,2)  SL(1,0) SL(1,1) SL(1,2)
  SL(2,0) SL(2,1) SL(2,2)  SL(3,0) SL(3,1) SL(3,2)
  SL(4,0) SL(4,1) SL(4,2)  SL(5,0) SL(5,1) SL(5,2)
  SL(6,0) SL(6,1) SL(6,2)  SL(7,0) SL(7,1) SL(7,2)
#undef SL

  {
    float4 bg0 = make_float4(bgat<0>(bB,t),  bgat<1>(bB,t),  bgat<2>(bB,t),  bgat<3>(bB,t));
    float4 bg1 = make_float4(bgat<4>(bB,t),  bgat<5>(bB,t),  bgat<6>(bB,t),  bgat<7>(bB,t));
    float4 bg2 = make_float4(bgat<8>(bB,t),  bgat<9>(bB,t),  bgat<10>(bB,t), bgat<11>(bB,t));
    float4 bg3 = make_float4(bgat<12>(bB,t), bgat<13>(bB,t), bgat<14>(bB,t), bgat<15>(bB,t));
    float4 bg4 = make_float4(bgat<16>(bB,t), bgat<17>(bB,t), bgat<18>(bB,t), bgat<19>(bB,t));
    float4 bg5 = make_float4(bgat<20>(bB,t), bgat<21>(bB,t), bgat<22>(bB,t), bgat<23>(bB,t));
    float d0 = 0.f, d1 = 0.f, d2 = 0.f;
    FMA4(d0, PMQ(S.pm0,0), bg0); FMA4(d1, PMQ(S.pm1,0), bg0); FMA4(d2, PMQ(S.pm2,0), bg0);
    FMA4(d0, PMQ(S.pm0,1), bg1); FMA4(d1, PMQ(S.pm1,1), bg1); FMA4(d2, PMQ(S.pm2,1), bg1);
    FMA4(d0, PMQ(S.pm0,2), bg2); FMA4(d1, PMQ(S.pm1,2), bg2); FMA4(d2, PMQ(S.pm2,2), bg2);
    FMA4(d0, PMQ(S.pm0,3), bg3); FMA4(d1, PMQ(S.pm1,3), bg3); FMA4(d2, PMQ(S.pm2,3), bg3);
    FMA4(d0, PMQ(S.pm0,4), bg4); FMA4(d1, PMQ(S.pm1,4), bg4); FMA4(d2, PMQ(S.pm2,4), bg4);
    FMA4(d0, PMQ(S.pm0,5), bg5); FMA4(d1, PMQ(S.pm1,5), bg5); FMA4(d2, PMQ(S.pm2,5), bg5);
    S.mu0 = u0 - d0;
    S.mu1 = u1 - d1;
    S.mu2 = u2 - d2;
  }
  S.cf0 = cfp[0]; S.cf1 = cfp[1]; S.cf2 = cfp[2];
  S.l0 = S.l1 = S.l2 = S.z0 = S.z1 = S.z2 = 0.f;
}

// epilogue for one env: lz writes, then x = (HtH)^-1 Ht (z - b)
__device__ __forceinline__ void epi_env(ES& S, const float* myH, float* gi,
                                        float* aux, float* bBm,
                                        float* xout, float* lzout,
                                        int env_, int t, int i1, int r0w) {
  lzout[(size_t)env_ * 48 + r0w]          = S.l0;
  lzout[(size_t)env_ * 48 + r0w + 1]      = S.l1;
  lzout[(size_t)env_ * 48 + r0w + 2]      = S.l2;
  lzout[(size_t)env_ * 48 + 24 + r0w]     = S.z0;
  lzout[(size_t)env_ * 48 + 24 + r0w + 1] = S.z1;
  lzout[(size_t)env_ * 48 + 24 + r0w + 2] = S.z2;

  float bo0 = bBm[r0w];
  float bo1 = bBm[r0w + 1];
  float bo2 = bBm[r0w + 2];
  WFENCE();
  aux[r0w]     = S.z0 - bo0;
  aux[r0w + 1] = S.z1 - bo1;
  aux[r0w + 2] = S.z2 - bo2;
  WFENCE();

  float rv0 = 0.f, rv8 = 0.f;
  {
    const float4* a4 = (const float4*)aux;
    float4 au0 = a4[0], au1 = a4[1], au2 = a4[2], au3 = a4[3], au4 = a4[4], au5 = a4[5];
#define RVS(k, AV) { rv0 = fmaf(myH[(k) * 12 + t],  (AV), rv0);   \
                     rv8 = fmaf(myH[(k) * 12 + i1], (AV), rv8); }
    RVS(0,  au0.x) RVS(1,  au0.y) RVS(2,  au0.z) RVS(3,  au0.w)
    RVS(4,  au1.x) RVS(5,  au1.y) RVS(6,  au1.z) RVS(7,  au1.w)
    RVS(8,  au2.x) RVS(9,  au2.y) RVS(10, au2.z) RVS(11, au2.w)
    RVS(12, au3.x) RVS(13, au3.y) RVS(14, au3.z) RVS(15, au3.w)
    RVS(16, au4.x) RVS(17, au4.y) RVS(18, au4.z) RVS(19, au4.w)
    RVS(20, au5.x) RVS(21, au5.y) RVS(22, au5.z) RVS(23, au5.w)
#undef RVS
  }

  float4 g0a, g0b, g0c, g1a, g1b, g1c;
  gram_rows(myH, t, i1, g0a, g0b, g0c, g1a, g1b, g1c);
  WFENCE();
  aux[t] = rv0;
  if (t < 4) aux[t + 8] = rv8;
  WFENCE();
  rgj_all<0>(g0a, g0b, g0c, g1a, g1b, g1c, bBm, t);

  xout[(size_t)env_ * 12 + t] = dot12(g0a, g0b, g0c, aux);
  if (t < 4)
    xout[(size_t)env_ * 12 + t + 8] = dot12(g1a, g1b, g1c, aux);
}

// ---- iteration body macros (E = env state variable name) ------------------
// Full body per env, SEQUENTIAL in source: the pre-RA scheduler interleaves
// the two env bodies up to its register-pressure budget (round-4's forced
// interleave pushed peak liveness past 256 VGPRs -> scratch spill).
#define IT_BODY(E) {                                                          \
  float s0 = E.l0 + E.z0, s1 = E.l1 + E.z1, s2 = E.l2 + E.z2;                 \
  float g3  = dppv<DPP_XOR1>(s0), g4  = dppv<DPP_XOR1>(s1), g5  = dppv<DPP_XOR1>(s2); \
  float g6  = dppv<DPP_XOR2>(s0), g7  = dppv<DPP_XOR2>(s1), g8  = dppv<DPP_XOR2>(s2); \
  float g9  = dppv<DPP_QP3>(s0),  g10 = dppv<DPP_QP3>(s1),  g11 = dppv<DPP_QP3>(s2);  \
  float g12 = dppv<DPP_HMIR>(s0), g13 = dppv<DPP_HMIR>(s1), g14 = dppv<DPP_HMIR>(s2); \
  float g15 = dppv<DPP_HMIR>(g3), g16 = dppv<DPP_HMIR>(g4), g17 = dppv<DPP_HMIR>(g5); \
  float g18 = dppv<DPP_HMIR>(g6), g19 = dppv<DPP_HMIR>(g7), g20 = dppv<DPP_HMIR>(g8); \
  float g21 = dppv<DPP_HMIR>(g9), g22 = dppv<DPP_HMIR>(g10), g23 = dppv<DPP_HMIR>(g11); \
  f2 vp0 = {s0, s1},   vp1 = {s2, g3},   vp2 = {g4, g5};                      \
  f2 vp3 = {g6, g7},   vp4 = {g8, g9},   vp5 = {g10, g11};                    \
  f2 vp6 = {g12, g13}, vp7 = {g14, g15}, vp8 = {g16, g17};                    \
  f2 vp9 = {g18, g19}, vp10 = {g20, g21}, vp11 = {g22, g23};                  \
  f2 A0 = {E.mu0, 0.f}, A1 = {E.mu1, 0.f}, A2 = {E.mu2, 0.f};                 \
  f2 B0 = {0.f, 0.f}, B1 = {0.f, 0.f}, B2 = {0.f, 0.f};                       \
  A0 = pkfma(E.pm0[0], vp0, A0); A1 = pkfma(E.pm1[0], vp0, A1); A2 = pkfma(E.pm2[0], vp0, A2); \
  A0 = pkfma(E.pm0[1], vp1, A0); A1 = pkfma(E.pm1[1], vp1, A1); A2 = pkfma(E.pm2[1], vp1, A2); \
  A0 = pkfma(E.pm0[2], vp2, A0); A1 = pkfma(E.pm1[2], vp2, A1); A2 = pkfma(E.pm2[2], vp2, A2); \
  A0 = pkfma(E.pm0[3], vp3, A0); A1 = pkfma(E.pm1[3], vp3, A1); A2 = pkfma(E.pm2[3], vp3, A2); \
  A0 = pkfma(E.pm0[4], vp4, A0); A1 = pkfma(E.pm1[4], vp4, A1); A2 = pkfma(E.pm2[4], vp4, A2); \
  A0 = pkfma(E.pm0[5], vp5, A0); A1 = pkfma(E.pm1[5], vp5, A1); A2 = pkfma(E.pm2[5], vp5, A2); \
  B0 = pkfma(E.pm0[6], vp6, B0); B1 = pkfma(E.pm1[6], vp6, B1); B2 = pkfma(E.pm2[6], vp6, B2); \
  B0 = pkfma(E.pm0[7], vp7, B0); B1 = pkfma(E.pm1[7], vp7, B1); B2 = pkfma(E.pm2[7], vp7, B2); \
  B0 = pkfma(E.pm0[8], vp8, B0); B1 = pkfma(E.pm1[8], vp8, B1); B2 = pkfma(E.pm2[8], vp8, B2); \
  B0 = pkfma(E.pm0[9], vp9, B0); B1 = pkfma(E.pm1[9], vp9, B1); B2 = pkfma(E.pm2[9], vp9, B2); \
  B0 = pkfma(E.pm0[10], vp10, B0); B1 = pkfma(E.pm1[10], vp10, B1); B2 = pkfma(E.pm2[10], vp10, B2); \
  B0 = pkfma(E.pm0[11], vp11, B0); B1 = pkfma(E.pm1[11], vp11, B1); B2 = pkfma(E.pm2[11], vp11, B2); \
  f2 C0 = A0 + B0, C1 = A1 + B1, C2 = A2 + B2;                                \
  float w0 = C0.x + C0.y, w1 = C1.x + C1.y, w2 = C2.x + C2.y;                 \
  float zp0 = fmaf(-2.0f, w0, s0);                                            \
  float zp1 = fmaf(-2.0f, w1, s1);                                            \
  float zp2 = fmaf(-2.0f, w2, s2);                                            \
  E.l0 = w0; E.l1 = w1; E.l2 = w2;                                            \
  bool gt = zp2 > pthr;                                                       \
  float e0 = gt ? E.cf0 : 0.0f;                                               \
  float e1 = gt ? E.cf1 : 0.0f;                                               \
  float e2 = gt ? E.cf2 : 0.0f;                                               \
  E.z0 = __builtin_amdgcn_fmed3f(zp0, -phi, phi) * e0;                        \
  E.z1 = __builtin_amdgcn_fmed3f(zp1, -phi, phi) * e1;                        \
  E.z2 = __builtin_amdgcn_fmed3f(zp2, -phi, phi) * e2;                        \
}

__global__ __attribute__((amdgpu_flat_work_group_size(BLOCK, BLOCK),
                          amdgpu_waves_per_eu(1, 4)))
void pdhg_kernel(const float* __restrict__ P, const float* __restrict__ q,
                 const float* __restrict__ H, const float* __restrict__ b,
                 const float* __restrict__ cf, const int* __restrict__ itp,
                 float* __restrict__ out, int Btot) {
  __shared__ __align__(16) float sH[EPB * HS];
  __shared__ __align__(16) float sGi[EPB * GS];
  __shared__ __align__(16) float sB[EPB * SS];
  __shared__ __align__(16) float sAux[EPB * SS];

  const int tid  = threadIdx.x;
  const int wq   = tid >> 6;          // wave 0..1 — fully independent
  const int lane = tid & 63;
  const int g8   = lane >> 3;         // 8-lane group 0..7
  const int t    = lane & 7;
  const int eA   = wq * 16 + g8;      // this group's two envs (block-local)
  const int eB   = eA + 8;
  const int envA = blockIdx.x * EPB + eA;
  const int envB = envA + 8;
  const int envW0 = blockIdx.x * EPB + wq * 16;
  const int niter = itp[0];
  const int r0w = 3 * t;
  const int i1 = (t < 4) ? t + 8 : t;   // second owned row (safe alias for t>=4)

  // ---- PER-WAVE float4 staging of this wave's 16 envs: H, P, q, b ----
  {
    const float4* gH = (const float4*)(H + (size_t)envW0 * 288);
#pragma unroll
    for (int rep = 0; rep < 18; ++rep) {          // 16 envs * 72 f4 = 1152
      int i = lane + rep * 64;
      int ee = i / 72, off = i - ee * 72;
      *(float4*)&sH[(wq * 16 + ee) * HS + off * 4] = gH[i];
    }
    const float4* gP = (const float4*)(P + (size_t)envW0 * 144);
#pragma unroll
    for (int rep = 0; rep < 9; ++rep) {           // 16 envs * 36 f4 = 576
      int i = lane + rep * 64;
      int ee = i / 36, off = i - ee * 36;
      *(float4*)&sGi[(wq * 16 + ee) * GS + off * 4] = gP[i];
    }
    const float4* gq = (const float4*)(q + (size_t)envW0 * 12);
    if (lane < 48) {                              // 16 envs * 3 f4
      int ee = lane / 3, off = lane - ee * 3;
      *(float4*)&sAux[(wq * 16 + ee) * SS + off * 4] = gq[lane];
    }
    const float4* gb = (const float4*)(b + (size_t)envW0 * 24);
    {                                             // 16 envs * 6 f4 = 96
      int i = lane;
      int ee = i / 6, off = i - ee * 6;
      *(float4*)&sB[(wq * 16 + ee) * SS + off * 4] = gb[i];
      if (lane < 32) {
        i = lane + 64;
        ee = i / 6; off = i - ee * 6;
        *(float4*)&sB[(wq * 16 + ee) * SS + off * 4] = gb[i];
      }
    }
  }
  WFENCE();

  const float* myHA = &sH[eA * HS];
  const float* myHB = &sH[eB * HS];
  float* giA  = &sGi[eA * GS];
  float* giBp = &sGi[eB * GS];
  float* auxA = &sAux[eA * SS];
  float* auxBp = &sAux[eB * SS];
  float* bA   = &sB[eA * SS];
  float* bBp  = &sB[eB * SS];

  ES A, B;
  build_env(A, myHA, giA, auxA, bA, cf + (size_t)envA * 24 + r0w, t, i1, r0w);
  build_env(B, myHB, giBp, auxBp, bBp, cf + (size_t)envB * 24 + r0w, t, i1, r0w);

  // ---- iterations: two independent envs, sequential bodies; scheduler ----
  // ---- interleaves within its pressure budget ----------------------------
  const float phi  = (t < 4) ?  3.0e38f :  10.0f;
  const float pthr = (t < 4) ? 0.0f     : -3.0e38f;
#pragma unroll 1
  for (int it = 0; it < niter; ++it) {
    IT_BODY(A)
    IT_BODY(B)
  }

  // ---- outputs ------------------------------------------------------------
  float* xout  = out;
  float* lzout = out + (size_t)Btot * 12;
  epi_env(A, myHA, giA, auxA, bA, xout, lzout, envA, t, i1, r0w);
  epi_env(B, myHB, giBp, auxBp, bBp, xout, lzout, envB, t, i1, r0w);
}

extern "C" void kernel_launch(void* const* d_in, const int* in_sizes, int n_in,
                              void* d_out, int out_size, void* d_ws, size_t ws_size,
                              hipStream_t stream) {
  const float* P  = (const float*)d_in[0];
  const float* q  = (const float*)d_in[1];
  const float* H  = (const float*)d_in[2];
  const float* b  = (const float*)d_in[3];
  const float* cf = (const float*)d_in[4];
  const int*   it = (const int*)d_in[5];
  float* out = (float*)d_out;
  const int B = in_sizes[1] / 12;       // q is [B,12]
  const int grid = B / EPB;             // 16384/32 = 512 blocks
  pdhg_kernel<<<grid, BLOCK, 0, stream>>>(P, q, H, b, cf, it, out, B);
}

// Round 6
// 145.855 us; speedup vs baseline: 1.2491x; 1.2454x over previous
//
#include <hip/hip_runtime.h>

#define EPB 32          // envs per block (8 per wave)
#define BLOCK 256       // 4 independent waves; env = 8 lanes, wave-internal
#define HS 292          // H LDS stride (288 + 4)
#define GS 148          // G/Ginv LDS stride (144 + 4)
#define SS 28           // b / aux stride (24 + 4)

#define WFENCE() __builtin_amdgcn_wave_barrier()   // compiler fence, 0 instr

#define DPP_XOR1 0xB1   // quad_perm [1,0,3,2]  : lane ^= 1
#define DPP_XOR2 0x4E   // quad_perm [2,3,0,1]  : lane ^= 2
#define DPP_QP3  0x1B   // quad_perm [3,2,1,0]  : lane ^= 3 (single hop)
#define DPP_HMIR 0x141  // row_half_mirror      : lane ^= 7 (within 8)

// gather slot-group g (0..7) holds the s-triple of lane (t ^ GMAP[g]):
// slots built as [own, ^1, ^2, ^3, ^7, ^6, ^5, ^4]
constexpr int GMAP[8] = {0, 1, 2, 3, 7, 6, 5, 4};

typedef float f2 __attribute__((ext_vector_type(2)));

__device__ __forceinline__ f2 pkfma(f2 a, f2 b, f2 c) {
  return __builtin_elementwise_fma(a, b, c);   // -> v_pk_fma_f32 on gfx950
}

// acc += dot(f4, s4)
#define FMA4(acc, f, s)                                         \
  acc = fmaf((f).x, (s).x,                                      \
        fmaf((f).y, (s).y,                                      \
        fmaf((f).z, (s).z,                                      \
        fmaf((f).w, (s).w, (acc)))))

// acc4 += s * v4
#define VFMA(acc, s, v)                                         \
  { (acc).x = fmaf((s), (v).x, (acc).x);                        \
    (acc).y = fmaf((s), (v).y, (acc).y);                        \
    (acc).z = fmaf((s), (v).z, (acc).z);                        \
    (acc).w = fmaf((s), (v).w, (acc).w); }

#define ADD4(A, B) { (A).x += (B).x; (A).y += (B).y; (A).z += (B).z; (A).w += (B).w; }

template<int CTRL>
__device__ __forceinline__ float dppv(float v) {
  return __int_as_float(__builtin_amdgcn_update_dpp(
      0, __float_as_int(v), CTRL, 0xF, 0xF, true));
}

template<int K>
__device__ __forceinline__ float getel(const float4& a, const float4& b, const float4& c) {
  if constexpr (K == 0) return a.x; else if constexpr (K == 1) return a.y;
  else if constexpr (K == 2) return a.z; else if constexpr (K == 3) return a.w;
  else if constexpr (K == 4) return b.x; else if constexpr (K == 5) return b.y;
  else if constexpr (K == 6) return b.z; else if constexpr (K == 7) return b.w;
  else if constexpr (K == 8) return c.x; else if constexpr (K == 9) return c.y;
  else if constexpr (K == 10) return c.z; else return c.w;
}
template<int K>
__device__ __forceinline__ void setel(float4& a, float4& b, float4& c, float v) {
  if constexpr (K == 0) a.x = v; else if constexpr (K == 1) a.y = v;
  else if constexpr (K == 2) a.z = v; else if constexpr (K == 3) a.w = v;
  else if constexpr (K == 4) b.x = v; else if constexpr (K == 5) b.y = v;
  else if constexpr (K == 6) b.z = v; else if constexpr (K == 7) b.w = v;
  else if constexpr (K == 8) c.x = v; else if constexpr (K == 9) c.y = v;
  else if constexpr (K == 10) c.z = v; else c.w = v;
}

__device__ __forceinline__ float dot12(float4 a0, float4 a1, float4 a2,
                                       const float* p) {
  const float4* p4 = (const float4*)p;
  float4 b0 = p4[0], b1 = p4[1], b2 = p4[2];
  float acc = 0.f;
  FMA4(acc, a0, b0); FMA4(acc, a1, b1); FMA4(acc, a2, b2);
  return acc;
}

// ---- register-resident Gauss-Jordan (SPD, no pivoting) --------------------
template<int K>
__device__ __forceinline__ void pivot_pub(float4& a, float4& b, float4& c, float* piv) {
  float ip = 1.0f / getel<K>(a, b, c);
  setel<K>(a, b, c, 1.0f);
  a.x *= ip; a.y *= ip; a.z *= ip; a.w *= ip;
  b.x *= ip; b.y *= ip; b.z *= ip; b.w *= ip;
  c.x *= ip; c.y *= ip; c.z *= ip; c.w *= ip;
  float4* pv = (float4*)piv;
  pv[0] = a; pv[1] = b; pv[2] = c;
}

#define ELIM(f, A, B, C)                                              \
  { (A).x = fmaf(-(f), p0.x, (A).x); (A).y = fmaf(-(f), p0.y, (A).y); \
    (A).z = fmaf(-(f), p0.z, (A).z); (A).w = fmaf(-(f), p0.w, (A).w); \
    (B).x = fmaf(-(f), p1.x, (B).x); (B).y = fmaf(-(f), p1.y, (B).y); \
    (B).z = fmaf(-(f), p1.z, (B).z); (B).w = fmaf(-(f), p1.w, (B).w); \
    (C).x = fmaf(-(f), p2.x, (C).x); (C).y = fmaf(-(f), p2.y, (C).y); \
    (C).z = fmaf(-(f), p2.z, (C).z); (C).w = fmaf(-(f), p2.w, (C).w); }

template<int K>
__device__ __forceinline__ void rgj_step(float4& a0, float4& b0, float4& c0,
                                         float4& a1, float4& b1, float4& c1,
                                         float* piv, int t) {
  if constexpr (K < 8) {
    if (t == K) pivot_pub<K>(a0, b0, c0, piv);
  } else {
    if (t == K - 8) pivot_pub<K>(a1, b1, c1, piv);
  }
  WFENCE();
  const float4* pv = (const float4*)piv;
  float4 p0 = pv[0], p1 = pv[1], p2 = pv[2];
  {
    const bool own = (K < 8) && (t == K);
    float cur = getel<K>(a0, b0, c0);
    float f = own ? 0.0f : cur;
    setel<K>(a0, b0, c0, own ? cur : 0.0f);
    ELIM(f, a0, b0, c0);
  }
  {
    const bool own = (K >= 8) && (t == K - 8);
    float cur = getel<K>(a1, b1, c1);
    float f = own ? 0.0f : cur;
    setel<K>(a1, b1, c1, own ? cur : 0.0f);
    ELIM(f, a1, b1, c1);
  }
  WFENCE();
}

template<int K>
__device__ __forceinline__ void rgj_all(float4& a0, float4& b0, float4& c0,
                                        float4& a1, float4& b1, float4& c1,
                                        float* piv, int t) {
  rgj_step<K>(a0, b0, c0, a1, b1, c1, piv, t);
  if constexpr (K < 11) rgj_all<K + 1>(a0, b0, c0, a1, b1, c1, piv, t);
}

// ---- merged Gram rows (HtH) for rows t and i1, into registers -------------
__device__ __forceinline__ void gram_rows(const float* myH, int t, int i1,
    float4& a0, float4& b0, float4& c0, float4& a1, float4& b1, float4& c1) {
  a0 = make_float4(0.f, 0.f, 0.f, 0.f);
  b0 = a0; c0 = a0; a1 = a0; b1 = a0; c1 = a0;
#pragma unroll
  for (int k = 0; k < 24; ++k) {
    const float4* hk = (const float4*)(myH + k * 12);
    float4 h0 = hk[0], h1 = hk[1], h2 = hk[2];
    float f0 = myH[k * 12 + t];
    float f1 = myH[k * 12 + i1];
    VFMA(a0, f0, h0); VFMA(b0, f0, h1); VFMA(c0, f0, h2);
    VFMA(a1, f1, h0); VFMA(b1, f1, h1); VFMA(c1, f1, h2);
  }
}

// ---- one permuted Fm slot (all 3 rows at once, shared H[c] load) ----------
// Fm symmetric: Fm[r][c] = delta - <H[c,:], W[:,r]>, W[:,r] = Ginv * H[r,:].
// ROW-PAIR storage: pm01[S] = {Fm[r0][colS], Fm[r1][colS]}, pm2s[S] = Fm[r2][colS].
template<int g, int k>
__device__ __forceinline__ void slot3(const float* myH, int t,
    const float4* W0, const float4* W1, const float4* W2,
    f2* pm01, float* pm2s) {
  const int c = 3 * (t ^ GMAP[g]) + k;
  const float4* hc = (const float4*)(myH + c * 12);
  float4 h0 = hc[0], h1 = hc[1], h2 = hc[2];
  float d0 = 0.f, d1 = 0.f, d2 = 0.f;
  FMA4(d0, h0, W0[0]); FMA4(d0, h1, W0[1]); FMA4(d0, h2, W0[2]);
  FMA4(d1, h0, W1[0]); FMA4(d1, h1, W1[1]); FMA4(d1, h2, W1[2]);
  FMA4(d2, h0, W2[0]); FMA4(d2, h1, W2[1]); FMA4(d2, h2, W2[2]);
  constexpr int S = 3 * g + k;
  pm01[S].x = ((g == 0 && k == 0) ? 1.0f : 0.0f) - d0;
  pm01[S].y = ((g == 0 && k == 1) ? 1.0f : 0.0f) - d1;
  pm2s[S]   = ((g == 0 && k == 2) ? 1.0f : 0.0f) - d2;
}

// b element in gather-permuted slot S
template<int S>
__device__ __forceinline__ float bgat(const float* bB, int t) {
  constexpr int g = S / 3, k = S % 3;
  return bB[3 * (t ^ GMAP[g]) + k];
}

// row-wise element accessors into the pair layout (S must be a literal)
#define MPV0(S) pm01[S].x
#define MPV1(S) pm01[S].y
#define MPV2(S) pm2s[S]
// bit-exact round-3 mu quad chain: acc order S+3 innermost .. S outermost
#define MUQ(d, PV, q, bg)                                             \
  d = fmaf(PV(4*(q)), (bg).x,                                         \
      fmaf(PV(4*(q)+1), (bg).y,                                       \
      fmaf(PV(4*(q)+2), (bg).z,                                       \
      fmaf(PV(4*(q)+3), (bg).w, d))));

__global__ __attribute__((amdgpu_flat_work_group_size(BLOCK, BLOCK),
                          amdgpu_waves_per_eu(1, 4)))
void pdhg_kernel(const float* __restrict__ P, const float* __restrict__ q,
                 const float* __restrict__ H, const float* __restrict__ b,
                 const float* __restrict__ cf, const int* __restrict__ itp,
                 float* __restrict__ out, int Btot) {
  __shared__ __align__(16) float sH[EPB * HS];
  __shared__ __align__(16) float sGi[EPB * GS];
  __shared__ __align__(16) float sB[EPB * SS];
  __shared__ __align__(16) float sAux[EPB * SS];

  const int tid  = threadIdx.x;
  const int wq   = tid >> 6;          // wave 0..3 — fully independent
  const int lane = tid & 63;
  const int e    = wq * 8 + (lane >> 3);
  const int t    = lane & 7;
  const int env  = blockIdx.x * EPB + e;
  const int envW0 = blockIdx.x * EPB + wq * 8;
  const int niter = itp[0];
  const int r0w = 3 * t;
  const int i1 = (t < 4) ? t + 8 : t;   // second owned row (safe alias for t>=4)

  // ---- PER-WAVE float4 staging of this wave's 8 envs: H, P, q, b ----
  {
    const float4* gH = (const float4*)(H + (size_t)envW0 * 288);
#pragma unroll
    for (int rep = 0; rep < 9; ++rep) {
      int i = lane + rep * 64;
      int ee = i / 72, off = i - ee * 72;
      *(float4*)&sH[(wq * 8 + ee) * HS + off * 4] = gH[i];
    }
    const float4* gP = (const float4*)(P + (size_t)envW0 * 144);
#pragma unroll
    for (int rep = 0; rep < 4; ++rep) {
      int i = lane + rep * 64;
      int ee = i / 36, off = i - ee * 36;
      *(float4*)&sGi[(wq * 8 + ee) * GS + off * 4] = gP[i];
    }
    { int i = lane + 256; if (lane < 32) {
        int ee = i / 36, off = i - ee * 36;
        *(float4*)&sGi[(wq * 8 + ee) * GS + off * 4] = gP[i]; } }
    const float4* gq = (const float4*)(q + (size_t)envW0 * 12);
    if (lane < 24) {
      int ee = lane / 3, off = lane - ee * 3;
      *(float4*)&sAux[(wq * 8 + ee) * SS + off * 4] = gq[lane];
    }
    const float4* gb = (const float4*)(b + (size_t)envW0 * 24);
    if (lane < 48) {
      int ee = lane / 6, off = lane - ee * 6;
      *(float4*)&sB[(wq * 8 + ee) * SS + off * 4] = gb[lane];
    }
  }
  WFENCE();

  const float* myH = &sH[e * HS];
  float* giB  = &sGi[e * GS];
  float* auxB = &sAux[e * SS];
  float* bBm  = &sB[e * SS];
  const float* bB = bBm;

  // ---- G = P + HtH in registers (rows t, i1); invert in place -------------
  float4 g0a, g0b, g0c, g1a, g1b, g1c;
  gram_rows(myH, t, i1, g0a, g0b, g0c, g1a, g1b, g1c);
  {
    const float4* p0 = (const float4*)(giB + t * 12);
    const float4* p1 = (const float4*)(giB + i1 * 12);
    float4 q0 = p0[0], q1 = p0[1], q2 = p0[2];
    float4 r0 = p1[0], r1 = p1[1], r2 = p1[2];
    ADD4(g0a, q0); ADD4(g0b, q1); ADD4(g0c, q2);
    ADD4(g1a, r0); ADD4(g1b, r1); ADD4(g1c, r2);
  }
  // pivot buffer: aux[12..23] (free until y is written)
  rgj_all<0>(g0a, g0b, g0c, g1a, g1b, g1c, auxB + 12, t);

  // ---- publish Ginv to LDS (overwrites staged P) + y = Ginv*q -------------
  {
    float4* w0 = (float4*)(giB + t * 12);
    w0[0] = g0a; w0[1] = g0b; w0[2] = g0c;
    if (t < 4) {
      float4* w1 = (float4*)(giB + (t + 8) * 12);
      w1[0] = g1a; w1[1] = g1b; w1[2] = g1c;
    }
  }
  float y0 = dot12(g0a, g0b, g0c, auxB);
  float y1 = dot12(g1a, g1b, g1c, auxB);
  WFENCE();
  auxB[12 + t] = y0;
  if (t < 4) auxB[20 + t] = y1;
  WFENCE();

  // ---- own H rows to regs; u = H*y (own rows) -----------------------------
  float4 hr0[3], hr1[3], hr2[3];
  { const float4* p = (const float4*)(myH + (r0w + 0) * 12); hr0[0]=p[0]; hr0[1]=p[1]; hr0[2]=p[2]; }
  { const float4* p = (const float4*)(myH + (r0w + 1) * 12); hr1[0]=p[0]; hr1[1]=p[1]; hr1[2]=p[2]; }
  { const float4* p = (const float4*)(myH + (r0w + 2) * 12); hr2[0]=p[0]; hr2[1]=p[1]; hr2[2]=p[2]; }
  float u0, u1, u2;
  {
    const float4* y4 = (const float4*)(auxB + 12);
    float4 ya = y4[0], yb = y4[1], yc = y4[2];
    u0 = 0.f; FMA4(u0, hr0[0], ya); FMA4(u0, hr0[1], yb); FMA4(u0, hr0[2], yc);
    u1 = 0.f; FMA4(u1, hr1[0], ya); FMA4(u1, hr1[1], yb); FMA4(u1, hr1[2], yc);
    u2 = 0.f; FMA4(u2, hr2[0], ya); FMA4(u2, hr2[1], yb); FMA4(u2, hr2[2], yc);
  }

  // ---- W[:,r] = Ginv * H[r,:] for the 3 own rows (Ginv rows read ONCE) ----
  float4 W0[3], W1[3], W2[3];
  W0[0] = make_float4(0.f,0.f,0.f,0.f); W0[1] = W0[0]; W0[2] = W0[0];
  W1[0] = W0[0]; W1[1] = W0[0]; W1[2] = W0[0];
  W2[0] = W0[0]; W2[1] = W0[0]; W2[2] = W0[0];
#define ACC_W(c, EX)                                                   \
  { const float4* g4 = (const float4*)(giB + (c) * 12);                \
    float4 r0 = g4[0], r1 = g4[1], r2 = g4[2];                         \
    float k0 = hr0[(c) >> 2].EX, k1 = hr1[(c) >> 2].EX, k2 = hr2[(c) >> 2].EX; \
    VFMA(W0[0], k0, r0); VFMA(W0[1], k0, r1); VFMA(W0[2], k0, r2);     \
    VFMA(W1[0], k1, r0); VFMA(W1[1], k1, r1); VFMA(W1[2], k1, r2);     \
    VFMA(W2[0], k2, r0); VFMA(W2[1], k2, r1); VFMA(W2[2], k2, r2); }
  ACC_W(0, x) ACC_W(1, y) ACC_W(2,  z) ACC_W(3,  w)
  ACC_W(4, x) ACC_W(5, y) ACC_W(6,  z) ACC_W(7,  w)
  ACC_W(8, x) ACC_W(9, y) ACC_W(10, z) ACC_W(11, w)
#undef ACC_W

  // ---- column-PERMUTED Fm rows (row-pair packed), one pass ---------------
  f2 pm01[24]; float pm2s[24];
#define SL(g, k) slot3<g, k>(myH, t, W0, W1, W2, pm01, pm2s);
  SL(0,0) SL(0,1) SL(0,2)  SL(1,0) SL(1,1) SL(1,2)
  SL(2,0) SL(2,1) SL(2,2)  SL(3,0) SL(3,1) SL(3,2)
  SL(4,0) SL(4,1) SL(4,2)  SL(5,0) SL(5,1) SL(5,2)
  SL(6,0) SL(6,1) SL(6,2)  SL(7,0) SL(7,1) SL(7,2)
#undef SL

  // ---- mu = H*y - Fm*b (b gathered permuted; bit-exact round-3 order) -----
  f2 mu01; float mu2s;
  {
    float4 bg0 = make_float4(bgat<0>(bB,t),  bgat<1>(bB,t),  bgat<2>(bB,t),  bgat<3>(bB,t));
    float4 bg1 = make_float4(bgat<4>(bB,t),  bgat<5>(bB,t),  bgat<6>(bB,t),  bgat<7>(bB,t));
    float4 bg2 = make_float4(bgat<8>(bB,t),  bgat<9>(bB,t),  bgat<10>(bB,t), bgat<11>(bB,t));
    float4 bg3 = make_float4(bgat<12>(bB,t), bgat<13>(bB,t), bgat<14>(bB,t), bgat<15>(bB,t));
    float4 bg4 = make_float4(bgat<16>(bB,t), bgat<17>(bB,t), bgat<18>(bB,t), bgat<19>(bB,t));
    float4 bg5 = make_float4(bgat<20>(bB,t), bgat<21>(bB,t), bgat<22>(bB,t), bgat<23>(bB,t));
    float d0 = 0.f, d1 = 0.f, d2 = 0.f;
    MUQ(d0, MPV0, 0, bg0) MUQ(d1, MPV1, 0, bg0) MUQ(d2, MPV2, 0, bg0)
    MUQ(d0, MPV0, 1, bg1) MUQ(d1, MPV1, 1, bg1) MUQ(d2, MPV2, 1, bg1)
    MUQ(d0, MPV0, 2, bg2) MUQ(d1, MPV1, 2, bg2) MUQ(d2, MPV2, 2, bg2)
    MUQ(d0, MPV0, 3, bg3) MUQ(d1, MPV1, 3, bg3) MUQ(d2, MPV2, 3, bg3)
    MUQ(d0, MPV0, 4, bg4) MUQ(d1, MPV1, 4, bg4) MUQ(d2, MPV2, 4, bg4)
    MUQ(d0, MPV0, 5, bg5) MUQ(d1, MPV1, 5, bg5) MUQ(d2, MPV2, 5, bg5)
    mu01.x = u0 - d0;
    mu01.y = u1 - d1;
    mu2s   = u2 - d2;
  }
  f2 cf01; float cf2v;
  cf01.x = cf[(size_t)env * 24 + r0w];
  cf01.y = cf[(size_t)env * 24 + r0w + 1];
  cf2v   = cf[(size_t)env * 24 + r0w + 2];

  // ---- iterations: 21-op DPP all-gather + row-pair pk FMA, pk tail --------
  // rows 0,1 ride in f2 pairs with SPLAT multipliers (op_sel broadcast, no
  // pack movs); row 2 runs scalar. {w0,w1} is the natural accumulator pair,
  // so the round-3 horizontal adds are gone.
  const float phi  = (t < 4) ?  3.0e38f :  10.0f;
  const float pthr = (t < 4) ? 0.0f     : -3.0e38f;
  const f2 lo01 = {-phi, -phi};
  const f2 hi01 = { phi,  phi};
  f2 l01 = {0.f, 0.f}, z01 = {0.f, 0.f};
  float l2 = 0.f, z2 = 0.f;
#pragma unroll 2
  for (int it = 0; it < niter; ++it) {
    f2 s01 = l01 + z01;                 // v_pk_add_f32
    float s2 = l2 + z2;
    float s0 = s01.x, s1 = s01.y;
    // ---- gather ladder: 21 DPP (QP3 single-hop; HMIR second level) ----
    float x1a = dppv<DPP_XOR1>(s0), x1b = dppv<DPP_XOR1>(s1), x1c = dppv<DPP_XOR1>(s2);
    float x2a = dppv<DPP_XOR2>(s0), x2b = dppv<DPP_XOR2>(s1), x2c = dppv<DPP_XOR2>(s2);
    float q3a = dppv<DPP_QP3>(s0),  q3b = dppv<DPP_QP3>(s1),  q3c = dppv<DPP_QP3>(s2);
    float h0a = dppv<DPP_HMIR>(s0), h0b = dppv<DPP_HMIR>(s1), h0c = dppv<DPP_HMIR>(s2);
    float h1a = dppv<DPP_HMIR>(x1a), h1b = dppv<DPP_HMIR>(x1b), h1c = dppv<DPP_HMIR>(x1c);
    float h2a = dppv<DPP_HMIR>(x2a), h2b = dppv<DPP_HMIR>(x2b), h2c = dppv<DPP_HMIR>(x2c);
    float h3a = dppv<DPP_HMIR>(q3a), h3b = dppv<DPP_HMIR>(q3b), h3c = dppv<DPP_HMIR>(q3c);
    // ---- 24 pk + 24 scalar FMA, 4 independent chains ----
    f2 A01 = mu01, B01 = {0.f, 0.f};
    float a2 = mu2s, b2 = 0.f;
#define STEPA(S, m) { f2 mm = {(m), (m)};                              \
      A01 = pkfma(pm01[S], mm, A01); a2 = fmaf(pm2s[S], (m), a2); }
#define STEPB(S, m) { f2 mm = {(m), (m)};                              \
      B01 = pkfma(pm01[S], mm, B01); b2 = fmaf(pm2s[S], (m), b2); }
    STEPA(0, s0)   STEPA(1, s1)   STEPA(2, s2)
    STEPA(3, x1a)  STEPA(4, x1b)  STEPA(5, x1c)
    STEPA(6, x2a)  STEPA(7, x2b)  STEPA(8, x2c)
    STEPA(9, q3a)  STEPA(10, q3b) STEPA(11, q3c)
    STEPB(12, h0a) STEPB(13, h0b) STEPB(14, h0c)
    STEPB(15, h1a) STEPB(16, h1b) STEPB(17, h1c)
    STEPB(18, h2a) STEPB(19, h2b) STEPB(20, h2c)
    STEPB(21, h3a) STEPB(22, h3b) STEPB(23, h3c)
#undef STEPA
#undef STEPB
    // ---- pk tail ----
    f2 w01 = A01 + B01;                 // = {w0, w1}
    float w2 = a2 + b2;
    f2 zp01 = pkfma((f2){-2.f, -2.f}, w01, s01);
    float zp2 = fmaf(-2.0f, w2, s2);
    l01 = w01; l2 = w2;
    f2 c01 = __builtin_elementwise_min(__builtin_elementwise_max(zp01, lo01), hi01);
    float c2 = __builtin_amdgcn_fmed3f(zp2, -phi, phi);
    bool gt = zp2 > pthr;               // cone: gate on zp2>0; box: always true
    f2 m01 = c01 * cf01;                // v_pk_mul_f32
    float m2 = c2 * cf2v;
    z01.x = gt ? m01.x : 0.0f;
    z01.y = gt ? m01.y : 0.0f;
    z2    = gt ? m2    : 0.0f;
  }

  // ---- outputs: lz, then x = (HtH)^-1 Ht (z - b) --------------------------
  float* xout  = out;
  float* lzout = out + (size_t)Btot * 12;
  lzout[(size_t)env * 48 + r0w]          = l01.x;
  lzout[(size_t)env * 48 + r0w + 1]      = l01.y;
  lzout[(size_t)env * 48 + r0w + 2]      = l2;
  lzout[(size_t)env * 48 + 24 + r0w]     = z01.x;
  lzout[(size_t)env * 48 + 24 + r0w + 1] = z01.y;
  lzout[(size_t)env * 48 + 24 + r0w + 2] = z2;

  float bo0 = bB[r0w];
  float bo1 = bB[r0w + 1];
  float bo2 = bB[r0w + 2];
  WFENCE();
  auxB[r0w]     = z01.x - bo0;
  auxB[r0w + 1] = z01.y - bo1;
  auxB[r0w + 2] = z2    - bo2;
  WFENCE();

  // rv = Ht (z - b), both owned columns in one pass, vectorized aux reads
  float rv0 = 0.f, rv8 = 0.f;
  {
    const float4* a4 = (const float4*)auxB;
    float4 au0 = a4[0], au1 = a4[1], au2 = a4[2], au3 = a4[3], au4 = a4[4], au5 = a4[5];
#define RVS(k, AV) { rv0 = fmaf(myH[(k) * 12 + t],  (AV), rv0);   \
                     rv8 = fmaf(myH[(k) * 12 + i1], (AV), rv8); }
    RVS(0,  au0.x) RVS(1,  au0.y) RVS(2,  au0.z) RVS(3,  au0.w)
    RVS(4,  au1.x) RVS(5,  au1.y) RVS(6,  au1.z) RVS(7,  au1.w)
    RVS(8,  au2.x) RVS(9,  au2.y) RVS(10, au2.z) RVS(11, au2.w)
    RVS(12, au3.x) RVS(13, au3.y) RVS(14, au3.z) RVS(15, au3.w)
    RVS(16, au4.x) RVS(17, au4.y) RVS(18, au4.z) RVS(19, au4.w)
    RVS(20, au5.x) RVS(21, au5.y) RVS(22, au5.z) RVS(23, au5.w)
#undef RVS
  }

  // second Gram (no P) + register GJ; pivot buffer reuses sB[0..11]
  gram_rows(myH, t, i1, g0a, g0b, g0c, g1a, g1b, g1c);
  WFENCE();
  auxB[t] = rv0;
  if (t < 4) auxB[t + 8] = rv8;
  WFENCE();
  rgj_all<0>(g0a, g0b, g0c, g1a, g1b, g1c, bBm, t);

  xout[(size_t)env * 12 + t] = dot12(g0a, g0b, g0c, auxB);
  if (t < 4)
    xout[(size_t)env * 12 + t + 8] = dot12(g1a, g1b, g1c, auxB);
}

extern "C" void kernel_launch(void* const* d_in, const int* in_sizes, int n_in,
                              void* d_out, int out_size, void* d_ws, size_t ws_size,
                              hipStream_t stream) {
  const float* P  = (const float*)d_in[0];
  const float* q  = (const float*)d_in[1];
  const float* H  = (const float*)d_in[2];
  const float* b  = (const float*)d_in[3];
  const float* cf = (const float*)d_in[4];
  const int*   it = (const int*)d_in[5];
  float* out = (float*)d_out;
  const int B = in_sizes[1] / 12;       // q is [B,12]
  const int grid = B / EPB;             // 16384/32 = 512 blocks
  pdhg_kernel<<<grid, BLOCK, 0, stream>>>(P, q, H, b, cf, it, out, B);
}

// Round 7
// 142.897 us; speedup vs baseline: 1.2750x; 1.0207x over previous
//
#include <hip/hip_runtime.h>

#define EPB 32          // envs per block (8 per wave)
#define BLOCK 256       // 4 independent waves; env = 8 lanes, wave-internal
#define HS 292          // H LDS stride (288 + 4)
#define GS 148          // G/Ginv LDS stride (144 + 4)
#define SS 28           // b / aux stride (24 + 4)

#define WFENCE() __builtin_amdgcn_wave_barrier()   // compiler fence, 0 instr

#define DPP_XOR1 0xB1   // quad_perm [1,0,3,2]  : lane ^= 1
#define DPP_XOR2 0x4E   // quad_perm [2,3,0,1]  : lane ^= 2
#define DPP_QP3  0x1B   // quad_perm [3,2,1,0]  : lane ^= 3 (single hop)
#define DPP_HMIR 0x141  // row_half_mirror      : lane ^= 7 (within 8)

// gather slot-group g (0..7) holds the s-triple of lane (t ^ GMAP[g]):
// slots built as [own, ^1, ^2, ^3, ^7, ^6, ^5, ^4]
constexpr int GMAP[8] = {0, 1, 2, 3, 7, 6, 5, 4};

typedef float f2 __attribute__((ext_vector_type(2)));

__device__ __forceinline__ f2 pkfma(f2 a, f2 b, f2 c) {
  return __builtin_elementwise_fma(a, b, c);   // -> v_pk_fma_f32 on gfx950
}

// acc += dot(f4, s4)
#define FMA4(acc, f, s)                                         \
  acc = fmaf((f).x, (s).x,                                      \
        fmaf((f).y, (s).y,                                      \
        fmaf((f).z, (s).z,                                      \
        fmaf((f).w, (s).w, (acc)))))

// acc4 += s * v4
#define VFMA(acc, s, v)                                         \
  { (acc).x = fmaf((s), (v).x, (acc).x);                        \
    (acc).y = fmaf((s), (v).y, (acc).y);                        \
    (acc).z = fmaf((s), (v).z, (acc).z);                        \
    (acc).w = fmaf((s), (v).w, (acc).w); }

#define ADD4(A, B) { (A).x += (B).x; (A).y += (B).y; (A).z += (B).z; (A).w += (B).w; }

template<int CTRL>
__device__ __forceinline__ float dppv(float v) {
  return __int_as_float(__builtin_amdgcn_update_dpp(
      0, __float_as_int(v), CTRL, 0xF, 0xF, true));
}

template<int K>
__device__ __forceinline__ float getel(const float4& a, const float4& b, const float4& c) {
  if constexpr (K == 0) return a.x; else if constexpr (K == 1) return a.y;
  else if constexpr (K == 2) return a.z; else if constexpr (K == 3) return a.w;
  else if constexpr (K == 4) return b.x; else if constexpr (K == 5) return b.y;
  else if constexpr (K == 6) return b.z; else if constexpr (K == 7) return b.w;
  else if constexpr (K == 8) return c.x; else if constexpr (K == 9) return c.y;
  else if constexpr (K == 10) return c.z; else return c.w;
}
template<int K>
__device__ __forceinline__ void setel(float4& a, float4& b, float4& c, float v) {
  if constexpr (K == 0) a.x = v; else if constexpr (K == 1) a.y = v;
  else if constexpr (K == 2) a.z = v; else if constexpr (K == 3) a.w = v;
  else if constexpr (K == 4) b.x = v; else if constexpr (K == 5) b.y = v;
  else if constexpr (K == 6) b.z = v; else if constexpr (K == 7) b.w = v;
  else if constexpr (K == 8) c.x = v; else if constexpr (K == 9) c.y = v;
  else if constexpr (K == 10) c.z = v; else c.w = v;
}

// write scalar into slot S (0..23) of an f2[12] row (all-constant indices)
template<int S>
__device__ __forceinline__ void putS2(f2* m, float v) {
  if constexpr ((S & 1) == 0) m[S / 2].x = v; else m[S / 2].y = v;
}

// float4 view of quad Q (slots 4Q..4Q+3) of an f2[12] row — for bit-exact
// reuse of the FMA4 ordering in the mu computation.
#define PMQ(pm, Q) make_float4(pm[2*(Q)].x, pm[2*(Q)].y, pm[2*(Q)+1].x, pm[2*(Q)+1].y)

__device__ __forceinline__ float dot12(float4 a0, float4 a1, float4 a2,
                                       const float* p) {
  const float4* p4 = (const float4*)p;
  float4 b0 = p4[0], b1 = p4[1], b2 = p4[2];
  float acc = 0.f;
  FMA4(acc, a0, b0); FMA4(acc, a1, b1); FMA4(acc, a2, b2);
  return acc;
}

// ---- register-resident Gauss-Jordan (SPD, no pivoting) --------------------
template<int K>
__device__ __forceinline__ void pivot_pub(float4& a, float4& b, float4& c, float* piv) {
  float ip = 1.0f / getel<K>(a, b, c);
  setel<K>(a, b, c, 1.0f);
  a.x *= ip; a.y *= ip; a.z *= ip; a.w *= ip;
  b.x *= ip; b.y *= ip; b.z *= ip; b.w *= ip;
  c.x *= ip; c.y *= ip; c.z *= ip; c.w *= ip;
  float4* pv = (float4*)piv;
  pv[0] = a; pv[1] = b; pv[2] = c;
}

#define ELIM(f, A, B, C)                                              \
  { (A).x = fmaf(-(f), p0.x, (A).x); (A).y = fmaf(-(f), p0.y, (A).y); \
    (A).z = fmaf(-(f), p0.z, (A).z); (A).w = fmaf(-(f), p0.w, (A).w); \
    (B).x = fmaf(-(f), p1.x, (B).x); (B).y = fmaf(-(f), p1.y, (B).y); \
    (B).z = fmaf(-(f), p1.z, (B).z); (B).w = fmaf(-(f), p1.w, (B).w); \
    (C).x = fmaf(-(f), p2.x, (C).x); (C).y = fmaf(-(f), p2.y, (C).y); \
    (C).z = fmaf(-(f), p2.z, (C).z); (C).w = fmaf(-(f), p2.w, (C).w); }

template<int K>
__device__ __forceinline__ void rgj_step(float4& a0, float4& b0, float4& c0,
                                         float4& a1, float4& b1, float4& c1,
                                         float* piv, int t) {
  if constexpr (K < 8) {
    if (t == K) pivot_pub<K>(a0, b0, c0, piv);
  } else {
    if (t == K - 8) pivot_pub<K>(a1, b1, c1, piv);
  }
  WFENCE();
  const float4* pv = (const float4*)piv;
  float4 p0 = pv[0], p1 = pv[1], p2 = pv[2];
  {
    const bool own = (K < 8) && (t == K);
    float cur = getel<K>(a0, b0, c0);
    float f = own ? 0.0f : cur;
    setel<K>(a0, b0, c0, own ? cur : 0.0f);
    ELIM(f, a0, b0, c0);
  }
  {
    const bool own = (K >= 8) && (t == K - 8);
    float cur = getel<K>(a1, b1, c1);
    float f = own ? 0.0f : cur;
    setel<K>(a1, b1, c1, own ? cur : 0.0f);
    ELIM(f, a1, b1, c1);
  }
  WFENCE();
}

template<int K>
__device__ __forceinline__ void rgj_all(float4& a0, float4& b0, float4& c0,
                                        float4& a1, float4& b1, float4& c1,
                                        float* piv, int t) {
  rgj_step<K>(a0, b0, c0, a1, b1, c1, piv, t);
  if constexpr (K < 11) rgj_all<K + 1>(a0, b0, c0, a1, b1, c1, piv, t);
}

// ---- merged Gram rows (HtH) for rows t and i1, into registers -------------
__device__ __forceinline__ void gram_rows(const float* myH, int t, int i1,
    float4& a0, float4& b0, float4& c0, float4& a1, float4& b1, float4& c1) {
  a0 = make_float4(0.f, 0.f, 0.f, 0.f);
  b0 = a0; c0 = a0; a1 = a0; b1 = a0; c1 = a0;
#pragma unroll
  for (int k = 0; k < 24; ++k) {
    const float4* hk = (const float4*)(myH + k * 12);
    float4 h0 = hk[0], h1 = hk[1], h2 = hk[2];
    float f0 = myH[k * 12 + t];
    float f1 = myH[k * 12 + i1];
    VFMA(a0, f0, h0); VFMA(b0, f0, h1); VFMA(c0, f0, h2);
    VFMA(a1, f1, h0); VFMA(b1, f1, h1); VFMA(c1, f1, h2);
  }
}

// ---- one permuted Fm slot (all 3 rows at once, shared H[c] load) ----------
// Fm symmetric: Fm[r][c] = delta - <H[c,:], W[:,r]>, W[:,r] = Ginv * H[r,:].
// COLUMN-PAIR storage (round-3 layout): pmR[S/2].{x,y} = Fm[rR][colS even/odd]
template<int g, int k>
__device__ __forceinline__ void slot3(const float* myH, int t,
    const float4* W0, const float4* W1, const float4* W2,
    f2* P0, f2* P1, f2* P2) {
  const int c = 3 * (t ^ GMAP[g]) + k;
  const float4* hc = (const float4*)(myH + c * 12);
  float4 h0 = hc[0], h1 = hc[1], h2 = hc[2];
  float d0 = 0.f, d1 = 0.f, d2 = 0.f;
  FMA4(d0, h0, W0[0]); FMA4(d0, h1, W0[1]); FMA4(d0, h2, W0[2]);
  FMA4(d1, h0, W1[0]); FMA4(d1, h1, W1[1]); FMA4(d1, h2, W1[2]);
  FMA4(d2, h0, W2[0]); FMA4(d2, h1, W2[1]); FMA4(d2, h2, W2[2]);
  constexpr int S = 3 * g + k;
  putS2<S>(P0, ((g == 0 && k == 0) ? 1.0f : 0.0f) - d0);
  putS2<S>(P1, ((g == 0 && k == 1) ? 1.0f : 0.0f) - d1);
  putS2<S>(P2, ((g == 0 && k == 2) ? 1.0f : 0.0f) - d2);
}

// b element in gather-permuted slot S
template<int S>
__device__ __forceinline__ float bgat(const float* bB, int t) {
  constexpr int g = S / 3, k = S % 3;
  return bB[3 * (t ^ GMAP[g]) + k];
}

__global__ __attribute__((amdgpu_flat_work_group_size(BLOCK, BLOCK),
                          amdgpu_waves_per_eu(1, 4)))
void pdhg_kernel(const float* __restrict__ P, const float* __restrict__ q,
                 const float* __restrict__ H, const float* __restrict__ b,
                 const float* __restrict__ cf, const int* __restrict__ itp,
                 float* __restrict__ out, int Btot) {
  __shared__ __align__(16) float sH[EPB * HS];
  __shared__ __align__(16) float sGi[EPB * GS];
  __shared__ __align__(16) float sB[EPB * SS];
  __shared__ __align__(16) float sAux[EPB * SS];

  const int tid  = threadIdx.x;
  const int wq   = tid >> 6;          // wave 0..3 — fully independent
  const int lane = tid & 63;
  const int e    = wq * 8 + (lane >> 3);
  const int t    = lane & 7;
  const int env  = blockIdx.x * EPB + e;
  const int envW0 = blockIdx.x * EPB + wq * 8;
  const int niter = itp[0];
  const int r0w = 3 * t;
  const int i1 = (t < 4) ? t + 8 : t;   // second owned row (safe alias for t>=4)

  // ---- PER-WAVE float4 staging of this wave's 8 envs: H, P, q, b ----
  {
    const float4* gH = (const float4*)(H + (size_t)envW0 * 288);
#pragma unroll
    for (int rep = 0; rep < 9; ++rep) {
      int i = lane + rep * 64;
      int ee = i / 72, off = i - ee * 72;
      *(float4*)&sH[(wq * 8 + ee) * HS + off * 4] = gH[i];
    }
    const float4* gP = (const float4*)(P + (size_t)envW0 * 144);
#pragma unroll
    for (int rep = 0; rep < 4; ++rep) {
      int i = lane + rep * 64;
      int ee = i / 36, off = i - ee * 36;
      *(float4*)&sGi[(wq * 8 + ee) * GS + off * 4] = gP[i];
    }
    { int i = lane + 256; if (lane < 32) {
        int ee = i / 36, off = i - ee * 36;
        *(float4*)&sGi[(wq * 8 + ee) * GS + off * 4] = gP[i]; } }
    const float4* gq = (const float4*)(q + (size_t)envW0 * 12);
    if (lane < 24) {
      int ee = lane / 3, off = lane - ee * 3;
      *(float4*)&sAux[(wq * 8 + ee) * SS + off * 4] = gq[lane];
    }
    const float4* gb = (const float4*)(b + (size_t)envW0 * 24);
    if (lane < 48) {
      int ee = lane / 6, off = lane - ee * 6;
      *(float4*)&sB[(wq * 8 + ee) * SS + off * 4] = gb[lane];
    }
  }
  WFENCE();

  const float* myH = &sH[e * HS];
  float* giB  = &sGi[e * GS];
  float* auxB = &sAux[e * SS];
  float* bBm  = &sB[e * SS];
  const float* bB = bBm;

  // ---- G = P + HtH in registers (rows t, i1); invert in place -------------
  float4 g0a, g0b, g0c, g1a, g1b, g1c;
  gram_rows(myH, t, i1, g0a, g0b, g0c, g1a, g1b, g1c);
  {
    const float4* p0 = (const float4*)(giB + t * 12);
    const float4* p1 = (const float4*)(giB + i1 * 12);
    float4 q0 = p0[0], q1 = p0[1], q2 = p0[2];
    float4 r0 = p1[0], r1 = p1[1], r2 = p1[2];
    ADD4(g0a, q0); ADD4(g0b, q1); ADD4(g0c, q2);
    ADD4(g1a, r0); ADD4(g1b, r1); ADD4(g1c, r2);
  }
  // pivot buffer: aux[12..23] (free until y is written)
  rgj_all<0>(g0a, g0b, g0c, g1a, g1b, g1c, auxB + 12, t);

  // ---- publish Ginv to LDS (overwrites staged P) + y = Ginv*q -------------
  {
    float4* w0 = (float4*)(giB + t * 12);
    w0[0] = g0a; w0[1] = g0b; w0[2] = g0c;
    if (t < 4) {
      float4* w1 = (float4*)(giB + (t + 8) * 12);
      w1[0] = g1a; w1[1] = g1b; w1[2] = g1c;
    }
  }
  float y0 = dot12(g0a, g0b, g0c, auxB);
  float y1 = dot12(g1a, g1b, g1c, auxB);
  WFENCE();
  auxB[12 + t] = y0;
  if (t < 4) auxB[20 + t] = y1;
  WFENCE();

  // ---- own H rows to regs; u = H*y (own rows) -----------------------------
  float4 hr0[3], hr1[3], hr2[3];
  { const float4* p = (const float4*)(myH + (r0w + 0) * 12); hr0[0]=p[0]; hr0[1]=p[1]; hr0[2]=p[2]; }
  { const float4* p = (const float4*)(myH + (r0w + 1) * 12); hr1[0]=p[0]; hr1[1]=p[1]; hr1[2]=p[2]; }
  { const float4* p = (const float4*)(myH + (r0w + 2) * 12); hr2[0]=p[0]; hr2[1]=p[1]; hr2[2]=p[2]; }
  float u0, u1, u2;
  {
    const float4* y4 = (const float4*)(auxB + 12);
    float4 ya = y4[0], yb = y4[1], yc = y4[2];
    u0 = 0.f; FMA4(u0, hr0[0], ya); FMA4(u0, hr0[1], yb); FMA4(u0, hr0[2], yc);
    u1 = 0.f; FMA4(u1, hr1[0], ya); FMA4(u1, hr1[1], yb); FMA4(u1, hr1[2], yc);
    u2 = 0.f; FMA4(u2, hr2[0], ya); FMA4(u2, hr2[1], yb); FMA4(u2, hr2[2], yc);
  }

  // ---- W[:,r] = Ginv * H[r,:] for the 3 own rows (Ginv rows read ONCE) ----
  float4 W0[3], W1[3], W2[3];
  W0[0] = make_float4(0.f,0.f,0.f,0.f); W0[1] = W0[0]; W0[2] = W0[0];
  W1[0] = W0[0]; W1[1] = W0[0]; W1[2] = W0[0];
  W2[0] = W0[0]; W2[1] = W0[0]; W2[2] = W0[0];
#define ACC_W(c, EX)                                                   \
  { const float4* g4 = (const float4*)(giB + (c) * 12);                \
    float4 r0 = g4[0], r1 = g4[1], r2 = g4[2];                         \
    float k0 = hr0[(c) >> 2].EX, k1 = hr1[(c) >> 2].EX, k2 = hr2[(c) >> 2].EX; \
    VFMA(W0[0], k0, r0); VFMA(W0[1], k0, r1); VFMA(W0[2], k0, r2);     \
    VFMA(W1[0], k1, r0); VFMA(W1[1], k1, r1); VFMA(W1[2], k1, r2);     \
    VFMA(W2[0], k2, r0); VFMA(W2[1], k2, r1); VFMA(W2[2], k2, r2); }
  ACC_W(0, x) ACC_W(1, y) ACC_W(2,  z) ACC_W(3,  w)
  ACC_W(4, x) ACC_W(5, y) ACC_W(6,  z) ACC_W(7,  w)
  ACC_W(8, x) ACC_W(9, y) ACC_W(10, z) ACC_W(11, w)
#undef ACC_W

  // ---- column-PERMUTED Fm rows (f2 column-pairs), one pass ---------------
  f2 pm0[12], pm1[12], pm2[12];
#define SL(g, k) slot3<g, k>(myH, t, W0, W1, W2, pm0, pm1, pm2);
  SL(0,0) SL(0,1) SL(0,2)  SL(1,0) SL(1,1) SL(1,2)
  SL(2,0) SL(2,1) SL(2,2)  SL(3,0) SL(3,1) SL(3,2)
  SL(4,0) SL(4,1) SL(4,2)  SL(5,0) SL(5,1) SL(5,2)
  SL(6,0) SL(6,1) SL(6,2)  SL(7,0) SL(7,1) SL(7,2)
#undef SL

  // ---- mu = H*y - Fm*b (b gathered permuted; bit-exact FMA4 order) --------
  float mu0, mu1, mu2;
  {
    float4 bg0 = make_float4(bgat<0>(bB,t),  bgat<1>(bB,t),  bgat<2>(bB,t),  bgat<3>(bB,t));
    float4 bg1 = make_float4(bgat<4>(bB,t),  bgat<5>(bB,t),  bgat<6>(bB,t),  bgat<7>(bB,t));
    float4 bg2 = make_float4(bgat<8>(bB,t),  bgat<9>(bB,t),  bgat<10>(bB,t), bgat<11>(bB,t));
    float4 bg3 = make_float4(bgat<12>(bB,t), bgat<13>(bB,t), bgat<14>(bB,t), bgat<15>(bB,t));
    float4 bg4 = make_float4(bgat<16>(bB,t), bgat<17>(bB,t), bgat<18>(bB,t), bgat<19>(bB,t));
    float4 bg5 = make_float4(bgat<20>(bB,t), bgat<21>(bB,t), bgat<22>(bB,t), bgat<23>(bB,t));
    float d0 = 0.f, d1 = 0.f, d2 = 0.f;
    FMA4(d0, PMQ(pm0,0), bg0); FMA4(d1, PMQ(pm1,0), bg0); FMA4(d2, PMQ(pm2,0), bg0);
    FMA4(d0, PMQ(pm0,1), bg1); FMA4(d1, PMQ(pm1,1), bg1); FMA4(d2, PMQ(pm2,1), bg1);
    FMA4(d0, PMQ(pm0,2), bg2); FMA4(d1, PMQ(pm1,2), bg2); FMA4(d2, PMQ(pm2,2), bg2);
    FMA4(d0, PMQ(pm0,3), bg3); FMA4(d1, PMQ(pm1,3), bg3); FMA4(d2, PMQ(pm2,3), bg3);
    FMA4(d0, PMQ(pm0,4), bg4); FMA4(d1, PMQ(pm1,4), bg4); FMA4(d2, PMQ(pm2,4), bg4);
    FMA4(d0, PMQ(pm0,5), bg5); FMA4(d1, PMQ(pm1,5), bg5); FMA4(d2, PMQ(pm2,5), bg5);
    mu0 = u0 - d0;
    mu1 = u1 - d1;
    mu2 = u2 - d2;
  }
  f2 cf01; float cf2v;
  cf01.x = cf[(size_t)env * 24 + r0w];
  cf01.y = cf[(size_t)env * 24 + r0w + 1];
  cf2v   = cf[(size_t)env * 24 + r0w + 2];

  // ---- iterations: 21-DPP (2-level QP3 ladder) + 36 pkfma (r3 core) + ----
  // ---- packed {row0,row1} tail / state, scalar row2 ----------------------
  const float phi  = (t < 4) ?  3.0e38f :  10.0f;
  const float pthr = (t < 4) ? 0.0f     : -3.0e38f;
  const f2 lo01 = {-phi, -phi};
  const f2 hi01 = { phi,  phi};
  f2 l01 = {0.f, 0.f}, z01 = {0.f, 0.f};
  float l2 = 0.f, z2 = 0.f;
#pragma unroll 2
  for (int it = 0; it < niter; ++it) {
    f2 s01 = l01 + z01;                 // v_pk_add_f32; s01 IS vp0 (no movs)
    float s2 = l2 + z2;
    float s0 = s01.x, s1 = s01.y;       // register halves, no extract cost
    // ---- gather ladder: 21 DPP, depth 2 (QP3 replaces XOR2∘XOR1 hop) ----
    float x1a = dppv<DPP_XOR1>(s0), x1b = dppv<DPP_XOR1>(s1), x1c = dppv<DPP_XOR1>(s2);
    float x2a = dppv<DPP_XOR2>(s0), x2b = dppv<DPP_XOR2>(s1), x2c = dppv<DPP_XOR2>(s2);
    float q3a = dppv<DPP_QP3>(s0),  q3b = dppv<DPP_QP3>(s1),  q3c = dppv<DPP_QP3>(s2);
    float h0a = dppv<DPP_HMIR>(s0), h0b = dppv<DPP_HMIR>(s1), h0c = dppv<DPP_HMIR>(s2);
    float h1a = dppv<DPP_HMIR>(x1a), h1b = dppv<DPP_HMIR>(x1b), h1c = dppv<DPP_HMIR>(x1c);
    float h2a = dppv<DPP_HMIR>(x2a), h2b = dppv<DPP_HMIR>(x2b), h2c = dppv<DPP_HMIR>(x2c);
    float h3a = dppv<DPP_HMIR>(q3a), h3b = dppv<DPP_HMIR>(q3b), h3c = dppv<DPP_HMIR>(q3c);
    // ---- r3 column-pair core: 36 pkfma, 6 independent chains ----
    f2 vp1 = {s2, x1a},  vp2 = {x1b, x1c}, vp3 = {x2a, x2b};
    f2 vp4 = {x2c, q3a}, vp5 = {q3b, q3c};
    f2 vp6 = {h0a, h0b}, vp7 = {h0c, h1a}, vp8 = {h1b, h1c};
    f2 vp9 = {h2a, h2b}, vp10 = {h2c, h3a}, vp11 = {h3b, h3c};
    f2 A0 = {mu0, 0.f}, A1 = {mu1, 0.f}, A2 = {mu2, 0.f};
    f2 B0 = {0.f, 0.f}, B1 = {0.f, 0.f}, B2 = {0.f, 0.f};
    A0 = pkfma(pm0[0], s01, A0); A1 = pkfma(pm1[0], s01, A1); A2 = pkfma(pm2[0], s01, A2);
    A0 = pkfma(pm0[1], vp1, A0); A1 = pkfma(pm1[1], vp1, A1); A2 = pkfma(pm2[1], vp1, A2);
    A0 = pkfma(pm0[2], vp2, A0); A1 = pkfma(pm1[2], vp2, A1); A2 = pkfma(pm2[2], vp2, A2);
    A0 = pkfma(pm0[3], vp3, A0); A1 = pkfma(pm1[3], vp3, A1); A2 = pkfma(pm2[3], vp3, A2);
    A0 = pkfma(pm0[4], vp4, A0); A1 = pkfma(pm1[4], vp4, A1); A2 = pkfma(pm2[4], vp4, A2);
    A0 = pkfma(pm0[5], vp5, A0); A1 = pkfma(pm1[5], vp5, A1); A2 = pkfma(pm2[5], vp5, A2);
    B0 = pkfma(pm0[6], vp6, B0); B1 = pkfma(pm1[6], vp6, B1); B2 = pkfma(pm2[6], vp6, B2);
    B0 = pkfma(pm0[7], vp7, B0); B1 = pkfma(pm1[7], vp7, B1); B2 = pkfma(pm2[7], vp7, B2);
    B0 = pkfma(pm0[8], vp8, B0); B1 = pkfma(pm1[8], vp8, B1); B2 = pkfma(pm2[8], vp8, B2);
    B0 = pkfma(pm0[9], vp9, B0); B1 = pkfma(pm1[9], vp9, B1); B2 = pkfma(pm2[9], vp9, B2);
    B0 = pkfma(pm0[10], vp10, B0); B1 = pkfma(pm1[10], vp10, B1); B2 = pkfma(pm2[10], vp10, B2);
    B0 = pkfma(pm0[11], vp11, B0); B1 = pkfma(pm1[11], vp11, B1); B2 = pkfma(pm2[11], vp11, B2);
    // ---- packed tail ----
    f2 C0 = A0 + B0, C1 = A1 + B1, C2 = A2 + B2;   // v_pk_add_f32
    f2 w01; float w2;
    w01.x = C0.x + C0.y;                // horizontal adds write pair halves
    w01.y = C1.x + C1.y;
    w2    = C2.x + C2.y;
    f2 zp01 = pkfma((f2){-2.f, -2.f}, w01, s01);
    float zp2 = fmaf(-2.0f, w2, s2);
    l01 = w01; l2 = w2;
    bool gt = zp2 > pthr;               // cone: gate on zp2>0; box: always true
    f2 c01 = __builtin_elementwise_min(__builtin_elementwise_max(zp01, lo01), hi01);
    float c2 = __builtin_amdgcn_fmed3f(zp2, -phi, phi);
    f2 m01 = c01 * cf01;                // v_pk_mul_f32
    float m2 = c2 * cf2v;
    z01.x = gt ? m01.x : 0.0f;
    z01.y = gt ? m01.y : 0.0f;
    z2    = gt ? m2    : 0.0f;
  }

  // ---- outputs: lz, then x = (HtH)^-1 Ht (z - b) --------------------------
  float* xout  = out;
  float* lzout = out + (size_t)Btot * 12;
  lzout[(size_t)env * 48 + r0w]          = l01.x;
  lzout[(size_t)env * 48 + r0w + 1]      = l01.y;
  lzout[(size_t)env * 48 + r0w + 2]      = l2;
  lzout[(size_t)env * 48 + 24 + r0w]     = z01.x;
  lzout[(size_t)env * 48 + 24 + r0w + 1] = z01.y;
  lzout[(size_t)env * 48 + 24 + r0w + 2] = z2;

  float bo0 = bB[r0w];
  float bo1 = bB[r0w + 1];
  float bo2 = bB[r0w + 2];
  WFENCE();
  auxB[r0w]     = z01.x - bo0;
  auxB[r0w + 1] = z01.y - bo1;
  auxB[r0w + 2] = z2    - bo2;
  WFENCE();

  // rv = Ht (z - b), both owned columns in one pass, vectorized aux reads
  float rv0 = 0.f, rv8 = 0.f;
  {
    const float4* a4 = (const float4*)auxB;
    float4 au0 = a4[0], au1 = a4[1], au2 = a4[2], au3 = a4[3], au4 = a4[4], au5 = a4[5];
#define RVS(k, AV) { rv0 = fmaf(myH[(k) * 12 + t],  (AV), rv0);   \
                     rv8 = fmaf(myH[(k) * 12 + i1], (AV), rv8); }
    RVS(0,  au0.x) RVS(1,  au0.y) RVS(2,  au0.z) RVS(3,  au0.w)
    RVS(4,  au1.x) RVS(5,  au1.y) RVS(6,  au1.z) RVS(7,  au1.w)
    RVS(8,  au2.x) RVS(9,  au2.y) RVS(10, au2.z) RVS(11, au2.w)
    RVS(12, au3.x) RVS(13, au3.y) RVS(14, au3.z) RVS(15, au3.w)
    RVS(16, au4.x) RVS(17, au4.y) RVS(18, au4.z) RVS(19, au4.w)
    RVS(20, au5.x) RVS(21, au5.y) RVS(22, au5.z) RVS(23, au5.w)
#undef RVS
  }

  // second Gram (no P) + register GJ; pivot buffer reuses sB[0..11]
  gram_rows(myH, t, i1, g0a, g0b, g0c, g1a, g1b, g1c);
  WFENCE();
  auxB[t] = rv0;
  if (t < 4) auxB[t + 8] = rv8;
  WFENCE();
  rgj_all<0>(g0a, g0b, g0c, g1a, g1b, g1c, bBm, t);

  xout[(size_t)env * 12 + t] = dot12(g0a, g0b, g0c, auxB);
  if (t < 4)
    xout[(size_t)env * 12 + t + 8] = dot12(g1a, g1b, g1c, auxB);
}

extern "C" void kernel_launch(void* const* d_in, const int* in_sizes, int n_in,
                              void* d_out, int out_size, void* d_ws, size_t ws_size,
                              hipStream_t stream) {
  const float* P  = (const float*)d_in[0];
  const float* q  = (const float*)d_in[1];
  const float* H  = (const float*)d_in[2];
  const float* b  = (const float*)d_in[3];
  const float* cf = (const float*)d_in[4];
  const int*   it = (const int*)d_in[5];
  float* out = (float*)d_out;
  const int B = in_sizes[1] / 12;       // q is [B,12]
  const int grid = B / EPB;             // 16384/32 = 512 blocks
  pdhg_kernel<<<grid, BLOCK, 0, stream>>>(P, q, H, b, cf, it, out, B);
}

// Round 8
// 140.040 us; speedup vs baseline: 1.3010x; 1.0204x over previous
//
#include <hip/hip_runtime.h>

#define EPB 32          // envs per block (8 per wave)
#define BLOCK 256       // 4 independent waves; env = 8 lanes, wave-internal
#define HS 292          // H LDS stride (288 + 4)
#define GS 148          // G/Ginv LDS stride (144 + 4)
#define SS 28           // b / aux stride (24 + 4)

#define WFENCE() __builtin_amdgcn_wave_barrier()   // compiler fence, 0 instr

#define DPP_XOR1 0xB1   // quad_perm [1,0,3,2]  : lane ^= 1
#define DPP_XOR2 0x4E   // quad_perm [2,3,0,1]  : lane ^= 2
#define DPP_QP3  0x1B   // quad_perm [3,2,1,0]  : lane ^= 3 (single hop)
#define DPP_HMIR 0x141  // row_half_mirror      : lane ^= 7 (within 8)

// gather slot-group g (0..7) holds the s-triple of lane (t ^ GMAP[g])
constexpr int GMAP[8] = {0, 1, 2, 3, 7, 6, 5, 4};

typedef float f2 __attribute__((ext_vector_type(2)));

__device__ __forceinline__ f2 pkfma(f2 a, f2 b, f2 c) {
  return __builtin_elementwise_fma(a, b, c);   // -> v_pk_fma_f32 on gfx950
}

// acc += dot(f4, s4)
#define FMA4(acc, f, s)                                         \
  acc = fmaf((f).x, (s).x,                                      \
        fmaf((f).y, (s).y,                                      \
        fmaf((f).z, (s).z,                                      \
        fmaf((f).w, (s).w, (acc)))))

// acc4 += s * v4
#define VFMA(acc, s, v)                                         \
  { (acc).x = fmaf((s), (v).x, (acc).x);                        \
    (acc).y = fmaf((s), (v).y, (acc).y);                        \
    (acc).z = fmaf((s), (v).z, (acc).z);                        \
    (acc).w = fmaf((s), (v).w, (acc).w); }

#define ADD4(A, B) { (A).x += (B).x; (A).y += (B).y; (A).z += (B).z; (A).w += (B).w; }

template<int CTRL>
__device__ __forceinline__ float dppv(float v) {
  return __int_as_float(__builtin_amdgcn_update_dpp(
      0, __float_as_int(v), CTRL, 0xF, 0xF, true));
}

template<int K>
__device__ __forceinline__ float getel(const float4& a, const float4& b, const float4& c) {
  if constexpr (K == 0) return a.x; else if constexpr (K == 1) return a.y;
  else if constexpr (K == 2) return a.z; else if constexpr (K == 3) return a.w;
  else if constexpr (K == 4) return b.x; else if constexpr (K == 5) return b.y;
  else if constexpr (K == 6) return b.z; else if constexpr (K == 7) return b.w;
  else if constexpr (K == 8) return c.x; else if constexpr (K == 9) return c.y;
  else if constexpr (K == 10) return c.z; else return c.w;
}
template<int K>
__device__ __forceinline__ void setel(float4& a, float4& b, float4& c, float v) {
  if constexpr (K == 0) a.x = v; else if constexpr (K == 1) a.y = v;
  else if constexpr (K == 2) a.z = v; else if constexpr (K == 3) a.w = v;
  else if constexpr (K == 4) b.x = v; else if constexpr (K == 5) b.y = v;
  else if constexpr (K == 6) b.z = v; else if constexpr (K == 7) b.w = v;
  else if constexpr (K == 8) c.x = v; else if constexpr (K == 9) c.y = v;
  else if constexpr (K == 10) c.z = v; else c.w = v;
}

// ---- pm pair layout (level-aligned pairs; see loop) -----------------------
// old slot (g,k) -> pair P, half h:
//   k<2 :      P = (g<4) ? g : g+2,            h = k
//   k==2:      P = g<2?4 : g<4?5 : g<6?10 :11, h = g&1
template<int g, int k>
struct PMap {
  static constexpr int P = (k < 2) ? ((g < 4) ? g : g + 2)
                                   : ((g < 2) ? 4 : (g < 4) ? 5 : (g < 6) ? 10 : 11);
  static constexpr int h = (k < 2) ? k : (g & 1);
};

// element of old slot S (0..23) from the pair-layout array — compile-time
template<int S>
__device__ __forceinline__ float pmel(const f2* pm) {
  constexpr int g = S / 3, k = S % 3;
  if constexpr (PMap<g, k>::h == 0) return pm[PMap<g, k>::P].x;
  else                              return pm[PMap<g, k>::P].y;
}
// float4 of old slots 4Q..4Q+3 — keeps mu bit-exact with round-3 order
#define PMQ(pm, Q) make_float4(pmel<4*(Q)>(pm), pmel<4*(Q)+1>(pm), \
                               pmel<4*(Q)+2>(pm), pmel<4*(Q)+3>(pm))

__device__ __forceinline__ float dot12(float4 a0, float4 a1, float4 a2,
                                       const float* p) {
  const float4* p4 = (const float4*)p;
  float4 b0 = p4[0], b1 = p4[1], b2 = p4[2];
  float acc = 0.f;
  FMA4(acc, a0, b0); FMA4(acc, a1, b1); FMA4(acc, a2, b2);
  return acc;
}

// ---- register-resident Gauss-Jordan (SPD, no pivoting) --------------------
template<int K>
__device__ __forceinline__ void pivot_pub(float4& a, float4& b, float4& c, float* piv) {
  float ip = 1.0f / getel<K>(a, b, c);
  setel<K>(a, b, c, 1.0f);
  a.x *= ip; a.y *= ip; a.z *= ip; a.w *= ip;
  b.x *= ip; b.y *= ip; b.z *= ip; b.w *= ip;
  c.x *= ip; c.y *= ip; c.z *= ip; c.w *= ip;
  float4* pv = (float4*)piv;
  pv[0] = a; pv[1] = b; pv[2] = c;
}

#define ELIM(f, A, B, C)                                              \
  { (A).x = fmaf(-(f), p0.x, (A).x); (A).y = fmaf(-(f), p0.y, (A).y); \
    (A).z = fmaf(-(f), p0.z, (A).z); (A).w = fmaf(-(f), p0.w, (A).w); \
    (B).x = fmaf(-(f), p1.x, (B).x); (B).y = fmaf(-(f), p1.y, (B).y); \
    (B).z = fmaf(-(f), p1.z, (B).z); (B).w = fmaf(-(f), p1.w, (B).w); \
    (C).x = fmaf(-(f), p2.x, (C).x); (C).y = fmaf(-(f), p2.y, (C).y); \
    (C).z = fmaf(-(f), p2.z, (C).z); (C).w = fmaf(-(f), p2.w, (C).w); }

template<int K>
__device__ __forceinline__ void rgj_step(float4& a0, float4& b0, float4& c0,
                                         float4& a1, float4& b1, float4& c1,
                                         float* piv, int t) {
  if constexpr (K < 8) {
    if (t == K) pivot_pub<K>(a0, b0, c0, piv);
  } else {
    if (t == K - 8) pivot_pub<K>(a1, b1, c1, piv);
  }
  WFENCE();
  const float4* pv = (const float4*)piv;
  float4 p0 = pv[0], p1 = pv[1], p2 = pv[2];
  {
    const bool own = (K < 8) && (t == K);
    float cur = getel<K>(a0, b0, c0);
    float f = own ? 0.0f : cur;
    setel<K>(a0, b0, c0, own ? cur : 0.0f);
    ELIM(f, a0, b0, c0);
  }
  {
    const bool own = (K >= 8) && (t == K - 8);
    float cur = getel<K>(a1, b1, c1);
    float f = own ? 0.0f : cur;
    setel<K>(a1, b1, c1, own ? cur : 0.0f);
    ELIM(f, a1, b1, c1);
  }
  WFENCE();
}

template<int K>
__device__ __forceinline__ void rgj_all(float4& a0, float4& b0, float4& c0,
                                        float4& a1, float4& b1, float4& c1,
                                        float* piv, int t) {
  rgj_step<K>(a0, b0, c0, a1, b1, c1, piv, t);
  if constexpr (K < 11) rgj_all<K + 1>(a0, b0, c0, a1, b1, c1, piv, t);
}

// ---- merged Gram rows (HtH) for rows t and i1, into registers -------------
__device__ __forceinline__ void gram_rows(const float* myH, int t, int i1,
    float4& a0, float4& b0, float4& c0, float4& a1, float4& b1, float4& c1) {
  a0 = make_float4(0.f, 0.f, 0.f, 0.f);
  b0 = a0; c0 = a0; a1 = a0; b1 = a0; c1 = a0;
#pragma unroll
  for (int k = 0; k < 24; ++k) {
    const float4* hk = (const float4*)(myH + k * 12);
    float4 h0 = hk[0], h1 = hk[1], h2 = hk[2];
    float f0 = myH[k * 12 + t];
    float f1 = myH[k * 12 + i1];
    VFMA(a0, f0, h0); VFMA(b0, f0, h1); VFMA(c0, f0, h2);
    VFMA(a1, f1, h0); VFMA(b1, f1, h1); VFMA(c1, f1, h2);
  }
}

// ---- one permuted Fm slot (all 3 rows at once, shared H[c] load) ----------
// Fm symmetric: Fm[r][c] = delta - <H[c,:], W[:,r]>, W[:,r] = Ginv * H[r,:].
// Writes into the pair layout via PMap.
template<int g, int k>
__device__ __forceinline__ void slot3(const float* myH, int t,
    const float4* W0, const float4* W1, const float4* W2,
    f2* P0, f2* P1, f2* P2) {
  const int c = 3 * (t ^ GMAP[g]) + k;
  const float4* hc = (const float4*)(myH + c * 12);
  float4 h0 = hc[0], h1 = hc[1], h2 = hc[2];
  float d0 = 0.f, d1 = 0.f, d2 = 0.f;
  FMA4(d0, h0, W0[0]); FMA4(d0, h1, W0[1]); FMA4(d0, h2, W0[2]);
  FMA4(d1, h0, W1[0]); FMA4(d1, h1, W1[1]); FMA4(d1, h2, W1[2]);
  FMA4(d2, h0, W2[0]); FMA4(d2, h1, W2[1]); FMA4(d2, h2, W2[2]);
  float v0 = ((g == 0 && k == 0) ? 1.0f : 0.0f) - d0;
  float v1 = ((g == 0 && k == 1) ? 1.0f : 0.0f) - d1;
  float v2 = ((g == 0 && k == 2) ? 1.0f : 0.0f) - d2;
  constexpr int P = PMap<g, k>::P;
  if constexpr (PMap<g, k>::h == 0) { P0[P].x = v0; P1[P].x = v1; P2[P].x = v2; }
  else                              { P0[P].y = v0; P1[P].y = v1; P2[P].y = v2; }
}

// b element in gather-permuted slot S
template<int S>
__device__ __forceinline__ float bgat(const float* bB, int t) {
  constexpr int g = S / 3, k = S % 3;
  return bB[3 * (t ^ GMAP[g]) + k];
}

__global__ __attribute__((amdgpu_flat_work_group_size(BLOCK, BLOCK),
                          amdgpu_waves_per_eu(1, 4)))
void pdhg_kernel(const float* __restrict__ P, const float* __restrict__ q,
                 const float* __restrict__ H, const float* __restrict__ b,
                 const float* __restrict__ cf, const int* __restrict__ itp,
                 float* __restrict__ out, int Btot) {
  __shared__ __align__(16) float sH[EPB * HS];
  __shared__ __align__(16) float sGi[EPB * GS];
  __shared__ __align__(16) float sB[EPB * SS];
  __shared__ __align__(16) float sAux[EPB * SS];

  const int tid  = threadIdx.x;
  const int wq   = tid >> 6;          // wave 0..3 — fully independent
  const int lane = tid & 63;
  const int e    = wq * 8 + (lane >> 3);
  const int t    = lane & 7;
  const int env  = blockIdx.x * EPB + e;
  const int envW0 = blockIdx.x * EPB + wq * 8;
  const int niter = itp[0];
  const int r0w = 3 * t;
  const int i1 = (t < 4) ? t + 8 : t;   // second owned row (safe alias for t>=4)

  // ---- PER-WAVE float4 staging of this wave's 8 envs: H, P, q, b ----
  {
    const float4* gH = (const float4*)(H + (size_t)envW0 * 288);
#pragma unroll
    for (int rep = 0; rep < 9; ++rep) {
      int i = lane + rep * 64;
      int ee = i / 72, off = i - ee * 72;
      *(float4*)&sH[(wq * 8 + ee) * HS + off * 4] = gH[i];
    }
    const float4* gP = (const float4*)(P + (size_t)envW0 * 144);
#pragma unroll
    for (int rep = 0; rep < 4; ++rep) {
      int i = lane + rep * 64;
      int ee = i / 36, off = i - ee * 36;
      *(float4*)&sGi[(wq * 8 + ee) * GS + off * 4] = gP[i];
    }
    { int i = lane + 256; if (lane < 32) {
        int ee = i / 36, off = i - ee * 36;
        *(float4*)&sGi[(wq * 8 + ee) * GS + off * 4] = gP[i]; } }
    const float4* gq = (const float4*)(q + (size_t)envW0 * 12);
    if (lane < 24) {
      int ee = lane / 3, off = lane - ee * 3;
      *(float4*)&sAux[(wq * 8 + ee) * SS + off * 4] = gq[lane];
    }
    const float4* gb = (const float4*)(b + (size_t)envW0 * 24);
    if (lane < 48) {
      int ee = lane / 6, off = lane - ee * 6;
      *(float4*)&sB[(wq * 8 + ee) * SS + off * 4] = gb[lane];
    }
  }
  WFENCE();

  const float* myH = &sH[e * HS];
  float* giB  = &sGi[e * GS];
  float* auxB = &sAux[e * SS];
  float* bBm  = &sB[e * SS];
  const float* bB = bBm;

  // ---- G = P + HtH in registers (rows t, i1); invert in place -------------
  float4 g0a, g0b, g0c, g1a, g1b, g1c;
  gram_rows(myH, t, i1, g0a, g0b, g0c, g1a, g1b, g1c);
  {
    const float4* p0 = (const float4*)(giB + t * 12);
    const float4* p1 = (const float4*)(giB + i1 * 12);
    float4 q0 = p0[0], q1 = p0[1], q2 = p0[2];
    float4 r0 = p1[0], r1 = p1[1], r2 = p1[2];
    ADD4(g0a, q0); ADD4(g0b, q1); ADD4(g0c, q2);
    ADD4(g1a, r0); ADD4(g1b, r1); ADD4(g1c, r2);
  }
  // pivot buffer: aux[12..23] (free until y is written)
  rgj_all<0>(g0a, g0b, g0c, g1a, g1b, g1c, auxB + 12, t);

  // ---- publish Ginv to LDS (overwrites staged P) + y = Ginv*q -------------
  {
    float4* w0 = (float4*)(giB + t * 12);
    w0[0] = g0a; w0[1] = g0b; w0[2] = g0c;
    if (t < 4) {
      float4* w1 = (float4*)(giB + (t + 8) * 12);
      w1[0] = g1a; w1[1] = g1b; w1[2] = g1c;
    }
  }
  float y0 = dot12(g0a, g0b, g0c, auxB);
  float y1 = dot12(g1a, g1b, g1c, auxB);
  WFENCE();
  auxB[12 + t] = y0;
  if (t < 4) auxB[20 + t] = y1;
  WFENCE();

  // ---- own H rows to regs; u = H*y (own rows) -----------------------------
  float4 hr0[3], hr1[3], hr2[3];
  { const float4* p = (const float4*)(myH + (r0w + 0) * 12); hr0[0]=p[0]; hr0[1]=p[1]; hr0[2]=p[2]; }
  { const float4* p = (const float4*)(myH + (r0w + 1) * 12); hr1[0]=p[0]; hr1[1]=p[1]; hr1[2]=p[2]; }
  { const float4* p = (const float4*)(myH + (r0w + 2) * 12); hr2[0]=p[0]; hr2[1]=p[1]; hr2[2]=p[2]; }
  float u0, u1, u2;
  {
    const float4* y4 = (const float4*)(auxB + 12);
    float4 ya = y4[0], yb = y4[1], yc = y4[2];
    u0 = 0.f; FMA4(u0, hr0[0], ya); FMA4(u0, hr0[1], yb); FMA4(u0, hr0[2], yc);
    u1 = 0.f; FMA4(u1, hr1[0], ya); FMA4(u1, hr1[1], yb); FMA4(u1, hr1[2], yc);
    u2 = 0.f; FMA4(u2, hr2[0], ya); FMA4(u2, hr2[1], yb); FMA4(u2, hr2[2], yc);
  }

  // ---- W[:,r] = Ginv * H[r,:] for the 3 own rows (Ginv rows read ONCE) ----
  float4 W0[3], W1[3], W2[3];
  W0[0] = make_float4(0.f,0.f,0.f,0.f); W0[1] = W0[0]; W0[2] = W0[0];
  W1[0] = W0[0]; W1[1] = W0[0]; W1[2] = W0[0];
  W2[0] = W0[0]; W2[1] = W0[0]; W2[2] = W0[0];
#define ACC_W(c, EX)                                                   \
  { const float4* g4 = (const float4*)(giB + (c) * 12);                \
    float4 r0 = g4[0], r1 = g4[1], r2 = g4[2];                         \
    float k0 = hr0[(c) >> 2].EX, k1 = hr1[(c) >> 2].EX, k2 = hr2[(c) >> 2].EX; \
    VFMA(W0[0], k0, r0); VFMA(W0[1], k0, r1); VFMA(W0[2], k0, r2);     \
    VFMA(W1[0], k1, r0); VFMA(W1[1], k1, r1); VFMA(W1[2], k1, r2);     \
    VFMA(W2[0], k2, r0); VFMA(W2[1], k2, r1); VFMA(W2[2], k2, r2); }
  ACC_W(0, x) ACC_W(1, y) ACC_W(2,  z) ACC_W(3,  w)
  ACC_W(4, x) ACC_W(5, y) ACC_W(6,  z) ACC_W(7,  w)
  ACC_W(8, x) ACC_W(9, y) ACC_W(10, z) ACC_W(11, w)
#undef ACC_W

  // ---- column-PERMUTED Fm rows (pair layout), one pass --------------------
  f2 pm0[12], pm1[12], pm2[12];
#define SL(g, k) slot3<g, k>(myH, t, W0, W1, W2, pm0, pm1, pm2);
  SL(0,0) SL(0,1) SL(0,2)  SL(1,0) SL(1,1) SL(1,2)
  SL(2,0) SL(2,1) SL(2,2)  SL(3,0) SL(3,1) SL(3,2)
  SL(4,0) SL(4,1) SL(4,2)  SL(5,0) SL(5,1) SL(5,2)
  SL(6,0) SL(6,1) SL(6,2)  SL(7,0) SL(7,1) SL(7,2)
#undef SL

  // ---- mu = H*y - Fm*b (b gathered permuted; bit-exact round-3 order) -----
  float mu0, mu1, mu2;
  {
    float4 bg0 = make_float4(bgat<0>(bB,t),  bgat<1>(bB,t),  bgat<2>(bB,t),  bgat<3>(bB,t));
    float4 bg1 = make_float4(bgat<4>(bB,t),  bgat<5>(bB,t),  bgat<6>(bB,t),  bgat<7>(bB,t));
    float4 bg2 = make_float4(bgat<8>(bB,t),  bgat<9>(bB,t),  bgat<10>(bB,t), bgat<11>(bB,t));
    float4 bg3 = make_float4(bgat<12>(bB,t), bgat<13>(bB,t), bgat<14>(bB,t), bgat<15>(bB,t));
    float4 bg4 = make_float4(bgat<16>(bB,t), bgat<17>(bB,t), bgat<18>(bB,t), bgat<19>(bB,t));
    float4 bg5 = make_float4(bgat<20>(bB,t), bgat<21>(bB,t), bgat<22>(bB,t), bgat<23>(bB,t));
    float d0 = 0.f, d1 = 0.f, d2 = 0.f;
    FMA4(d0, PMQ(pm0,0), bg0); FMA4(d1, PMQ(pm1,0), bg0); FMA4(d2, PMQ(pm2,0), bg0);
    FMA4(d0, PMQ(pm0,1), bg1); FMA4(d1, PMQ(pm1,1), bg1); FMA4(d2, PMQ(pm2,1), bg1);
    FMA4(d0, PMQ(pm0,2), bg2); FMA4(d1, PMQ(pm1,2), bg2); FMA4(d2, PMQ(pm2,2), bg2);
    FMA4(d0, PMQ(pm0,3), bg3); FMA4(d1, PMQ(pm1,3), bg3); FMA4(d2, PMQ(pm2,3), bg3);
    FMA4(d0, PMQ(pm0,4), bg4); FMA4(d1, PMQ(pm1,4), bg4); FMA4(d2, PMQ(pm2,4), bg4);
    FMA4(d0, PMQ(pm0,5), bg5); FMA4(d1, PMQ(pm1,5), bg5); FMA4(d2, PMQ(pm2,5), bg5);
    mu0 = u0 - d0;
    mu1 = u1 - d1;
    mu2 = u2 - d2;
  }
  float cfr0 = cf[(size_t)env * 24 + r0w];
  float cfr1 = cf[(size_t)env * 24 + r0w + 1];
  float cfr2 = cf[(size_t)env * 24 + r0w + 2];
  const f2 mu0p = {mu0, 0.f};
  const f2 mu1p = {mu1, 0.f};
  const f2 mu2p = {mu2, 0.f};

  // ---- iterations: 21 DPP (level-aligned pairs, zero pack-movs) + 36 pkfma
  const float plo  = (t < 4) ? -3.0e38f : -10.0f;
  const float phi  = (t < 4) ?  3.0e38f :  10.0f;
  const float pthr = (t < 4) ? 0.0f     : -3.0e38f;
  float l0 = 0.f, l1 = 0.f, l2 = 0.f, z0 = 0.f, z1 = 0.f, z2 = 0.f;
#pragma unroll 2
  for (int it = 0; it < niter; ++it) {
    f2 s01; s01.x = l0 + z0; s01.y = l1 + z1;
    float s2 = l2 + z2;
    // L1 pairs from {s0,s1}: each DPP writes its pair half directly
    f2 v1, v2, v3, v4, v5, v6, v7, v8, v9, v10, v11;
    v1.x = dppv<DPP_XOR1>(s01.x); v1.y = dppv<DPP_XOR1>(s01.y);   // {x1a,x1b}
    v2.x = dppv<DPP_XOR2>(s01.x); v2.y = dppv<DPP_XOR2>(s01.y);   // {x2a,x2b}
    v3.x = dppv<DPP_QP3>(s01.x);  v3.y = dppv<DPP_QP3>(s01.y);    // {q3a,q3b}
    v8.x = s2;                    v8.y = dppv<DPP_XOR1>(s2);      // {s2, x1c}
    v9.x = dppv<DPP_XOR2>(s2);    v9.y = dppv<DPP_QP3>(s2);       // {x2c,q3c}
    // L2 pairs: HMIR of L1
    v4.x = dppv<DPP_HMIR>(s01.x); v4.y = dppv<DPP_HMIR>(s01.y);   // {h0a,h0b}
    v5.x = dppv<DPP_HMIR>(v1.x);  v5.y = dppv<DPP_HMIR>(v1.y);    // {h1a,h1b}
    v6.x = dppv<DPP_HMIR>(v2.x);  v6.y = dppv<DPP_HMIR>(v2.y);    // {h2a,h2b}
    v7.x = dppv<DPP_HMIR>(v3.x);  v7.y = dppv<DPP_HMIR>(v3.y);    // {h3a,h3b}
    v10.x = dppv<DPP_HMIR>(v8.x); v10.y = dppv<DPP_HMIR>(v8.y);   // {h0c,h1c}
    v11.x = dppv<DPP_HMIR>(v9.x); v11.y = dppv<DPP_HMIR>(v9.y);   // {h2c,h3c}
    // 36 pkfma, 6 independent chains; A uses L1 pairs, B uses L2 pairs
    f2 A0 = mu0p, A1 = mu1p, A2 = mu2p;
    f2 B0 = {0.f, 0.f}, B1 = {0.f, 0.f}, B2 = {0.f, 0.f};
    A0 = pkfma(pm0[0], s01, A0); A1 = pkfma(pm1[0], s01, A1); A2 = pkfma(pm2[0], s01, A2);
    A0 = pkfma(pm0[1], v1,  A0); A1 = pkfma(pm1[1], v1,  A1); A2 = pkfma(pm2[1], v1,  A2);
    A0 = pkfma(pm0[2], v2,  A0); A1 = pkfma(pm1[2], v2,  A1); A2 = pkfma(pm2[2], v2,  A2);
    A0 = pkfma(pm0[3], v3,  A0); A1 = pkfma(pm1[3], v3,  A1); A2 = pkfma(pm2[3], v3,  A2);
    A0 = pkfma(pm0[4], v8,  A0); A1 = pkfma(pm1[4], v8,  A1); A2 = pkfma(pm2[4], v8,  A2);
    A0 = pkfma(pm0[5], v9,  A0); A1 = pkfma(pm1[5], v9,  A1); A2 = pkfma(pm2[5], v9,  A2);
    B0 = pkfma(pm0[6], v4,  B0); B1 = pkfma(pm1[6], v4,  B1); B2 = pkfma(pm2[6], v4,  B2);
    B0 = pkfma(pm0[7], v5,  B0); B1 = pkfma(pm1[7], v5,  B1); B2 = pkfma(pm2[7], v5,  B2);
    B0 = pkfma(pm0[8], v6,  B0); B1 = pkfma(pm1[8], v6,  B1); B2 = pkfma(pm2[8], v6,  B2);
    B0 = pkfma(pm0[9], v7,  B0); B1 = pkfma(pm1[9], v7,  B1); B2 = pkfma(pm2[9], v7,  B2);
    B0 = pkfma(pm0[10], v10, B0); B1 = pkfma(pm1[10], v10, B1); B2 = pkfma(pm2[10], v10, B2);
    B0 = pkfma(pm0[11], v11, B0); B1 = pkfma(pm1[11], v11, B1); B2 = pkfma(pm2[11], v11, B2);
    // ---- scalar tail (round-3 proven form) ----
    f2 C0 = A0 + B0, C1 = A1 + B1, C2 = A2 + B2;   // v_pk_add_f32
    float w0 = C0.x + C0.y, w1 = C1.x + C1.y, w2 = C2.x + C2.y;
    float zp0 = fmaf(-2.0f, w0, s01.x);
    float zp1 = fmaf(-2.0f, w1, s01.y);
    float zp2 = fmaf(-2.0f, w2, s2);
    l0 = w0; l1 = w1; l2 = w2;
    bool gt = zp2 > pthr;               // cone: gate on zp2>0; box: always true
    float e0 = gt ? cfr0 : 0.0f;
    float e1 = gt ? cfr1 : 0.0f;
    float e2 = gt ? cfr2 : 0.0f;
    z0 = __builtin_amdgcn_fmed3f(zp0, plo, phi) * e0;
    z1 = __builtin_amdgcn_fmed3f(zp1, plo, phi) * e1;
    z2 = __builtin_amdgcn_fmed3f(zp2, plo, phi) * e2;
  }

  // ---- outputs: lz, then x = (HtH)^-1 Ht (z - b) --------------------------
  float* xout  = out;
  float* lzout = out + (size_t)Btot * 12;
  lzout[(size_t)env * 48 + r0w]          = l0;
  lzout[(size_t)env * 48 + r0w + 1]      = l1;
  lzout[(size_t)env * 48 + r0w + 2]      = l2;
  lzout[(size_t)env * 48 + 24 + r0w]     = z0;
  lzout[(size_t)env * 48 + 24 + r0w + 1] = z1;
  lzout[(size_t)env * 48 + 24 + r0w + 2] = z2;

  float bo0 = bB[r0w];
  float bo1 = bB[r0w + 1];
  float bo2 = bB[r0w + 2];
  WFENCE();
  auxB[r0w]     = z0 - bo0;
  auxB[r0w + 1] = z1 - bo1;
  auxB[r0w + 2] = z2 - bo2;
  WFENCE();

  // rv = Ht (z - b), both owned columns in one pass, vectorized aux reads
  float rv0 = 0.f, rv8 = 0.f;
  {
    const float4* a4 = (const float4*)auxB;
    float4 au0 = a4[0], au1 = a4[1], au2 = a4[2], au3 = a4[3], au4 = a4[4], au5 = a4[5];
#define RVS(k, AV) { rv0 = fmaf(myH[(k) * 12 + t],  (AV), rv0);   \
                     rv8 = fmaf(myH[(k) * 12 + i1], (AV), rv8); }
    RVS(0,  au0.x) RVS(1,  au0.y) RVS(2,  au0.z) RVS(3,  au0.w)
    RVS(4,  au1.x) RVS(5,  au1.y) RVS(6,  au1.z) RVS(7,  au1.w)
    RVS(8,  au2.x) RVS(9,  au2.y) RVS(10, au2.z) RVS(11, au2.w)
    RVS(12, au3.x) RVS(13, au3.y) RVS(14, au3.z) RVS(15, au3.w)
    RVS(16, au4.x) RVS(17, au4.y) RVS(18, au4.z) RVS(19, au4.w)
    RVS(20, au5.x) RVS(21, au5.y) RVS(22, au5.z) RVS(23, au5.w)
#undef RVS
  }

  // second Gram (no P) + register GJ; pivot buffer reuses sB[0..11]
  gram_rows(myH, t, i1, g0a, g0b, g0c, g1a, g1b, g1c);
  WFENCE();
  auxB[t] = rv0;
  if (t < 4) auxB[t + 8] = rv8;
  WFENCE();
  rgj_all<0>(g0a, g0b, g0c, g1a, g1b, g1c, bBm, t);

  xout[(size_t)env * 12 + t] = dot12(g0a, g0b, g0c, auxB);
  if (t < 4)
    xout[(size_t)env * 12 + t + 8] = dot12(g1a, g1b, g1c, auxB);
}

extern "C" void kernel_launch(void* const* d_in, const int* in_sizes, int n_in,
                              void* d_out, int out_size, void* d_ws, size_t ws_size,
                              hipStream_t stream) {
  const float* P  = (const float*)d_in[0];
  const float* q  = (const float*)d_in[1];
  const float* H  = (const float*)d_in[2];
  const float* b  = (const float*)d_in[3];
  const float* cf = (const float*)d_in[4];
  const int*   it = (const int*)d_in[5];
  float* out = (float*)d_out;
  const int B = in_sizes[1] / 12;       // q is [B,12]
  const int grid = B / EPB;             // 16384/32 = 512 blocks
  pdhg_kernel<<<grid, BLOCK, 0, stream>>>(P, q, H, b, cf, it, out, B);
}

// Round 9
// 132.059 us; speedup vs baseline: 1.3796x; 1.0604x over previous
//
#include <hip/hip_runtime.h>

#define EPB 32          // envs per block (16 per wave, 4 lanes per env)
#define BLOCK 128       // 2 waves per block; 1 wave/SIMD at 2 blocks/CU
#define HS 292          // H LDS stride (288 + 4)
#define GS 148          // G/Ginv LDS stride (144 + 4)
#define SS 28           // b / aux stride (24 + 4)

#define WFENCE() __builtin_amdgcn_wave_barrier()   // compiler fence, 0 instr

#define DPP_XOR1 0xB1   // quad_perm [1,0,3,2]  : lane ^= 1
#define DPP_XOR2 0x4E   // quad_perm [2,3,0,1]  : lane ^= 2
#define DPP_QP3  0x1B   // quad_perm [3,2,1,0]  : lane ^= 3

typedef float f2 __attribute__((ext_vector_type(2)));

__device__ __forceinline__ f2 pkfma(f2 a, f2 b, f2 c) {
  return __builtin_elementwise_fma(a, b, c);   // -> v_pk_fma_f32 on gfx950
}

// acc += dot(f4, s4)
#define FMA4(acc, f, s)                                         \
  acc = fmaf((f).x, (s).x,                                      \
        fmaf((f).y, (s).y,                                      \
        fmaf((f).z, (s).z,                                      \
        fmaf((f).w, (s).w, (acc)))))

// acc4 += s * v4
#define VFMA(acc, s, v)                                         \
  { (acc).x = fmaf((s), (v).x, (acc).x);                        \
    (acc).y = fmaf((s), (v).y, (acc).y);                        \
    (acc).z = fmaf((s), (v).z, (acc).z);                        \
    (acc).w = fmaf((s), (v).w, (acc).w); }

#define ADD4(A, B) { (A).x += (B).x; (A).y += (B).y; (A).z += (B).z; (A).w += (B).w; }

template<int CTRL>
__device__ __forceinline__ float dppv(float v) {
  return __int_as_float(__builtin_amdgcn_update_dpp(
      0, __float_as_int(v), CTRL, 0xF, 0xF, true));
}

template<int K>
__device__ __forceinline__ float getel(const float4& a, const float4& b, const float4& c) {
  if constexpr (K == 0) return a.x; else if constexpr (K == 1) return a.y;
  else if constexpr (K == 2) return a.z; else if constexpr (K == 3) return a.w;
  else if constexpr (K == 4) return b.x; else if constexpr (K == 5) return b.y;
  else if constexpr (K == 6) return b.z; else if constexpr (K == 7) return b.w;
  else if constexpr (K == 8) return c.x; else if constexpr (K == 9) return c.y;
  else if constexpr (K == 10) return c.z; else return c.w;
}
template<int K>
__device__ __forceinline__ void setel(float4& a, float4& b, float4& c, float v) {
  if constexpr (K == 0) a.x = v; else if constexpr (K == 1) a.y = v;
  else if constexpr (K == 2) a.z = v; else if constexpr (K == 3) a.w = v;
  else if constexpr (K == 4) b.x = v; else if constexpr (K == 5) b.y = v;
  else if constexpr (K == 6) b.z = v; else if constexpr (K == 7) b.w = v;
  else if constexpr (K == 8) c.x = v; else if constexpr (K == 9) c.y = v;
  else if constexpr (K == 10) c.z = v; else c.w = v;
}

__device__ __forceinline__ float dot12(float4 a0, float4 a1, float4 a2,
                                       const float* p) {
  const float4* p4 = (const float4*)p;
  float4 b0 = p4[0], b1 = p4[1], b2 = p4[2];
  float acc = 0.f;
  FMA4(acc, a0, b0); FMA4(acc, a1, b1); FMA4(acc, a2, b2);
  return acc;
}

// ---- register-resident Gauss-Jordan, 3 row-sets per lane ------------------
// Lane t (0..3) owns rows t (set0), t+4 (set1), t+8 (set2).
template<int K>
__device__ __forceinline__ void pivot_pub(float4& a, float4& b, float4& c, float* piv) {
  float ip = 1.0f / getel<K>(a, b, c);
  setel<K>(a, b, c, 1.0f);
  a.x *= ip; a.y *= ip; a.z *= ip; a.w *= ip;
  b.x *= ip; b.y *= ip; b.z *= ip; b.w *= ip;
  c.x *= ip; c.y *= ip; c.z *= ip; c.w *= ip;
  float4* pv = (float4*)piv;
  pv[0] = a; pv[1] = b; pv[2] = c;
}

#define ELIM(f, A, B, C)                                              \
  { (A).x = fmaf(-(f), p0.x, (A).x); (A).y = fmaf(-(f), p0.y, (A).y); \
    (A).z = fmaf(-(f), p0.z, (A).z); (A).w = fmaf(-(f), p0.w, (A).w); \
    (B).x = fmaf(-(f), p1.x, (B).x); (B).y = fmaf(-(f), p1.y, (B).y); \
    (B).z = fmaf(-(f), p1.z, (B).z); (B).w = fmaf(-(f), p1.w, (B).w); \
    (C).x = fmaf(-(f), p2.x, (C).x); (C).y = fmaf(-(f), p2.y, (C).y); \
    (C).z = fmaf(-(f), p2.z, (C).z); (C).w = fmaf(-(f), p2.w, (C).w); }

template<int K>
__device__ __forceinline__ void rgj3_step(
    float4& a0, float4& b0, float4& c0,
    float4& a1, float4& b1, float4& c1,
    float4& a2, float4& b2, float4& c2,
    float* piv, int t) {
  constexpr int SET = K >> 2, OWN = K & 3;
  if (t == OWN) {
    if constexpr (SET == 0)      pivot_pub<K>(a0, b0, c0, piv);
    else if constexpr (SET == 1) pivot_pub<K>(a1, b1, c1, piv);
    else                         pivot_pub<K>(a2, b2, c2, piv);
  }
  WFENCE();
  const float4* pv = (const float4*)piv;
  float4 p0 = pv[0], p1 = pv[1], p2 = pv[2];
  {
    const bool own = (SET == 0) && (t == OWN);
    float cur = getel<K>(a0, b0, c0);
    float f = own ? 0.0f : cur;
    setel<K>(a0, b0, c0, own ? cur : 0.0f);
    ELIM(f, a0, b0, c0);
  }
  {
    const bool own = (SET == 1) && (t == OWN);
    float cur = getel<K>(a1, b1, c1);
    float f = own ? 0.0f : cur;
    setel<K>(a1, b1, c1, own ? cur : 0.0f);
    ELIM(f, a1, b1, c1);
  }
  {
    const bool own = (SET == 2) && (t == OWN);
    float cur = getel<K>(a2, b2, c2);
    float f = own ? 0.0f : cur;
    setel<K>(a2, b2, c2, own ? cur : 0.0f);
    ELIM(f, a2, b2, c2);
  }
  WFENCE();
}

template<int K>
__device__ __forceinline__ void rgj3_all(
    float4& a0, float4& b0, float4& c0,
    float4& a1, float4& b1, float4& c1,
    float4& a2, float4& b2, float4& c2,
    float* piv, int t) {
  rgj3_step<K>(a0, b0, c0, a1, b1, c1, a2, b2, c2, piv, t);
  if constexpr (K < 11) rgj3_all<K + 1>(a0, b0, c0, a1, b1, c1, a2, b2, c2, piv, t);
}

// ---- Gram rows (HtH) for rows t, t+4, t+8 ---------------------------------
__device__ __forceinline__ void gram3(const float* myH, int t,
    float4& a0, float4& b0, float4& c0,
    float4& a1, float4& b1, float4& c1,
    float4& a2, float4& b2, float4& c2) {
  a0 = make_float4(0.f, 0.f, 0.f, 0.f);
  b0 = a0; c0 = a0; a1 = a0; b1 = a0; c1 = a0; a2 = a0; b2 = a0; c2 = a0;
#pragma unroll
  for (int k = 0; k < 24; ++k) {
    const float4* hk = (const float4*)(myH + k * 12);
    float4 h0 = hk[0], h1 = hk[1], h2 = hk[2];
    float f0 = myH[k * 12 + t];
    float f1 = myH[k * 12 + t + 4];
    float f2v = myH[k * 12 + t + 8];
    VFMA(a0, f0, h0);  VFMA(b0, f0, h1);  VFMA(c0, f0, h2);
    VFMA(a1, f1, h0);  VFMA(b1, f1, h1);  VFMA(c1, f1, h2);
    VFMA(a2, f2v, h0); VFMA(b2, f2v, h1); VFMA(c2, f2v, h2);
  }
}

// ---- W = Ginv * H[r,:] for 3 consecutive own rows (coeffs read from LDS) --
__device__ __forceinline__ void buildW(const float* myH, const float* gi, int r0,
                                       float4* Wa, float4* Wb, float4* Wc) {
  Wa[0] = make_float4(0.f, 0.f, 0.f, 0.f); Wa[1] = Wa[0]; Wa[2] = Wa[0];
  Wb[0] = Wa[0]; Wb[1] = Wa[0]; Wb[2] = Wa[0];
  Wc[0] = Wa[0]; Wc[1] = Wa[0]; Wc[2] = Wa[0];
#pragma unroll
  for (int c = 0; c < 12; ++c) {
    const float4* g4 = (const float4*)(gi + c * 12);
    float4 r0v = g4[0], r1v = g4[1], r2v = g4[2];
    float k0 = myH[(r0 + 0) * 12 + c];
    float k1 = myH[(r0 + 1) * 12 + c];
    float k2 = myH[(r0 + 2) * 12 + c];
    VFMA(Wa[0], k0, r0v); VFMA(Wa[1], k0, r1v); VFMA(Wa[2], k0, r2v);
    VFMA(Wb[0], k1, r0v); VFMA(Wb[1], k1, r1v); VFMA(Wb[2], k1, r2v);
    VFMA(Wc[0], k2, r0v); VFMA(Wc[1], k2, r1v); VFMA(Wc[2], k2, r2v);
  }
}

// ---- one permuted Fm slot for 3 rows (base..base+2 of the lane's 6) -------
// Fm[r][c] = delta - <H[c,:], W[:,r]>. Slot (m,k): column c = 6*(t^m)+k.
// Pair layout: P = 3m + k/2, half = k&1 — pair halves share the DPP control.
template<int m, int k, int base>
__device__ __forceinline__ void slot4(const float* myH, int t,
    const float4* Wa, const float4* Wb, const float4* Wc,
    f2* pA, f2* pB, f2* pC) {
  const int c = 6 * (t ^ m) + k;
  const float4* hc = (const float4*)(myH + c * 12);
  float4 h0 = hc[0], h1 = hc[1], h2 = hc[2];
  float d0 = 0.f, d1 = 0.f, d2 = 0.f;
  FMA4(d0, h0, Wa[0]); FMA4(d0, h1, Wa[1]); FMA4(d0, h2, Wa[2]);
  FMA4(d1, h0, Wb[0]); FMA4(d1, h1, Wb[1]); FMA4(d1, h2, Wb[2]);
  FMA4(d2, h0, Wc[0]); FMA4(d2, h1, Wc[1]); FMA4(d2, h2, Wc[2]);
  float v0 = ((m == 0 && k == base + 0) ? 1.0f : 0.0f) - d0;
  float v1 = ((m == 0 && k == base + 1) ? 1.0f : 0.0f) - d1;
  float v2 = ((m == 0 && k == base + 2) ? 1.0f : 0.0f) - d2;
  constexpr int P = 3 * m + (k >> 1);
  if constexpr ((k & 1) == 0) { pA[P].x = v0; pB[P].x = v1; pC[P].x = v2; }
  else                        { pA[P].y = v0; pB[P].y = v1; pC[P].y = v2; }
}

#define SLOTS(base, pA, pB, pC)                                   \
  slot4<0,0,base>(myH,t,Wa,Wb,Wc,pA,pB,pC);                       \
  slot4<0,1,base>(myH,t,Wa,Wb,Wc,pA,pB,pC);                       \
  slot4<0,2,base>(myH,t,Wa,Wb,Wc,pA,pB,pC);                       \
  slot4<0,3,base>(myH,t,Wa,Wb,Wc,pA,pB,pC);                       \
  slot4<0,4,base>(myH,t,Wa,Wb,Wc,pA,pB,pC);                       \
  slot4<0,5,base>(myH,t,Wa,Wb,Wc,pA,pB,pC);                       \
  slot4<1,0,base>(myH,t,Wa,Wb,Wc,pA,pB,pC);                       \
  slot4<1,1,base>(myH,t,Wa,Wb,Wc,pA,pB,pC);                       \
  slot4<1,2,base>(myH,t,Wa,Wb,Wc,pA,pB,pC);                       \
  slot4<1,3,base>(myH,t,Wa,Wb,Wc,pA,pB,pC);                       \
  slot4<1,4,base>(myH,t,Wa,Wb,Wc,pA,pB,pC);                       \
  slot4<1,5,base>(myH,t,Wa,Wb,Wc,pA,pB,pC);                       \
  slot4<2,0,base>(myH,t,Wa,Wb,Wc,pA,pB,pC);                       \
  slot4<2,1,base>(myH,t,Wa,Wb,Wc,pA,pB,pC);                       \
  slot4<2,2,base>(myH,t,Wa,Wb,Wc,pA,pB,pC);                       \
  slot4<2,3,base>(myH,t,Wa,Wb,Wc,pA,pB,pC);                       \
  slot4<2,4,base>(myH,t,Wa,Wb,Wc,pA,pB,pC);                       \
  slot4<2,5,base>(myH,t,Wa,Wb,Wc,pA,pB,pC);                       \
  slot4<3,0,base>(myH,t,Wa,Wb,Wc,pA,pB,pC);                       \
  slot4<3,1,base>(myH,t,Wa,Wb,Wc,pA,pB,pC);                       \
  slot4<3,2,base>(myH,t,Wa,Wb,Wc,pA,pB,pC);                       \
  slot4<3,3,base>(myH,t,Wa,Wb,Wc,pA,pB,pC);                       \
  slot4<3,4,base>(myH,t,Wa,Wb,Wc,pA,pB,pC);                       \
  slot4<3,5,base>(myH,t,Wa,Wb,Wc,pA,pB,pC);

__global__ __attribute__((amdgpu_flat_work_group_size(BLOCK, BLOCK),
                          amdgpu_waves_per_eu(1, 4)))
void pdhg_kernel(const float* __restrict__ P, const float* __restrict__ q,
                 const float* __restrict__ H, const float* __restrict__ b,
                 const float* __restrict__ cf, const int* __restrict__ itp,
                 float* __restrict__ out, int Btot) {
  __shared__ __align__(16) float sH[EPB * HS];
  __shared__ __align__(16) float sGi[EPB * GS];
  __shared__ __align__(16) float sB[EPB * SS];
  __shared__ __align__(16) float sAux[EPB * SS];

  const int tid  = threadIdx.x;
  const int wq   = tid >> 6;          // wave 0..1 — fully independent
  const int lane = tid & 63;
  const int g16  = lane >> 2;         // 4-lane group 0..15
  const int t    = lane & 3;
  const int e    = wq * 16 + g16;     // block-local env
  const int env  = blockIdx.x * EPB + e;
  const int envW0 = blockIdx.x * EPB + wq * 16;
  const int niter = itp[0];
  const int r6 = 6 * t;               // first of this lane's 6 iteration rows

  // ---- PER-WAVE float4 staging of this wave's 16 envs: H, P, q, b ----
  {
    const float4* gH = (const float4*)(H + (size_t)envW0 * 288);
#pragma unroll
    for (int rep = 0; rep < 18; ++rep) {          // 16 envs * 72 f4 = 1152
      int i = lane + rep * 64;
      int ee = i / 72, off = i - ee * 72;
      *(float4*)&sH[(wq * 16 + ee) * HS + off * 4] = gH[i];
    }
    const float4* gP = (const float4*)(P + (size_t)envW0 * 144);
#pragma unroll
    for (int rep = 0; rep < 9; ++rep) {           // 16 envs * 36 f4 = 576
      int i = lane + rep * 64;
      int ee = i / 36, off = i - ee * 36;
      *(float4*)&sGi[(wq * 16 + ee) * GS + off * 4] = gP[i];
    }
    const float4* gq = (const float4*)(q + (size_t)envW0 * 12);
    if (lane < 48) {                              // 16 envs * 3 f4
      int ee = lane / 3, off = lane - ee * 3;
      *(float4*)&sAux[(wq * 16 + ee) * SS + off * 4] = gq[lane];
    }
    const float4* gb = (const float4*)(b + (size_t)envW0 * 24);
    {                                             // 16 envs * 6 f4 = 96
      int i = lane;
      int ee = i / 6, off = i - ee * 6;
      *(float4*)&sB[(wq * 16 + ee) * SS + off * 4] = gb[i];
      if (lane < 32) {
        i = lane + 64;
        ee = i / 6; off = i - ee * 6;
        *(float4*)&sB[(wq * 16 + ee) * SS + off * 4] = gb[i];
      }
    }
  }
  WFENCE();

  const float* myH = &sH[e * HS];
  float* giB  = &sGi[e * GS];
  float* auxB = &sAux[e * SS];
  float* bBm  = &sB[e * SS];
  const float* bB = bBm;

  // ---- G = P + HtH in registers (rows t, t+4, t+8); invert in place -------
  float4 a0, b0, c0, a1, b1, c1, a2, b2, c2;
  gram3(myH, t, a0, b0, c0, a1, b1, c1, a2, b2, c2);
  {
    const float4* p0 = (const float4*)(giB + t * 12);
    const float4* p1 = (const float4*)(giB + (t + 4) * 12);
    const float4* p2 = (const float4*)(giB + (t + 8) * 12);
    float4 q0 = p0[0], q1 = p0[1], q2 = p0[2];
    float4 r0 = p1[0], r1 = p1[1], r2 = p1[2];
    float4 s0 = p2[0], s1 = p2[1], s2 = p2[2];
    ADD4(a0, q0); ADD4(b0, q1); ADD4(c0, q2);
    ADD4(a1, r0); ADD4(b1, r1); ADD4(c1, r2);
    ADD4(a2, s0); ADD4(b2, s1); ADD4(c2, s2);
  }
  rgj3_all<0>(a0, b0, c0, a1, b1, c1, a2, b2, c2, auxB + 12, t);

  // ---- publish Ginv to LDS (overwrites staged P) + y = Ginv*q -------------
  {
    float4* w0 = (float4*)(giB + t * 12);        w0[0] = a0; w0[1] = b0; w0[2] = c0;
    float4* w1 = (float4*)(giB + (t + 4) * 12);  w1[0] = a1; w1[1] = b1; w1[2] = c1;
    float4* w2 = (float4*)(giB + (t + 8) * 12);  w2[0] = a2; w2[1] = b2; w2[2] = c2;
  }
  float y0 = dot12(a0, b0, c0, auxB);
  float y1 = dot12(a1, b1, c1, auxB);
  float y2 = dot12(a2, b2, c2, auxB);
  WFENCE();
  auxB[12 + t] = y0; auxB[16 + t] = y1; auxB[20 + t] = y2;
  WFENCE();

  // ---- u = H*y for the 6 own rows ----------------------------------------
  float u0, u1, u2, u3, u4, u5;
  {
    const float4* y4 = (const float4*)(auxB + 12);
    float4 ya = y4[0], yb = y4[1], yc = y4[2];
#define UROW(rr, dst) { const float4* hp = (const float4*)(myH + (r6 + (rr)) * 12); \
      float4 h0 = hp[0], h1 = hp[1], h2 = hp[2]; dst = 0.f;                         \
      FMA4(dst, h0, ya); FMA4(dst, h1, yb); FMA4(dst, h2, yc); }
    UROW(0, u0) UROW(1, u1) UROW(2, u2) UROW(3, u3) UROW(4, u4) UROW(5, u5)
#undef UROW
  }

  // ---- permuted Fm rows (6 rows x 12 col-pairs), two 3-row passes ---------
  f2 pm0_[12], pm1_[12], pm2_[12], pm3_[12], pm4_[12], pm5_[12];
  {
    float4 Wa[3], Wb[3], Wc[3];
    buildW(myH, giB, r6 + 0, Wa, Wb, Wc);
    SLOTS(0, pm0_, pm1_, pm2_)
    buildW(myH, giB, r6 + 3, Wa, Wb, Wc);
    SLOTS(3, pm3_, pm4_, pm5_)
  }

  // ---- mu = H*y - Fm*b (b gathered in the same pair order) ----------------
  float mu0, mu1, mu2, mu3, mu4, mu5;
  {
    const int cA = 6 * (t ^ 1), cB = 6 * (t ^ 2), cC = 6 * (t ^ 3);
    f2 bq0 = { bB[r6 + 0], bB[r6 + 1] };
    f2 bq1 = { bB[r6 + 2], bB[r6 + 3] };
    f2 bq2 = { bB[r6 + 4], bB[r6 + 5] };
    f2 bq3 = { bB[cA + 0], bB[cA + 1] };
    f2 bq4 = { bB[cA + 2], bB[cA + 3] };
    f2 bq5 = { bB[cA + 4], bB[cA + 5] };
    f2 bq6 = { bB[cB + 0], bB[cB + 1] };
    f2 bq7 = { bB[cB + 2], bB[cB + 3] };
    f2 bq8 = { bB[cB + 4], bB[cB + 5] };
    f2 bq9 = { bB[cC + 0], bB[cC + 1] };
    f2 bq10 = { bB[cC + 2], bB[cC + 3] };
    f2 bq11 = { bB[cC + 4], bB[cC + 5] };
#define MUROW(rr, uu) {                                              \
    f2 S1 = {0.f, 0.f}, S2 = {0.f, 0.f};                             \
    S1 = pkfma(pm##rr##_[0], bq0, S1);                               \
    S1 = pkfma(pm##rr##_[1], bq1, S1);                               \
    S1 = pkfma(pm##rr##_[2], bq2, S1);                               \
    S1 = pkfma(pm##rr##_[3], bq3, S1);                               \
    S1 = pkfma(pm##rr##_[4], bq4, S1);                               \
    S1 = pkfma(pm##rr##_[5], bq5, S1);                               \
    S2 = pkfma(pm##rr##_[6], bq6, S2);                               \
    S2 = pkfma(pm##rr##_[7], bq7, S2);                               \
    S2 = pkfma(pm##rr##_[8], bq8, S2);                               \
    S2 = pkfma(pm##rr##_[9], bq9, S2);                               \
    S2 = pkfma(pm##rr##_[10], bq10, S2);                             \
    S2 = pkfma(pm##rr##_[11], bq11, S2);                             \
    f2 St = S1 + S2;                                                 \
    mu##rr = (uu) - (St.x + St.y); }
    MUROW(0, u0) MUROW(1, u1) MUROW(2, u2)
    MUROW(3, u3) MUROW(4, u4) MUROW(5, u5)
#undef MUROW
  }
  const float* cfp = cf + (size_t)env * 24 + r6;
  float cfv0 = cfp[0], cfv1 = cfp[1], cfv2 = cfp[2];
  float cfv3 = cfp[3], cfv4 = cfp[4], cfv5 = cfp[5];

  // ---- iterations: 18 depth-1 DPP + 72 pkfma (6 rows x 12 pairs) ----------
  // Lane t<2: rows 0..11 = cones (two 3-row cones per lane, gate rows 2,5).
  // Lane t>=2: rows 12..23 = box (clamp +-10, gate always).
  const float plo  = (t < 2) ? -3.0e38f : -10.0f;
  const float phi  = (t < 2) ?  3.0e38f :  10.0f;
  const float pthr = (t < 2) ? 0.0f     : -3.0e38f;
  float l0 = 0.f, l1 = 0.f, l2 = 0.f, l3 = 0.f, l4 = 0.f, l5 = 0.f;
  float z0 = 0.f, z1 = 0.f, z2 = 0.f, z3 = 0.f, z4 = 0.f, z5 = 0.f;
#pragma unroll 2
  for (int it = 0; it < niter; ++it) {
    f2 q0, q1, q2;                       // own s pairs (pair indices 0..2)
    q0.x = l0 + z0; q0.y = l1 + z1;
    q1.x = l2 + z2; q1.y = l3 + z3;
    q2.x = l4 + z4; q2.y = l5 + z5;
    // 18 DPPs, all depth-1, pair halves share the control (mov-free)
    f2 q3, q4, q5, q6, q7, q8, q9, q10, q11;
    q3.x = dppv<DPP_XOR1>(q0.x);  q3.y = dppv<DPP_XOR1>(q0.y);
    q4.x = dppv<DPP_XOR1>(q1.x);  q4.y = dppv<DPP_XOR1>(q1.y);
    q5.x = dppv<DPP_XOR1>(q2.x);  q5.y = dppv<DPP_XOR1>(q2.y);
    q6.x = dppv<DPP_XOR2>(q0.x);  q6.y = dppv<DPP_XOR2>(q0.y);
    q7.x = dppv<DPP_XOR2>(q1.x);  q7.y = dppv<DPP_XOR2>(q1.y);
    q8.x = dppv<DPP_XOR2>(q2.x);  q8.y = dppv<DPP_XOR2>(q2.y);
    q9.x = dppv<DPP_QP3>(q0.x);   q9.y = dppv<DPP_QP3>(q0.y);
    q10.x = dppv<DPP_QP3>(q1.x);  q10.y = dppv<DPP_QP3>(q1.y);
    q11.x = dppv<DPP_QP3>(q2.x);  q11.y = dppv<DPP_QP3>(q2.y);
    // 72 pkfma: per row two independent 6-chains
#define FMAROW(rr, wdst) {                                           \
    f2 A = { mu##rr, 0.f };                                          \
    f2 Bv = { 0.f, 0.f };                                            \
    A = pkfma(pm##rr##_[0], q0, A);                                  \
    A = pkfma(pm##rr##_[1], q1, A);                                  \
    A = pkfma(pm##rr##_[2], q2, A);                                  \
    A = pkfma(pm##rr##_[3], q3, A);                                  \
    A = pkfma(pm##rr##_[4], q4, A);                                  \
    A = pkfma(pm##rr##_[5], q5, A);                                  \
    Bv = pkfma(pm##rr##_[6], q6, Bv);                                \
    Bv = pkfma(pm##rr##_[7], q7, Bv);                                \
    Bv = pkfma(pm##rr##_[8], q8, Bv);                                \
    Bv = pkfma(pm##rr##_[9], q9, Bv);                                \
    Bv = pkfma(pm##rr##_[10], q10, Bv);                              \
    Bv = pkfma(pm##rr##_[11], q11, Bv);                              \
    f2 C = A + Bv;                                                   \
    wdst = C.x + C.y; }
    float w0, w1, w2, w3, w4, w5;
    FMAROW(0, w0) FMAROW(1, w1) FMAROW(2, w2)
    FMAROW(3, w3) FMAROW(4, w4) FMAROW(5, w5)
#undef FMAROW
    float zp0 = fmaf(-2.0f, w0, q0.x);
    float zp1 = fmaf(-2.0f, w1, q0.y);
    float zp2 = fmaf(-2.0f, w2, q1.x);
    float zp3 = fmaf(-2.0f, w3, q1.y);
    float zp4 = fmaf(-2.0f, w4, q2.x);
    float zp5 = fmaf(-2.0f, w5, q2.y);
    l0 = w0; l1 = w1; l2 = w2; l3 = w3; l4 = w4; l5 = w5;
    bool gA = zp2 > pthr;               // cone 0 gate (rows 0-2) / box: true
    bool gB = zp5 > pthr;               // cone 1 gate (rows 3-5) / box: true
    float e0 = gA ? cfv0 : 0.0f;
    float e1 = gA ? cfv1 : 0.0f;
    float e2 = gA ? cfv2 : 0.0f;
    float e3 = gB ? cfv3 : 0.0f;
    float e4 = gB ? cfv4 : 0.0f;
    float e5 = gB ? cfv5 : 0.0f;
    z0 = __builtin_amdgcn_fmed3f(zp0, plo, phi) * e0;
    z1 = __builtin_amdgcn_fmed3f(zp1, plo, phi) * e1;
    z2 = __builtin_amdgcn_fmed3f(zp2, plo, phi) * e2;
    z3 = __builtin_amdgcn_fmed3f(zp3, plo, phi) * e3;
    z4 = __builtin_amdgcn_fmed3f(zp4, plo, phi) * e4;
    z5 = __builtin_amdgcn_fmed3f(zp5, plo, phi) * e5;
  }

  // ---- outputs: lz, then x = (HtH)^-1 Ht (z - b) --------------------------
  float* xout  = out;
  float* lzout = out + (size_t)Btot * 12;
  {
    size_t base = (size_t)env * 48 + r6;
    lzout[base + 0] = l0; lzout[base + 1] = l1; lzout[base + 2] = l2;
    lzout[base + 3] = l3; lzout[base + 4] = l4; lzout[base + 5] = l5;
    lzout[base + 24 + 0] = z0; lzout[base + 24 + 1] = z1; lzout[base + 24 + 2] = z2;
    lzout[base + 24 + 3] = z3; lzout[base + 24 + 4] = z4; lzout[base + 24 + 5] = z5;
  }

  float bo0 = bB[r6 + 0], bo1 = bB[r6 + 1], bo2 = bB[r6 + 2];
  float bo3 = bB[r6 + 3], bo4 = bB[r6 + 4], bo5 = bB[r6 + 5];
  WFENCE();
  auxB[r6 + 0] = z0 - bo0; auxB[r6 + 1] = z1 - bo1; auxB[r6 + 2] = z2 - bo2;
  auxB[r6 + 3] = z3 - bo3; auxB[r6 + 4] = z4 - bo4; auxB[r6 + 5] = z5 - bo5;
  WFENCE();

  // rv = Ht (z - b), three owned columns in one pass
  float rv0 = 0.f, rv1 = 0.f, rv2 = 0.f;
  {
    const float4* a4 = (const float4*)auxB;
    float4 au0 = a4[0], au1 = a4[1], au2 = a4[2], au3 = a4[3], au4 = a4[4], au5 = a4[5];
#define RVS(k, AV) { rv0 = fmaf(myH[(k) * 12 + t],     (AV), rv0);  \
                     rv1 = fmaf(myH[(k) * 12 + t + 4], (AV), rv1);  \
                     rv2 = fmaf(myH[(k) * 12 + t + 8], (AV), rv2); }
    RVS(0,  au0.x) RVS(1,  au0.y) RVS(2,  au0.z) RVS(3,  au0.w)
    RVS(4,  au1.x) RVS(5,  au1.y) RVS(6,  au1.z) RVS(7,  au1.w)
    RVS(8,  au2.x) RVS(9,  au2.y) RVS(10, au2.z) RVS(11, au2.w)
    RVS(12, au3.x) RVS(13, au3.y) RVS(14, au3.z) RVS(15, au3.w)
    RVS(16, au4.x) RVS(17, au4.y) RVS(18, au4.z) RVS(19, au4.w)
    RVS(20, au5.x) RVS(21, au5.y) RVS(22, au5.z) RVS(23, au5.w)
#undef RVS
  }

  // second Gram (no P) + register GJ; pivot buffer reuses sB[0..11]
  gram3(myH, t, a0, b0, c0, a1, b1, c1, a2, b2, c2);
  WFENCE();
  auxB[t] = rv0; auxB[t + 4] = rv1; auxB[t + 8] = rv2;
  WFENCE();
  rgj3_all<0>(a0, b0, c0, a1, b1, c1, a2, b2, c2, bBm, t);

  xout[(size_t)env * 12 + t]     = dot12(a0, b0, c0, auxB);
  xout[(size_t)env * 12 + t + 4] = dot12(a1, b1, c1, auxB);
  xout[(size_t)env * 12 + t + 8] = dot12(a2, b2, c2, auxB);
}

extern "C" void kernel_launch(void* const* d_in, const int* in_sizes, int n_in,
                              void* d_out, int out_size, void* d_ws, size_t ws_size,
                              hipStream_t stream) {
  const float* P  = (const float*)d_in[0];
  const float* q  = (const float*)d_in[1];
  const float* H  = (const float*)d_in[2];
  const float* b  = (const float*)d_in[3];
  const float* cf = (const float*)d_in[4];
  const int*   it = (const int*)d_in[5];
  float* out = (float*)d_out;
  const int B = in_sizes[1] / 12;       // q is [B,12]
  const int grid = B / EPB;             // 16384/32 = 512 blocks
  pdhg_kernel<<<grid, BLOCK, 0, stream>>>(P, q, H, b, cf, it, out, B);
}

// Round 10
// 129.454 us; speedup vs baseline: 1.4073x; 1.0201x over previous
//
#include <hip/hip_runtime.h>

#define EPB 32          // envs per block (16 per wave, 4 lanes per env)
#define BLOCK 128       // 2 waves per block; 1 wave/SIMD at 2 blocks/CU
#define HS 292          // H LDS stride (288 + 4)
#define GS 148          // G/Ginv LDS stride (144 + 4)
#define SS 28           // b / aux stride (24 + 4)

#define WFENCE() __builtin_amdgcn_wave_barrier()   // compiler fence, 0 instr

#define DPP_XOR1 0xB1   // quad_perm [1,0,3,2]  : lane ^= 1
#define DPP_XOR2 0x4E   // quad_perm [2,3,0,1]  : lane ^= 2
#define DPP_QP3  0x1B   // quad_perm [3,2,1,0]  : lane ^= 3

typedef float f2 __attribute__((ext_vector_type(2)));

__device__ __forceinline__ f2 pkfma(f2 a, f2 b, f2 c) {
  return __builtin_elementwise_fma(a, b, c);   // -> v_pk_fma_f32 on gfx950
}

// acc += dot(f4, s4)
#define FMA4(acc, f, s)                                         \
  acc = fmaf((f).x, (s).x,                                      \
        fmaf((f).y, (s).y,                                      \
        fmaf((f).z, (s).z,                                      \
        fmaf((f).w, (s).w, (acc)))))

// acc4 += s * v4
#define VFMA(acc, s, v)                                         \
  { (acc).x = fmaf((s), (v).x, (acc).x);                        \
    (acc).y = fmaf((s), (v).y, (acc).y);                        \
    (acc).z = fmaf((s), (v).z, (acc).z);                        \
    (acc).w = fmaf((s), (v).w, (acc).w); }

#define ADD4(A, B) { (A).x += (B).x; (A).y += (B).y; (A).z += (B).z; (A).w += (B).w; }

template<int CTRL>
__device__ __forceinline__ float dppv(float v) {
  return __int_as_float(__builtin_amdgcn_update_dpp(
      0, __float_as_int(v), CTRL, 0xF, 0xF, true));
}

template<int K>
__device__ __forceinline__ float getel(const float4& a, const float4& b, const float4& c) {
  if constexpr (K == 0) return a.x; else if constexpr (K == 1) return a.y;
  else if constexpr (K == 2) return a.z; else if constexpr (K == 3) return a.w;
  else if constexpr (K == 4) return b.x; else if constexpr (K == 5) return b.y;
  else if constexpr (K == 6) return b.z; else if constexpr (K == 7) return b.w;
  else if constexpr (K == 8) return c.x; else if constexpr (K == 9) return c.y;
  else if constexpr (K == 10) return c.z; else return c.w;
}
template<int K>
__device__ __forceinline__ void setel(float4& a, float4& b, float4& c, float v) {
  if constexpr (K == 0) a.x = v; else if constexpr (K == 1) a.y = v;
  else if constexpr (K == 2) a.z = v; else if constexpr (K == 3) a.w = v;
  else if constexpr (K == 4) b.x = v; else if constexpr (K == 5) b.y = v;
  else if constexpr (K == 6) b.z = v; else if constexpr (K == 7) b.w = v;
  else if constexpr (K == 8) c.x = v; else if constexpr (K == 9) c.y = v;
  else if constexpr (K == 10) c.z = v; else c.w = v;
}

__device__ __forceinline__ float dot12(float4 a0, float4 a1, float4 a2,
                                       const float* p) {
  const float4* p4 = (const float4*)p;
  float4 b0 = p4[0], b1 = p4[1], b2 = p4[2];
  float acc = 0.f;
  FMA4(acc, a0, b0); FMA4(acc, a1, b1); FMA4(acc, a2, b2);
  return acc;
}

// ---- register-resident Gauss-Jordan, 3 row-sets per lane ------------------
// Lane t (0..3) owns rows t (set0), t+4 (set1), t+8 (set2).
template<int K>
__device__ __forceinline__ void pivot_pub(float4& a, float4& b, float4& c, float* piv) {
  float ip = 1.0f / getel<K>(a, b, c);
  setel<K>(a, b, c, 1.0f);
  a.x *= ip; a.y *= ip; a.z *= ip; a.w *= ip;
  b.x *= ip; b.y *= ip; b.z *= ip; b.w *= ip;
  c.x *= ip; c.y *= ip; c.z *= ip; c.w *= ip;
  float4* pv = (float4*)piv;
  pv[0] = a; pv[1] = b; pv[2] = c;
}

#define ELIM(f, A, B, C)                                              \
  { (A).x = fmaf(-(f), p0.x, (A).x); (A).y = fmaf(-(f), p0.y, (A).y); \
    (A).z = fmaf(-(f), p0.z, (A).z); (A).w = fmaf(-(f), p0.w, (A).w); \
    (B).x = fmaf(-(f), p1.x, (B).x); (B).y = fmaf(-(f), p1.y, (B).y); \
    (B).z = fmaf(-(f), p1.z, (B).z); (B).w = fmaf(-(f), p1.w, (B).w); \
    (C).x = fmaf(-(f), p2.x, (C).x); (C).y = fmaf(-(f), p2.y, (C).y); \
    (C).z = fmaf(-(f), p2.z, (C).z); (C).w = fmaf(-(f), p2.w, (C).w); }

template<int K>
__device__ __forceinline__ void rgj3_step(
    float4& a0, float4& b0, float4& c0,
    float4& a1, float4& b1, float4& c1,
    float4& a2, float4& b2, float4& c2,
    float* piv, int t) {
  constexpr int SET = K >> 2, OWN = K & 3;
  if (t == OWN) {
    if constexpr (SET == 0)      pivot_pub<K>(a0, b0, c0, piv);
    else if constexpr (SET == 1) pivot_pub<K>(a1, b1, c1, piv);
    else                         pivot_pub<K>(a2, b2, c2, piv);
  }
  WFENCE();
  const float4* pv = (const float4*)piv;
  float4 p0 = pv[0], p1 = pv[1], p2 = pv[2];
  {
    const bool own = (SET == 0) && (t == OWN);
    float cur = getel<K>(a0, b0, c0);
    float f = own ? 0.0f : cur;
    setel<K>(a0, b0, c0, own ? cur : 0.0f);
    ELIM(f, a0, b0, c0);
  }
  {
    const bool own = (SET == 1) && (t == OWN);
    float cur = getel<K>(a1, b1, c1);
    float f = own ? 0.0f : cur;
    setel<K>(a1, b1, c1, own ? cur : 0.0f);
    ELIM(f, a1, b1, c1);
  }
  {
    const bool own = (SET == 2) && (t == OWN);
    float cur = getel<K>(a2, b2, c2);
    float f = own ? 0.0f : cur;
    setel<K>(a2, b2, c2, own ? cur : 0.0f);
    ELIM(f, a2, b2, c2);
  }
  WFENCE();
}

template<int K>
__device__ __forceinline__ void rgj3_all(
    float4& a0, float4& b0, float4& c0,
    float4& a1, float4& b1, float4& c1,
    float4& a2, float4& b2, float4& c2,
    float* piv, int t) {
  rgj3_step<K>(a0, b0, c0, a1, b1, c1, a2, b2, c2, piv, t);
  if constexpr (K < 11) rgj3_all<K + 1>(a0, b0, c0, a1, b1, c1, a2, b2, c2, piv, t);
}

// ---- Gram rows (HtH) for rows t, t+4, t+8 ---------------------------------
__device__ __forceinline__ void gram3(const float* myH, int t,
    float4& a0, float4& b0, float4& c0,
    float4& a1, float4& b1, float4& c1,
    float4& a2, float4& b2, float4& c2) {
  a0 = make_float4(0.f, 0.f, 0.f, 0.f);
  b0 = a0; c0 = a0; a1 = a0; b1 = a0; c1 = a0; a2 = a0; b2 = a0; c2 = a0;
#pragma unroll
  for (int k = 0; k < 24; ++k) {
    const float4* hk = (const float4*)(myH + k * 12);
    float4 h0 = hk[0], h1 = hk[1], h2 = hk[2];
    float f0 = myH[k * 12 + t];
    float f1 = myH[k * 12 + t + 4];
    float f2v = myH[k * 12 + t + 8];
    VFMA(a0, f0, h0);  VFMA(b0, f0, h1);  VFMA(c0, f0, h2);
    VFMA(a1, f1, h0);  VFMA(b1, f1, h1);  VFMA(c1, f1, h2);
    VFMA(a2, f2v, h0); VFMA(b2, f2v, h1); VFMA(c2, f2v, h2);
  }
}

// ---- W = Ginv * H[r,:] for 3 consecutive own rows (coeffs read from LDS) --
__device__ __forceinline__ void buildW(const float* myH, const float* gi, int r0,
                                       float4* Wa, float4* Wb, float4* Wc) {
  Wa[0] = make_float4(0.f, 0.f, 0.f, 0.f); Wa[1] = Wa[0]; Wa[2] = Wa[0];
  Wb[0] = Wa[0]; Wb[1] = Wa[0]; Wb[2] = Wa[0];
  Wc[0] = Wa[0]; Wc[1] = Wa[0]; Wc[2] = Wa[0];
#pragma unroll
  for (int c = 0; c < 12; ++c) {
    const float4* g4 = (const float4*)(gi + c * 12);
    float4 r0v = g4[0], r1v = g4[1], r2v = g4[2];
    float k0 = myH[(r0 + 0) * 12 + c];
    float k1 = myH[(r0 + 1) * 12 + c];
    float k2 = myH[(r0 + 2) * 12 + c];
    VFMA(Wa[0], k0, r0v); VFMA(Wa[1], k0, r1v); VFMA(Wa[2], k0, r2v);
    VFMA(Wb[0], k1, r0v); VFMA(Wb[1], k1, r1v); VFMA(Wb[2], k1, r2v);
    VFMA(Wc[0], k2, r0v); VFMA(Wc[1], k2, r1v); VFMA(Wc[2], k2, r2v);
  }
}

// ---- one permuted Fm slot for 3 rows (base..base+2 of the lane's 6) -------
// Fm[r][c] = delta - <H[c,:], W[:,r]>. Slot (m,k): column c = 6*(t^m)+k.
// Pair layout: P = 3m + k/2, half = k&1 — pair halves share the DPP control.
template<int m, int k, int base>
__device__ __forceinline__ void slot4(const float* myH, int t,
    const float4* Wa, const float4* Wb, const float4* Wc,
    f2* pA, f2* pB, f2* pC) {
  const int c = 6 * (t ^ m) + k;
  const float4* hc = (const float4*)(myH + c * 12);
  float4 h0 = hc[0], h1 = hc[1], h2 = hc[2];
  float d0 = 0.f, d1 = 0.f, d2 = 0.f;
  FMA4(d0, h0, Wa[0]); FMA4(d0, h1, Wa[1]); FMA4(d0, h2, Wa[2]);
  FMA4(d1, h0, Wb[0]); FMA4(d1, h1, Wb[1]); FMA4(d1, h2, Wb[2]);
  FMA4(d2, h0, Wc[0]); FMA4(d2, h1, Wc[1]); FMA4(d2, h2, Wc[2]);
  float v0 = ((m == 0 && k == base + 0) ? 1.0f : 0.0f) - d0;
  float v1 = ((m == 0 && k == base + 1) ? 1.0f : 0.0f) - d1;
  float v2 = ((m == 0 && k == base + 2) ? 1.0f : 0.0f) - d2;
  constexpr int P = 3 * m + (k >> 1);
  if constexpr ((k & 1) == 0) { pA[P].x = v0; pB[P].x = v1; pC[P].x = v2; }
  else                        { pA[P].y = v0; pB[P].y = v1; pC[P].y = v2; }
}

#define SLOTS(base, pA, pB, pC)                                   \
  slot4<0,0,base>(myH,t,Wa,Wb,Wc,pA,pB,pC);                       \
  slot4<0,1,base>(myH,t,Wa,Wb,Wc,pA,pB,pC);                       \
  slot4<0,2,base>(myH,t,Wa,Wb,Wc,pA,pB,pC);                       \
  slot4<0,3,base>(myH,t,Wa,Wb,Wc,pA,pB,pC);                       \
  slot4<0,4,base>(myH,t,Wa,Wb,Wc,pA,pB,pC);                       \
  slot4<0,5,base>(myH,t,Wa,Wb,Wc,pA,pB,pC);                       \
  slot4<1,0,base>(myH,t,Wa,Wb,Wc,pA,pB,pC);                       \
  slot4<1,1,base>(myH,t,Wa,Wb,Wc,pA,pB,pC);                       \
  slot4<1,2,base>(myH,t,Wa,Wb,Wc,pA,pB,pC);                       \
  slot4<1,3,base>(myH,t,Wa,Wb,Wc,pA,pB,pC);                       \
  slot4<1,4,base>(myH,t,Wa,Wb,Wc,pA,pB,pC);                       \
  slot4<1,5,base>(myH,t,Wa,Wb,Wc,pA,pB,pC);                       \
  slot4<2,0,base>(myH,t,Wa,Wb,Wc,pA,pB,pC);                       \
  slot4<2,1,base>(myH,t,Wa,Wb,Wc,pA,pB,pC);                       \
  slot4<2,2,base>(myH,t,Wa,Wb,Wc,pA,pB,pC);                       \
  slot4<2,3,base>(myH,t,Wa,Wb,Wc,pA,pB,pC);                       \
  slot4<2,4,base>(myH,t,Wa,Wb,Wc,pA,pB,pC);                       \
  slot4<2,5,base>(myH,t,Wa,Wb,Wc,pA,pB,pC);                       \
  slot4<3,0,base>(myH,t,Wa,Wb,Wc,pA,pB,pC);                       \
  slot4<3,1,base>(myH,t,Wa,Wb,Wc,pA,pB,pC);                       \
  slot4<3,2,base>(myH,t,Wa,Wb,Wc,pA,pB,pC);                       \
  slot4<3,3,base>(myH,t,Wa,Wb,Wc,pA,pB,pC);                       \
  slot4<3,4,base>(myH,t,Wa,Wb,Wc,pA,pB,pC);                       \
  slot4<3,5,base>(myH,t,Wa,Wb,Wc,pA,pB,pC);

__global__ __attribute__((amdgpu_flat_work_group_size(BLOCK, BLOCK),
                          amdgpu_waves_per_eu(1, 4)))
void pdhg_kernel(const float* __restrict__ P, const float* __restrict__ q,
                 const float* __restrict__ H, const float* __restrict__ b,
                 const float* __restrict__ cf, const int* __restrict__ itp,
                 float* __restrict__ out, int Btot) {
  __shared__ __align__(16) float sH[EPB * HS];
  __shared__ __align__(16) float sGi[EPB * GS];
  __shared__ __align__(16) float sB[EPB * SS];
  __shared__ __align__(16) float sAux[EPB * SS];

  const int tid  = threadIdx.x;
  const int wq   = tid >> 6;          // wave 0..1 — fully independent
  const int lane = tid & 63;
  const int g16  = lane >> 2;         // 4-lane group 0..15
  const int t    = lane & 3;
  const int e    = wq * 16 + g16;     // block-local env
  const int env  = blockIdx.x * EPB + e;
  const int envW0 = blockIdx.x * EPB + wq * 16;
  const int niter = itp[0];
  const int r6 = 6 * t;               // first of this lane's 6 iteration rows

  // ---- PER-WAVE float4 staging of this wave's 16 envs: H, P, q, b ----
  {
    const float4* gH = (const float4*)(H + (size_t)envW0 * 288);
#pragma unroll
    for (int rep = 0; rep < 18; ++rep) {          // 16 envs * 72 f4 = 1152
      int i = lane + rep * 64;
      int ee = i / 72, off = i - ee * 72;
      *(float4*)&sH[(wq * 16 + ee) * HS + off * 4] = gH[i];
    }
    const float4* gP = (const float4*)(P + (size_t)envW0 * 144);
#pragma unroll
    for (int rep = 0; rep < 9; ++rep) {           // 16 envs * 36 f4 = 576
      int i = lane + rep * 64;
      int ee = i / 36, off = i - ee * 36;
      *(float4*)&sGi[(wq * 16 + ee) * GS + off * 4] = gP[i];
    }
    const float4* gq = (const float4*)(q + (size_t)envW0 * 12);
    if (lane < 48) {                              // 16 envs * 3 f4
      int ee = lane / 3, off = lane - ee * 3;
      *(float4*)&sAux[(wq * 16 + ee) * SS + off * 4] = gq[lane];
    }
    const float4* gb = (const float4*)(b + (size_t)envW0 * 24);
    {                                             // 16 envs * 6 f4 = 96
      int i = lane;
      int ee = i / 6, off = i - ee * 6;
      *(float4*)&sB[(wq * 16 + ee) * SS + off * 4] = gb[i];
      if (lane < 32) {
        i = lane + 64;
        ee = i / 6; off = i - ee * 6;
        *(float4*)&sB[(wq * 16 + ee) * SS + off * 4] = gb[i];
      }
    }
  }
  WFENCE();

  const float* myH = &sH[e * HS];
  float* giB  = &sGi[e * GS];
  float* auxB = &sAux[e * SS];
  float* bBm  = &sB[e * SS];
  const float* bB = bBm;

  // ---- G = P + HtH in registers (rows t, t+4, t+8); invert in place -------
  float4 a0, b0, c0, a1, b1, c1, a2, b2, c2;
  gram3(myH, t, a0, b0, c0, a1, b1, c1, a2, b2, c2);
  {
    const float4* p0 = (const float4*)(giB + t * 12);
    const float4* p1 = (const float4*)(giB + (t + 4) * 12);
    const float4* p2 = (const float4*)(giB + (t + 8) * 12);
    float4 q0 = p0[0], q1 = p0[1], q2 = p0[2];
    float4 r0 = p1[0], r1 = p1[1], r2 = p1[2];
    float4 s0 = p2[0], s1 = p2[1], s2 = p2[2];
    ADD4(a0, q0); ADD4(b0, q1); ADD4(c0, q2);
    ADD4(a1, r0); ADD4(b1, r1); ADD4(c1, r2);
    ADD4(a2, s0); ADD4(b2, s1); ADD4(c2, s2);
  }
  rgj3_all<0>(a0, b0, c0, a1, b1, c1, a2, b2, c2, auxB + 12, t);

  // ---- publish Ginv to LDS (overwrites staged P) + y = Ginv*q -------------
  {
    float4* w0 = (float4*)(giB + t * 12);        w0[0] = a0; w0[1] = b0; w0[2] = c0;
    float4* w1 = (float4*)(giB + (t + 4) * 12);  w1[0] = a1; w1[1] = b1; w1[2] = c1;
    float4* w2 = (float4*)(giB + (t + 8) * 12);  w2[0] = a2; w2[1] = b2; w2[2] = c2;
  }
  float y0 = dot12(a0, b0, c0, auxB);
  float y1 = dot12(a1, b1, c1, auxB);
  float y2 = dot12(a2, b2, c2, auxB);
  WFENCE();
  auxB[12 + t] = y0; auxB[16 + t] = y1; auxB[20 + t] = y2;
  WFENCE();

  // ---- permuted Fm rows (6 rows x 12 col-pairs), two 3-row passes ---------
  f2 pm0_[12], pm1_[12], pm2_[12], pm3_[12], pm4_[12], pm5_[12];
  {
    float4 Wa[3], Wb[3], Wc[3];
    buildW(myH, giB, r6 + 0, Wa, Wb, Wc);
    SLOTS(0, pm0_, pm1_, pm2_)
    buildW(myH, giB, r6 + 3, Wa, Wb, Wc);
    SLOTS(3, pm3_, pm4_, pm5_)
  }

  // ---- u = H*y for the 6 own rows (AFTER pm build: short live range) ------
  float u0, u1, u2, u3, u4, u5;
  {
    const float4* y4 = (const float4*)(auxB + 12);
    float4 ya = y4[0], yb = y4[1], yc = y4[2];
#define UROW(rr, dst) { const float4* hp = (const float4*)(myH + (r6 + (rr)) * 12); \
      float4 h0 = hp[0], h1 = hp[1], h2 = hp[2]; dst = 0.f;                         \
      FMA4(dst, h0, ya); FMA4(dst, h1, yb); FMA4(dst, h2, yc); }
    UROW(0, u0) UROW(1, u1) UROW(2, u2) UROW(3, u3) UROW(4, u4) UROW(5, u5)
#undef UROW
  }

  // ---- mu = H*y - Fm*b (b gathered in the same pair order) ----------------
  float mu0, mu1, mu2, mu3, mu4, mu5;
  {
    const int cA = 6 * (t ^ 1), cB = 6 * (t ^ 2), cC = 6 * (t ^ 3);
    f2 bq0 = { bB[r6 + 0], bB[r6 + 1] };
    f2 bq1 = { bB[r6 + 2], bB[r6 + 3] };
    f2 bq2 = { bB[r6 + 4], bB[r6 + 5] };
    f2 bq3 = { bB[cA + 0], bB[cA + 1] };
    f2 bq4 = { bB[cA + 2], bB[cA + 3] };
    f2 bq5 = { bB[cA + 4], bB[cA + 5] };
    f2 bq6 = { bB[cB + 0], bB[cB + 1] };
    f2 bq7 = { bB[cB + 2], bB[cB + 3] };
    f2 bq8 = { bB[cB + 4], bB[cB + 5] };
    f2 bq9 = { bB[cC + 0], bB[cC + 1] };
    f2 bq10 = { bB[cC + 2], bB[cC + 3] };
    f2 bq11 = { bB[cC + 4], bB[cC + 5] };
#define MUROW(rr, uu) {                                              \
    f2 S1 = {0.f, 0.f}, S2 = {0.f, 0.f};                             \
    S1 = pkfma(pm##rr##_[0], bq0, S1);                               \
    S1 = pkfma(pm##rr##_[1], bq1, S1);                               \
    S1 = pkfma(pm##rr##_[2], bq2, S1);                               \
    S1 = pkfma(pm##rr##_[3], bq3, S1);                               \
    S1 = pkfma(pm##rr##_[4], bq4, S1);                               \
    S1 = pkfma(pm##rr##_[5], bq5, S1);                               \
    S2 = pkfma(pm##rr##_[6], bq6, S2);                               \
    S2 = pkfma(pm##rr##_[7], bq7, S2);                               \
    S2 = pkfma(pm##rr##_[8], bq8, S2);                               \
    S2 = pkfma(pm##rr##_[9], bq9, S2);                               \
    S2 = pkfma(pm##rr##_[10], bq10, S2);                             \
    S2 = pkfma(pm##rr##_[11], bq11, S2);                             \
    f2 St = S1 + S2;                                                 \
    mu##rr = (uu) - (St.x + St.y); }
    MUROW(0, u0) MUROW(1, u1) MUROW(2, u2)
    MUROW(3, u3) MUROW(4, u4) MUROW(5, u5)
#undef MUROW
  }
  const float* cfp = cf + (size_t)env * 24 + r6;
  float cfv0 = cfp[0], cfv1 = cfp[1], cfv2 = cfp[2];
  float cfv3 = cfp[3], cfv4 = cfp[4], cfv5 = cfp[5];

  // ---- iterations: 18 depth-1 DPP + 72 pkfma (6 rows x 12 pairs) ----------
  // Lane t<2: rows 0..11 = cones (two 3-row cones per lane, gate rows 2,5).
  // Lane t>=2: rows 12..23 = box (clamp +-10, gate always).
  const float plo  = (t < 2) ? -3.0e38f : -10.0f;
  const float phi  = (t < 2) ?  3.0e38f :  10.0f;
  const float pthr = (t < 2) ? 0.0f     : -3.0e38f;
  float l0 = 0.f, l1 = 0.f, l2 = 0.f, l3 = 0.f, l4 = 0.f, l5 = 0.f;
  float z0 = 0.f, z1 = 0.f, z2 = 0.f, z3 = 0.f, z4 = 0.f, z5 = 0.f;
#pragma unroll 1
  for (int it = 0; it < niter; ++it) {
    f2 q0, q1, q2;                       // own s pairs (pair indices 0..2)
    q0.x = l0 + z0; q0.y = l1 + z1;
    q1.x = l2 + z2; q1.y = l3 + z3;
    q2.x = l4 + z4; q2.y = l5 + z5;
    // 18 DPPs, all depth-1, pair halves share the control (mov-free)
    f2 q3, q4, q5, q6, q7, q8, q9, q10, q11;
    q3.x = dppv<DPP_XOR1>(q0.x);  q3.y = dppv<DPP_XOR1>(q0.y);
    q4.x = dppv<DPP_XOR1>(q1.x);  q4.y = dppv<DPP_XOR1>(q1.y);
    q5.x = dppv<DPP_XOR1>(q2.x);  q5.y = dppv<DPP_XOR1>(q2.y);
    q6.x = dppv<DPP_XOR2>(q0.x);  q6.y = dppv<DPP_XOR2>(q0.y);
    q7.x = dppv<DPP_XOR2>(q1.x);  q7.y = dppv<DPP_XOR2>(q1.y);
    q8.x = dppv<DPP_XOR2>(q2.x);  q8.y = dppv<DPP_XOR2>(q2.y);
    q9.x = dppv<DPP_QP3>(q0.x);   q9.y = dppv<DPP_QP3>(q0.y);
    q10.x = dppv<DPP_QP3>(q1.x);  q10.y = dppv<DPP_QP3>(q1.y);
    q11.x = dppv<DPP_QP3>(q2.x);  q11.y = dppv<DPP_QP3>(q2.y);
    // 72 pkfma: per row two independent 6-chains
#define FMAROW(rr, wdst) {                                           \
    f2 A = { mu##rr, 0.f };                                          \
    f2 Bv = { 0.f, 0.f };                                            \
    A = pkfma(pm##rr##_[0], q0, A);                                  \
    A = pkfma(pm##rr##_[1], q1, A);                                  \
    A = pkfma(pm##rr##_[2], q2, A);                                  \
    A = pkfma(pm##rr##_[3], q3, A);                                  \
    A = pkfma(pm##rr##_[4], q4, A);                                  \
    A = pkfma(pm##rr##_[5], q5, A);                                  \
    Bv = pkfma(pm##rr##_[6], q6, Bv);                                \
    Bv = pkfma(pm##rr##_[7], q7, Bv);                                \
    Bv = pkfma(pm##rr##_[8], q8, Bv);                                \
    Bv = pkfma(pm##rr##_[9], q9, Bv);                                \
    Bv = pkfma(pm##rr##_[10], q10, Bv);                              \
    Bv = pkfma(pm##rr##_[11], q11, Bv);                              \
    f2 C = A + Bv;                                                   \
    wdst = C.x + C.y; }
    float w0, w1, w2, w3, w4, w5;
    FMAROW(0, w0) FMAROW(1, w1) FMAROW(2, w2)
    FMAROW(3, w3) FMAROW(4, w4) FMAROW(5, w5)
#undef FMAROW
    float zp0 = fmaf(-2.0f, w0, q0.x);
    float zp1 = fmaf(-2.0f, w1, q0.y);
    float zp2 = fmaf(-2.0f, w2, q1.x);
    float zp3 = fmaf(-2.0f, w3, q1.y);
    float zp4 = fmaf(-2.0f, w4, q2.x);
    float zp5 = fmaf(-2.0f, w5, q2.y);
    l0 = w0; l1 = w1; l2 = w2; l3 = w3; l4 = w4; l5 = w5;
    bool gA = zp2 > pthr;               // cone 0 gate (rows 0-2) / box: true
    bool gB = zp5 > pthr;               // cone 1 gate (rows 3-5) / box: true
    float e0 = gA ? cfv0 : 0.0f;
    float e1 = gA ? cfv1 : 0.0f;
    float e2 = gA ? cfv2 : 0.0f;
    float e3 = gB ? cfv3 : 0.0f;
    float e4 = gB ? cfv4 : 0.0f;
    float e5 = gB ? cfv5 : 0.0f;
    z0 = __builtin_amdgcn_fmed3f(zp0, plo, phi) * e0;
    z1 = __builtin_amdgcn_fmed3f(zp1, plo, phi) * e1;
    z2 = __builtin_amdgcn_fmed3f(zp2, plo, phi) * e2;
    z3 = __builtin_amdgcn_fmed3f(zp3, plo, phi) * e3;
    z4 = __builtin_amdgcn_fmed3f(zp4, plo, phi) * e4;
    z5 = __builtin_amdgcn_fmed3f(zp5, plo, phi) * e5;
  }

  // ---- outputs: lz, then x = (HtH)^-1 Ht (z - b) --------------------------
  float* xout  = out;
  float* lzout = out + (size_t)Btot * 12;
  {
    size_t base = (size_t)env * 48 + r6;
    lzout[base + 0] = l0; lzout[base + 1] = l1; lzout[base + 2] = l2;
    lzout[base + 3] = l3; lzout[base + 4] = l4; lzout[base + 5] = l5;
    lzout[base + 24 + 0] = z0; lzout[base + 24 + 1] = z1; lzout[base + 24 + 2] = z2;
    lzout[base + 24 + 3] = z3; lzout[base + 24 + 4] = z4; lzout[base + 24 + 5] = z5;
  }

  float bo0 = bB[r6 + 0], bo1 = bB[r6 + 1], bo2 = bB[r6 + 2];
  float bo3 = bB[r6 + 3], bo4 = bB[r6 + 4], bo5 = bB[r6 + 5];
  WFENCE();
  auxB[r6 + 0] = z0 - bo0; auxB[r6 + 1] = z1 - bo1; auxB[r6 + 2] = z2 - bo2;
  auxB[r6 + 3] = z3 - bo3; auxB[r6 + 4] = z4 - bo4; auxB[r6 + 5] = z5 - bo5;
  WFENCE();

  // rv = Ht (z - b), three owned columns in one pass
  float rv0 = 0.f, rv1 = 0.f, rv2 = 0.f;
  {
    const float4* a4 = (const float4*)auxB;
    float4 au0 = a4[0], au1 = a4[1], au2 = a4[2], au3 = a4[3], au4 = a4[4], au5 = a4[5];
#define RVS(k, AV) { rv0 = fmaf(myH[(k) * 12 + t],     (AV), rv0);  \
                     rv1 = fmaf(myH[(k) * 12 + t + 4], (AV), rv1);  \
                     rv2 = fmaf(myH[(k) * 12 + t + 8], (AV), rv2); }
    RVS(0,  au0.x) RVS(1,  au0.y) RVS(2,  au0.z) RVS(3,  au0.w)
    RVS(4,  au1.x) RVS(5,  au1.y) RVS(6,  au1.z) RVS(7,  au1.w)
    RVS(8,  au2.x) RVS(9,  au2.y) RVS(10, au2.z) RVS(11, au2.w)
    RVS(12, au3.x) RVS(13, au3.y) RVS(14, au3.z) RVS(15, au3.w)
    RVS(16, au4.x) RVS(17, au4.y) RVS(18, au4.z) RVS(19, au4.w)
    RVS(20, au5.x) RVS(21, au5.y) RVS(22, au5.z) RVS(23, au5.w)
#undef RVS
  }

  // second Gram (no P) + register GJ; pivot buffer reuses sB[0..11]
  gram3(myH, t, a0, b0, c0, a1, b1, c1, a2, b2, c2);
  WFENCE();
  auxB[t] = rv0; auxB[t + 4] = rv1; auxB[t + 8] = rv2;
  WFENCE();
  rgj3_all<0>(a0, b0, c0, a1, b1, c1, a2, b2, c2, bBm, t);

  xout[(size_t)env * 12 + t]     = dot12(a0, b0, c0, auxB);
  xout[(size_t)env * 12 + t + 4] = dot12(a1, b1, c1, auxB);
  xout[(size_t)env * 12 + t + 8] = dot12(a2, b2, c2, auxB);
}

extern "C" void kernel_launch(void* const* d_in, const int* in_sizes, int n_in,
                              void* d_out, int out_size, void* d_ws, size_t ws_size,
                              hipStream_t stream) {
  const float* P  = (const float*)d_in[0];
  const float* q  = (const float*)d_in[1];
  const float* H  = (const float*)d_in[2];
  const float* b  = (const float*)d_in[3];
  const float* cf = (const float*)d_in[4];
  const int*   it = (const int*)d_in[5];
  float* out = (float*)d_out;
  const int B = in_sizes[1] / 12;       // q is [B,12]
  const int grid = B / EPB;             // 16384/32 = 512 blocks
  pdhg_kernel<<<grid, BLOCK, 0, stream>>>(P, q, H, b, cf, it, out, B);
}